// Round 1
// baseline (475.361 us; speedup 1.0000x reference)
//
#include <hip/hip_runtime.h>
#include <hip/hip_bf16.h>
#include <math.h>

#define HIDN  2048
#define NH    16
#define NKV   4
#define LORA  512
#define D_ROPE 64
#define D_NOPE 128
#define D_VV  128
#define D_QKD 192
#define BATCH 2
#define SEQ   2048
#define NTOK  (BATCH*SEQ)          // 4096
#define QKV_W (NH*D_QKD + LORA)    // 3584
#define KW    (NKV*D_QKD)          // 768
#define VW    (NKV*D_VV)           // 512
#define AW    (NH*D_VV)            // 2048
#define QSCALE 0.07216878364870323f   // 1/sqrt(192)
#define LOG2E  1.4426950408889634f

typedef __attribute__((ext_vector_type(8))) __bf16 bf16x8;
typedef __attribute__((ext_vector_type(4))) float f32x4;

static __device__ __forceinline__ unsigned short f2bf(float f) {
    unsigned int u = __builtin_bit_cast(unsigned int, f);
    u += 0x7fffu + ((u >> 16) & 1u);          // round-to-nearest-even
    return (unsigned short)(u >> 16);
}
static __device__ __forceinline__ float bf2f(unsigned short v) {
    unsigned int u = (unsigned int)v << 16;
    return __builtin_bit_cast(float, u);
}
static __device__ __forceinline__ void gl2lds16(const unsigned short* g, unsigned short* l) {
    __builtin_amdgcn_global_load_lds(
        (const __attribute__((address_space(1))) unsigned int*)g,
        (__attribute__((address_space(3))) unsigned int*)l, 16, 0, 0);
}

// ---------------------------------------------------------------------------
// Transpose + cast: W fp32 [K][N] -> Wt bf16 [N][K]; optional column scale.
// ---------------------------------------------------------------------------
__global__ __launch_bounds__(256) void transpose_w(
    const float* __restrict__ W, unsigned short* __restrict__ Wt,
    int K, int N, int scale_ncols, float scale)
{
    __shared__ float T[64][68];
    const int tid = threadIdx.x;
    const int k0 = blockIdx.y * 64, n0 = blockIdx.x * 64;
    const int rr = tid >> 4;
    const int c4 = (tid & 15) * 4;

#pragma unroll
    for (int i = 0; i < 4; ++i) {
        int r = rr + 16 * i;
        *(float4*)&T[r][c4] = *(const float4*)&W[(size_t)(k0 + r) * N + n0 + c4];
    }
    __syncthreads();
#pragma unroll
    for (int i = 0; i < 4; ++i) {
        int nr = rr + 16 * i;
        float sc = (n0 + nr < scale_ncols) ? scale : 1.0f;
        unsigned short tmp[4];
#pragma unroll
        for (int j = 0; j < 4; ++j) tmp[j] = f2bf(T[c4 + j][nr] * sc);
        unsigned int p0 = (unsigned int)tmp[0] | ((unsigned int)tmp[1] << 16);
        unsigned int p1 = (unsigned int)tmp[2] | ((unsigned int)tmp[3] << 16);
        *(uint2*)&Wt[(size_t)(n0 + nr) * K + k0 + c4] = make_uint2(p0, p1);
    }
}

__global__ __launch_bounds__(256) void cast_plain(const float* __restrict__ src,
                                                  unsigned short* __restrict__ dst)
{
    int idx = blockIdx.x * 256 + threadIdx.x;
    float4 v = *(const float4*)&src[(size_t)idx * 4];
    unsigned int p0 = (unsigned int)f2bf(v.x) | ((unsigned int)f2bf(v.y) << 16);
    unsigned int p1 = (unsigned int)f2bf(v.z) | ((unsigned int)f2bf(v.w) << 16);
    *(uint2*)&dst[(size_t)idx * 4] = make_uint2(p0, p1);
}

// ---------------------------------------------------------------------------
// bf16 MFMA GEMM (m97 structure): C = A[M,K] @ Bt[N,K]^T.
// OUT_MODE: 0 = fp32 C[M][N], 1 = bf16 C[M][N], 2 = bf16 transposed Ct[N][M].
// ---------------------------------------------------------------------------
template<int OUT_MODE>
__global__ __launch_bounds__(256) void gemm_bt(
    const unsigned short* __restrict__ A,
    const unsigned short* __restrict__ Bt,
    void* __restrict__ C,
    int K, int lda, int ldb, int ldc)
{
    __shared__ __align__(16) unsigned short As[128 * 32];
    __shared__ __align__(16) unsigned short Bs[128 * 32];

    const int tid  = threadIdx.x;
    const int w    = tid >> 6;
    const int lane = tid & 63;
    const int quad = lane >> 4;
    const int l15  = lane & 15;
    const int brow = blockIdx.y * 128;
    const int bcol = blockIdx.x * 128;
    const int wr   = (w >> 1) * 64;
    const int wc   = (w & 1) * 64;

    const int srow = lane >> 2;
    const int sseg = (lane & 3) * 8;
    const int r0   = w * 32;

    f32x4 acc[4][4];
#pragma unroll
    for (int mt = 0; mt < 4; ++mt)
#pragma unroll
        for (int nt = 0; nt < 4; ++nt) acc[mt][nt] = (f32x4){0.f, 0.f, 0.f, 0.f};

    const unsigned short* Ab = A  + (size_t)(brow + r0 + srow) * lda + sseg;
    const unsigned short* Bb = Bt + (size_t)(bcol + r0 + srow) * ldb + sseg;

    for (int k0 = 0; k0 < K; k0 += 32) {
        __syncthreads();
        gl2lds16(Ab + k0,                     As + r0 * 32);
        gl2lds16(Ab + k0 + (size_t)16 * lda,  As + (r0 + 16) * 32);
        gl2lds16(Bb + k0,                     Bs + r0 * 32);
        gl2lds16(Bb + k0 + (size_t)16 * ldb,  Bs + (r0 + 16) * 32);
        __syncthreads();

        bf16x8 af[4], bfr[4];
#pragma unroll
        for (int mt = 0; mt < 4; ++mt)
            af[mt] = __builtin_bit_cast(bf16x8,
                *(const uint4*)(As + (wr + mt * 16 + l15) * 32 + quad * 8));
#pragma unroll
        for (int nt = 0; nt < 4; ++nt)
            bfr[nt] = __builtin_bit_cast(bf16x8,
                *(const uint4*)(Bs + (wc + nt * 16 + l15) * 32 + quad * 8));
#pragma unroll
        for (int mt = 0; mt < 4; ++mt)
#pragma unroll
            for (int nt = 0; nt < 4; ++nt)
                acc[mt][nt] = __builtin_amdgcn_mfma_f32_16x16x32_bf16(
                    af[mt], bfr[nt], acc[mt][nt], 0, 0, 0);
    }

    if (OUT_MODE == 2) {
#pragma unroll
        for (int mt = 0; mt < 4; ++mt) {
            int row0 = brow + wr + mt * 16 + quad * 4;
#pragma unroll
            for (int nt = 0; nt < 4; ++nt) {
                int col = bcol + wc + nt * 16 + l15;
                unsigned int p0 = (unsigned int)f2bf(acc[mt][nt][0]) |
                                  ((unsigned int)f2bf(acc[mt][nt][1]) << 16);
                unsigned int p1 = (unsigned int)f2bf(acc[mt][nt][2]) |
                                  ((unsigned int)f2bf(acc[mt][nt][3]) << 16);
                *(uint2*)&((unsigned short*)C)[(size_t)col * ldc + row0] = make_uint2(p0, p1);
            }
        }
    } else {
#pragma unroll
        for (int mt = 0; mt < 4; ++mt)
#pragma unroll
            for (int i = 0; i < 4; ++i) {
                size_t row = (size_t)(brow + wr + mt * 16 + quad * 4 + i);
#pragma unroll
                for (int nt = 0; nt < 4; ++nt) {
                    int col = bcol + wc + nt * 16 + l15;
                    if (OUT_MODE == 1)
                        ((unsigned short*)C)[row * ldc + col] = f2bf(acc[mt][nt][i]);
                    else
                        ((float*)C)[row * ldc + col] = acc[mt][nt][i];
                }
            }
    }
}

// ---------------------------------------------------------------------------
// RoPE in-place on bf16 q (inside qkvb) and bf16 k (kb).
// ---------------------------------------------------------------------------
__global__ __launch_bounds__(256) void rope_bf16(unsigned short* __restrict__ qkvb,
                                                 unsigned short* __restrict__ kb)
{
    int idx = blockIdx.x * 256 + threadIdx.x;
    int i    = idx & 31;
    int head = (idx >> 5) % 20;
    int t    = idx / (20 * 32);
    if (t >= NTOK) return;
    int pos = t & (SEQ - 1);

    const float LOG_BASE_OVER_32 = 0.28782313662425572f; // ln(10000)/32
    float ang = (float)pos * __expf(-(float)i * LOG_BASE_OVER_32);
    float c = cosf(ang);
    float sn = sinf(ang);

    unsigned short* p;
    if (head < NH) p = qkvb + (size_t)t * QKV_W + head * D_QKD + D_NOPE;
    else           p = kb   + (size_t)t * KW    + (head - NH) * D_QKD + D_NOPE;

    float x1 = bf2f(p[i]), x2 = bf2f(p[i + 32]);
    p[i]      = f2bf(x1 * c - x2 * sn);
    p[i + 32] = f2bf(x2 * c + x1 * sn);
}

// ---------------------------------------------------------------------------
// MFMA flash attention, causal, GQA. Fixed m=0 softmax in exp2 domain.
// Double-buffered K/V staging via global_load_lds DMA (no staging VGPRs).
// XOR-swizzled unpadded LDS layouts (DMA needs contiguity; swizzle keeps
// ds_read_b128 fragment reads at free 2-way bank aliasing):
//   K: [row][24 blk16], stored blk = gblk ^ (row&7)
//   V: [d][4 blk16],    stored blk = gblk ^ ((d>>1)&3)
// One __syncthreads per K-tile (its vmcnt drain completes the DMA).
//
// Grid = 32 q-tiles x NH x BATCH (1024 blocks): one qt per block, mapped
// heavy-first (qt = 31 - blockIdx.x) so long-k blocks dispatch first and
// light blocks backfill. 3 blocks/CU resident (LDS-limited) vs 2 for the
// old paired-phase layout -> better latency hiding.
// ---------------------------------------------------------------------------
__global__ __launch_bounds__(256) void attn_mfma(
    const unsigned short* __restrict__ qkvb,
    const unsigned short* __restrict__ kb,
    const unsigned short* __restrict__ vt,
    unsigned short* __restrict__ attnb)
{
    __shared__ __align__(16) unsigned short KsL[2 * 32 * 192];  // 2 x 12 KB
    __shared__ __align__(16) unsigned short VtL[2 * 128 * 32];  // 2 x 8 KB
    __shared__ __align__(16) unsigned short Ps[4 * 16 * 40];    // 5 KB

    const int tid  = threadIdx.x;
    const int w    = tid >> 6;
    const int lane = tid & 63;
    const int quad = lane >> 4;
    const int l15  = lane & 15;
    const int h    = blockIdx.y;
    const int b    = blockIdx.z;
    const int kvh  = h >> 2;
    const int x7   = l15 & 7;             // K read swizzle
    const int vx   = (l15 >> 1) & 3;      // V read swizzle

    // Per-lane DMA source offsets (shorts), tile-invariant.
    int koff[3], voff[2];
#pragma unroll
    for (int it = 0; it < 3; ++it) {
        int bidx = (w * 3 + it) * 64 + lane;      // 16B-block index in K tile
        int row  = bidx / 24;
        int sblk = bidx - row * 24;
        int gblk = sblk ^ (row & 7);
        koff[it] = row * KW + gblk * 8;
    }
#pragma unroll
    for (int it = 0; it < 2; ++it) {
        int bidx = (w * 2 + it) * 64 + lane;      // 16B-block index in V tile
        int row  = bidx >> 2;
        int gblk = (bidx & 3) ^ ((row >> 1) & 3);
        voff[it] = row * NTOK + gblk * 8;
    }
    const unsigned short* kp0 = kb + (size_t)(b * SEQ) * KW + kvh * D_QKD;
    const unsigned short* vp0 = vt + (size_t)(kvh * 128) * NTOK + b * SEQ;

    const int qt   = 31 - (int)blockIdx.x;   // heavy-first
    const int q0   = qt * 64;
    const int q0w  = q0 + w * 16;
    const int wmax = q0w + 15;

    bf16x8 qf[6];
    {
        const unsigned short* qp =
            qkvb + (size_t)(b * SEQ + q0w + l15) * QKV_W + h * D_QKD + quad * 8;
#pragma unroll
        for (int t = 0; t < 6; ++t)
            qf[t] = __builtin_bit_cast(bf16x8, *(const uint4*)(qp + t * 32));
    }

    f32x4 o[8];
#pragma unroll
    for (int c = 0; c < 8; ++c) o[c] = (f32x4){0.f, 0.f, 0.f, 0.f};
    float lp[4] = {0.f, 0.f, 0.f, 0.f};

    const int nt = 2 * qt + 2;

    // DMA tile 0 into buffer 0
    {
        const unsigned short* ks = kp0;
        const unsigned short* vs = vp0;
#pragma unroll
        for (int it = 0; it < 3; ++it)
            gl2lds16(ks + koff[it], KsL + (w * 3 + it) * 512);
#pragma unroll
        for (int it = 0; it < 2; ++it)
            gl2lds16(vs + voff[it], VtL + (w * 2 + it) * 512);
    }
    __syncthreads();   // vmcnt drain: tile 0 staged

    for (int tk = 0; tk < nt; ++tk) {
        const int k0  = tk * 32;
        const int cur = tk & 1;

        // Issue DMA for tile tk+1 into the other buffer (no wait, no regs)
        if (tk + 1 < nt) {
            const int nxt = cur ^ 1;
            const unsigned short* ks = kp0 + (size_t)(k0 + 32) * KW;
            const unsigned short* vs = vp0 + (k0 + 32);
#pragma unroll
            for (int it = 0; it < 3; ++it)
                gl2lds16(ks + koff[it], KsL + nxt * (32 * 192) + (w * 3 + it) * 512);
#pragma unroll
            for (int it = 0; it < 2; ++it)
                gl2lds16(vs + voff[it], VtL + nxt * (128 * 32) + (w * 2 + it) * 512);
        }

        if (k0 <= wmax) {
            const unsigned short* Kc = KsL + cur * (32 * 192);
            const unsigned short* Vc = VtL + cur * (128 * 32);

            // ---- scores: S[16q][32k] = Q @ K^T (log2 domain) ----
            f32x4 s[2];
#pragma unroll
            for (int j = 0; j < 2; ++j) {
                f32x4 acc = {0.f, 0.f, 0.f, 0.f};
                const unsigned short* kr = Kc + (j * 16 + l15) * 192;
#pragma unroll
                for (int t = 0; t < 6; ++t) {
                    int sblk = (quad + 4 * t) ^ x7;
                    bf16x8 kf = __builtin_bit_cast(bf16x8, *(const uint4*)(kr + sblk * 8));
                    acc = __builtin_amdgcn_mfma_f32_16x16x32_bf16(qf[t], kf, acc, 0, 0, 0);
                }
                s[j] = acc;
            }

            // ---- softmax, fixed m=0, exp2; per-lane partial l only ----
#pragma unroll
            for (int i = 0; i < 4; ++i) {
                int row = q0w + quad * 4 + i;
                float p0 = (k0 + l15      <= row) ? __builtin_amdgcn_exp2f(s[0][i]) : 0.f;
                float p1 = (k0 + 16 + l15 <= row) ? __builtin_amdgcn_exp2f(s[1][i]) : 0.f;
                s[0][i] = p0; s[1][i] = p1;
                lp[i] += p0 + p1;
            }

            // ---- P: C-layout -> LDS -> A-layout frag ----
            unsigned short* pw = Ps + w * (16 * 40);
#pragma unroll
            for (int i = 0; i < 4; ++i) {
                int row = quad * 4 + i;
                pw[row * 40 + l15]      = f2bf(s[0][i]);
                pw[row * 40 + 16 + l15] = f2bf(s[1][i]);
            }
            __asm__ volatile("s_waitcnt lgkmcnt(0)" ::: "memory");
            bf16x8 pa = __builtin_bit_cast(bf16x8, *(const uint4*)(pw + l15 * 40 + quad * 8));

            // ---- PV: 8 MFMAs, swizzled V frags ----
#pragma unroll
            for (int c = 0; c < 8; ++c) {
                bf16x8 vf = __builtin_bit_cast(bf16x8,
                    *(const uint4*)(Vc + (c * 16 + l15) * 32 + ((quad ^ vx) * 8)));
                o[c] = __builtin_amdgcn_mfma_f32_16x16x32_bf16(pa, vf, o[c], 0, 0, 0);
            }
        }

        __syncthreads();   // waves done with buf cur; DMA for tk+1 drained
    }

    // ---- epilogue: reduce l across the 16-lane groups, write out ----
#pragma unroll
    for (int i = 0; i < 4; ++i) {
        float sum = lp[i];
        sum += __shfl_xor(sum, 1);
        sum += __shfl_xor(sum, 2);
        sum += __shfl_xor(sum, 4);
        sum += __shfl_xor(sum, 8);
        float inv = 1.0f / sum;
        size_t rowoff = (size_t)(b * SEQ + q0w + quad * 4 + i) * AW + h * D_VV + l15;
#pragma unroll
        for (int c = 0; c < 8; ++c)
            attnb[rowoff + c * 16] = f2bf(o[c][i] * inv);
    }
}

// ---------------------------------------------------------------------------
extern "C" void kernel_launch(void* const* d_in, const int* in_sizes, int n_in,
                              void* d_out, int out_size, void* d_ws, size_t ws_size,
                              hipStream_t stream)
{
    const float* X     = (const float*)d_in[0];
    const float* Wqkv  = (const float*)d_in[1];
    const float* Wk_up = (const float*)d_in[2];
    const float* Wv_up = (const float*)d_in[3];
    const float* Wo    = (const float*)d_in[4];
    float* out = (float*)d_out;

    unsigned short* Xb    = (unsigned short*)d_ws;                   // [4096][2048]
    unsigned short* Wqt   = Xb    + (size_t)NTOK * HIDN;             // [3584][2048]
    unsigned short* Wkt   = Wqt   + (size_t)QKV_W * HIDN;            // [768][512]
    unsigned short* Wvt   = Wkt   + (size_t)KW * LORA;               // [512][512]
    unsigned short* Wot   = Wvt   + (size_t)VW * LORA;               // [2048][2048]
    unsigned short* qkvb  = Wot   + (size_t)HIDN * AW;               // [4096][3584]
    unsigned short* kb    = qkvb  + (size_t)NTOK * QKV_W;            // [4096][768]
    unsigned short* vtb   = kb    + (size_t)NTOK * KW;               // [512][4096] (V^T)
    unsigned short* attnb = vtb   + (size_t)VW * NTOK;               // [4096][2048]

    cast_plain<<<NTOK * HIDN / 4 / 256, 256, 0, stream>>>(X, Xb);
    // q columns pre-scaled by (1/sqrt(192)) * log2(e): softmax runs in exp2 domain
    transpose_w<<<dim3(QKV_W / 64, HIDN / 64), 256, 0, stream>>>(
        Wqkv, Wqt, HIDN, QKV_W, NH * D_QKD, QSCALE * LOG2E);
    transpose_w<<<dim3(KW / 64, LORA / 64), 256, 0, stream>>>(Wk_up, Wkt, LORA, KW, 0, 1.0f);
    transpose_w<<<dim3(VW / 64, LORA / 64), 256, 0, stream>>>(Wv_up, Wvt, LORA, VW, 0, 1.0f);
    transpose_w<<<dim3(AW / 64, HIDN / 64), 256, 0, stream>>>(Wo, Wot, HIDN, AW, 0, 1.0f);

    // qkvb = Xb @ Wqt^T (bf16; q cols pre-scaled)
    gemm_bt<1><<<dim3(QKV_W / 128, NTOK / 128), 256, 0, stream>>>(
        Xb, Wqt, qkvb, HIDN, HIDN, HIDN, QKV_W);

    // kb = c_kv @ Wkt^T (bf16) ; vt = (c_kv @ Wvt^T)^T (bf16, transposed out)
    gemm_bt<1><<<dim3(KW / 128, NTOK / 128), 256, 0, stream>>>(
        qkvb + NH * D_QKD, Wkt, kb, LORA, QKV_W, LORA, KW);
    gemm_bt<2><<<dim3(VW / 128, NTOK / 128), 256, 0, stream>>>(
        qkvb + NH * D_QKD, Wvt, vtb, LORA, QKV_W, LORA, NTOK);

    rope_bf16<<<(NTOK * 20 * 32 + 255) / 256, 256, 0, stream>>>(qkvb, kb);

    attn_mfma<<<dim3(32, NH, BATCH), 256, 0, stream>>>(qkvb, kb, vtb, attnb);

    gemm_bt<0><<<dim3(HIDN / 128, NTOK / 128), 256, 0, stream>>>(
        attnb, Wot, out, AW, AW, AW, HIDN);
}

// Round 2
// 403.252 us; speedup vs baseline: 1.1788x; 1.1788x over previous
//
#include <hip/hip_runtime.h>
#include <hip/hip_bf16.h>
#include <math.h>

#define HIDN  2048
#define NH    16
#define NKV   4
#define LORA  512
#define D_ROPE 64
#define D_NOPE 128
#define D_VV  128
#define D_QKD 192
#define BATCH 2
#define SEQ   2048
#define NTOK  (BATCH*SEQ)          // 4096
#define QKV_W (NH*D_QKD + LORA)    // 3584
#define KW    (NKV*D_QKD)          // 768
#define VW    (NKV*D_VV)           // 512
#define AW    (NH*D_VV)            // 2048
#define QSCALE 0.07216878364870323f   // 1/sqrt(192)
#define LOG2E  1.4426950408889634f

typedef __attribute__((ext_vector_type(8))) __bf16 bf16x8;
typedef __attribute__((ext_vector_type(4))) float f32x4;

static __device__ __forceinline__ unsigned short f2bf(float f) {
    unsigned int u = __builtin_bit_cast(unsigned int, f);
    u += 0x7fffu + ((u >> 16) & 1u);          // round-to-nearest-even
    return (unsigned short)(u >> 16);
}
static __device__ __forceinline__ float bf2f(unsigned short v) {
    unsigned int u = (unsigned int)v << 16;
    return __builtin_bit_cast(float, u);
}
static __device__ __forceinline__ void gl2lds16(const unsigned short* g, unsigned short* l) {
    __builtin_amdgcn_global_load_lds(
        (const __attribute__((address_space(1))) unsigned int*)g,
        (__attribute__((address_space(3))) unsigned int*)l, 16, 0, 0);
}

// ---------------------------------------------------------------------------
// Transpose + cast: W fp32 [K][N] -> Wt bf16 [N][K]; optional column scale.
// ---------------------------------------------------------------------------
__global__ __launch_bounds__(256) void transpose_w(
    const float* __restrict__ W, unsigned short* __restrict__ Wt,
    int K, int N, int scale_ncols, float scale)
{
    __shared__ float T[64][68];
    const int tid = threadIdx.x;
    const int k0 = blockIdx.y * 64, n0 = blockIdx.x * 64;
    const int rr = tid >> 4;
    const int c4 = (tid & 15) * 4;

#pragma unroll
    for (int i = 0; i < 4; ++i) {
        int r = rr + 16 * i;
        *(float4*)&T[r][c4] = *(const float4*)&W[(size_t)(k0 + r) * N + n0 + c4];
    }
    __syncthreads();
#pragma unroll
    for (int i = 0; i < 4; ++i) {
        int nr = rr + 16 * i;
        float sc = (n0 + nr < scale_ncols) ? scale : 1.0f;
        unsigned short tmp[4];
#pragma unroll
        for (int j = 0; j < 4; ++j) tmp[j] = f2bf(T[c4 + j][nr] * sc);
        unsigned int p0 = (unsigned int)tmp[0] | ((unsigned int)tmp[1] << 16);
        unsigned int p1 = (unsigned int)tmp[2] | ((unsigned int)tmp[3] << 16);
        *(uint2*)&Wt[(size_t)(n0 + nr) * K + k0 + c4] = make_uint2(p0, p1);
    }
}

__global__ __launch_bounds__(256) void cast_plain(const float* __restrict__ src,
                                                  unsigned short* __restrict__ dst)
{
    int idx = blockIdx.x * 256 + threadIdx.x;
    float4 v = *(const float4*)&src[(size_t)idx * 4];
    unsigned int p0 = (unsigned int)f2bf(v.x) | ((unsigned int)f2bf(v.y) << 16);
    unsigned int p1 = (unsigned int)f2bf(v.z) | ((unsigned int)f2bf(v.w) << 16);
    *(uint2*)&dst[(size_t)idx * 4] = make_uint2(p0, p1);
}

// ---------------------------------------------------------------------------
// bf16 MFMA GEMM (m97 structure): C = A[M,K] @ Bt[N,K]^T.
// OUT_MODE: 0 = fp32 C[M][N], 1 = bf16 C[M][N],
//           2 = bf16 transposed Ct[N][M] with k-interleave permutation on M
//               within each 32-row group (pos(k): k=4a+j -> 8a+j,
//               k=16+4a+j -> 8a+4+j). Matches attn's in-register P A-frag.
// ---------------------------------------------------------------------------
template<int OUT_MODE>
__global__ __launch_bounds__(256) void gemm_bt(
    const unsigned short* __restrict__ A,
    const unsigned short* __restrict__ Bt,
    void* __restrict__ C,
    int K, int lda, int ldb, int ldc)
{
    __shared__ __align__(16) unsigned short As[128 * 32];
    __shared__ __align__(16) unsigned short Bs[128 * 32];

    const int tid  = threadIdx.x;
    const int w    = tid >> 6;
    const int lane = tid & 63;
    const int quad = lane >> 4;
    const int l15  = lane & 15;
    const int brow = blockIdx.y * 128;
    const int bcol = blockIdx.x * 128;
    const int wr   = (w >> 1) * 64;
    const int wc   = (w & 1) * 64;

    const int srow = lane >> 2;
    const int sseg = (lane & 3) * 8;
    const int r0   = w * 32;

    f32x4 acc[4][4];
#pragma unroll
    for (int mt = 0; mt < 4; ++mt)
#pragma unroll
        for (int nt = 0; nt < 4; ++nt) acc[mt][nt] = (f32x4){0.f, 0.f, 0.f, 0.f};

    const unsigned short* Ab = A  + (size_t)(brow + r0 + srow) * lda + sseg;
    const unsigned short* Bb = Bt + (size_t)(bcol + r0 + srow) * ldb + sseg;

    for (int k0 = 0; k0 < K; k0 += 32) {
        __syncthreads();
        gl2lds16(Ab + k0,                     As + r0 * 32);
        gl2lds16(Ab + k0 + (size_t)16 * lda,  As + (r0 + 16) * 32);
        gl2lds16(Bb + k0,                     Bs + r0 * 32);
        gl2lds16(Bb + k0 + (size_t)16 * ldb,  Bs + (r0 + 16) * 32);
        __syncthreads();

        bf16x8 af[4], bfr[4];
#pragma unroll
        for (int mt = 0; mt < 4; ++mt)
            af[mt] = __builtin_bit_cast(bf16x8,
                *(const uint4*)(As + (wr + mt * 16 + l15) * 32 + quad * 8));
#pragma unroll
        for (int nt = 0; nt < 4; ++nt)
            bfr[nt] = __builtin_bit_cast(bf16x8,
                *(const uint4*)(Bs + (wc + nt * 16 + l15) * 32 + quad * 8));
#pragma unroll
        for (int mt = 0; mt < 4; ++mt)
#pragma unroll
            for (int nt = 0; nt < 4; ++nt)
                acc[mt][nt] = __builtin_amdgcn_mfma_f32_16x16x32_bf16(
                    af[mt], bfr[nt], acc[mt][nt], 0, 0, 0);
    }

    if (OUT_MODE == 2) {
#pragma unroll
        for (int mt = 0; mt < 4; ++mt) {
            int row0 = brow + wr + mt * 16 + quad * 4;   // token base, %4 == 0
            int r5   = row0 & 31;
            int pos  = ((r5 & 15) >> 2) * 8 + ((r5 >> 4) << 2);
            int prow0 = (row0 & ~31) | pos;              // k-interleave permute
#pragma unroll
            for (int nt = 0; nt < 4; ++nt) {
                int col = bcol + wc + nt * 16 + l15;
                unsigned int p0 = (unsigned int)f2bf(acc[mt][nt][0]) |
                                  ((unsigned int)f2bf(acc[mt][nt][1]) << 16);
                unsigned int p1 = (unsigned int)f2bf(acc[mt][nt][2]) |
                                  ((unsigned int)f2bf(acc[mt][nt][3]) << 16);
                *(uint2*)&((unsigned short*)C)[(size_t)col * ldc + prow0] = make_uint2(p0, p1);
            }
        }
    } else {
#pragma unroll
        for (int mt = 0; mt < 4; ++mt)
#pragma unroll
            for (int i = 0; i < 4; ++i) {
                size_t row = (size_t)(brow + wr + mt * 16 + quad * 4 + i);
#pragma unroll
                for (int nt = 0; nt < 4; ++nt) {
                    int col = bcol + wc + nt * 16 + l15;
                    if (OUT_MODE == 1)
                        ((unsigned short*)C)[row * ldc + col] = f2bf(acc[mt][nt][i]);
                    else
                        ((float*)C)[row * ldc + col] = acc[mt][nt][i];
                }
            }
    }
}

// ---------------------------------------------------------------------------
// RoPE in-place on bf16 q (inside qkvb) and bf16 k (kb).
// ---------------------------------------------------------------------------
__global__ __launch_bounds__(256) void rope_bf16(unsigned short* __restrict__ qkvb,
                                                 unsigned short* __restrict__ kb)
{
    int idx = blockIdx.x * 256 + threadIdx.x;
    int i    = idx & 31;
    int head = (idx >> 5) % 20;
    int t    = idx / (20 * 32);
    if (t >= NTOK) return;
    int pos = t & (SEQ - 1);

    const float LOG_BASE_OVER_32 = 0.28782313662425572f; // ln(10000)/32
    float ang = (float)pos * __expf(-(float)i * LOG_BASE_OVER_32);
    float c = cosf(ang);
    float sn = sinf(ang);

    unsigned short* p;
    if (head < NH) p = qkvb + (size_t)t * QKV_W + head * D_QKD + D_NOPE;
    else           p = kb   + (size_t)t * KW    + (head - NH) * D_QKD + D_NOPE;

    float x1 = bf2f(p[i]), x2 = bf2f(p[i + 32]);
    p[i]      = f2bf(x1 * c - x2 * sn);
    p[i + 32] = f2bf(x2 * c + x1 * sn);
}

// ---------------------------------------------------------------------------
// MFMA flash attention, causal, GQA. Fixed m=0 softmax in exp2 domain.
// Double-buffered K/V staging via global_load_lds DMA (no staging VGPRs).
// XOR-swizzled unpadded LDS layouts:
//   K: [row][24 blk16], stored blk = gblk ^ (row&7)
//   V: [d][4 blk16],    stored blk = gblk ^ ((d>>1)&3)
//
// In-register P (no Ps LDS buffer): QK^T is computed SWAPPED, S^T=mfma(K,Q)
// (A/B frag register layouts are identical, reuse same kf/qf reads). Each
// lane then holds P[q=l15][k in {4*quad+i, 16+4*quad+i}] — a valid A-frag
// under a k-permutation which is baked into V^T's global layout by
// gemm_bt<2> (pos(k) interleave). P->PV needs ZERO lane data movement.
// LDS = 40960 B -> 4 blocks/CU; grid of 1024 blocks is fully co-resident.
// bid->qt mapping gives each round-robin CU the set {31-j,16+j,15-j,j}
// (constant work sum), so the grid is balanced AND tail-free.
// ---------------------------------------------------------------------------
__global__ __launch_bounds__(256) void attn_mfma(
    const unsigned short* __restrict__ qkvb,
    const unsigned short* __restrict__ kb,
    const unsigned short* __restrict__ vt,
    unsigned short* __restrict__ attnb)
{
    __shared__ __align__(16) unsigned short KsL[2 * 32 * 192];  // 2 x 12 KB
    __shared__ __align__(16) unsigned short VtL[2 * 128 * 32];  // 2 x 8 KB

    const int tid  = threadIdx.x;
    const int w    = tid >> 6;
    const int lane = tid & 63;
    const int quad = lane >> 4;
    const int l15  = lane & 15;

    // balanced co-resident mapping: g = bid>>5 selects qt, bid&31 selects (h,b)
    const int bid = blockIdx.x;
    const int g   = bid >> 5;
    const int jj  = g & 7;
    const int m   = g >> 3;
    int qt;
    if      (m == 0) qt = 31 - jj;
    else if (m == 1) qt = 16 + jj;
    else if (m == 2) qt = 15 - jj;
    else             qt = jj;
    const int hb = bid & 31;
    const int h  = hb & 15;
    const int b  = hb >> 4;
    const int kvh = h >> 2;

    const int x7   = l15 & 7;             // K read swizzle
    const int vx   = (l15 >> 1) & 3;      // V read swizzle

    // Per-lane DMA source offsets (shorts), tile-invariant.
    int koff[3], voff[2];
#pragma unroll
    for (int it = 0; it < 3; ++it) {
        int bidx = (w * 3 + it) * 64 + lane;      // 16B-block index in K tile
        int row  = bidx / 24;
        int sblk = bidx - row * 24;
        int gblk = sblk ^ (row & 7);
        koff[it] = row * KW + gblk * 8;
    }
#pragma unroll
    for (int it = 0; it < 2; ++it) {
        int bidx = (w * 2 + it) * 64 + lane;      // 16B-block index in V tile
        int row  = bidx >> 2;
        int gblk = (bidx & 3) ^ ((row >> 1) & 3);
        voff[it] = row * NTOK + gblk * 8;
    }
    const unsigned short* kp0 = kb + (size_t)(b * SEQ) * KW + kvh * D_QKD;
    const unsigned short* vp0 = vt + (size_t)(kvh * 128) * NTOK + b * SEQ;

    const int q0   = qt * 64;
    const int q0w  = q0 + w * 16;
    const int wmax = q0w + 15;

    bf16x8 qf[6];
    {
        const unsigned short* qp =
            qkvb + (size_t)(b * SEQ + q0w + l15) * QKV_W + h * D_QKD + quad * 8;
#pragma unroll
        for (int t = 0; t < 6; ++t)
            qf[t] = __builtin_bit_cast(bf16x8, *(const uint4*)(qp + t * 32));
    }

    f32x4 o[8];
#pragma unroll
    for (int c = 0; c < 8; ++c) o[c] = (f32x4){0.f, 0.f, 0.f, 0.f};
    float lp = 0.f;     // partial l for q-row l15 over this lane's k-slots

    const int nt = 2 * qt + 2;

    // DMA tile 0 into buffer 0
    {
#pragma unroll
        for (int it = 0; it < 3; ++it)
            gl2lds16(kp0 + koff[it], KsL + (w * 3 + it) * 512);
#pragma unroll
        for (int it = 0; it < 2; ++it)
            gl2lds16(vp0 + voff[it], VtL + (w * 2 + it) * 512);
    }
    __syncthreads();   // vmcnt drain: tile 0 staged

    for (int tk = 0; tk < nt; ++tk) {
        const int k0  = tk * 32;
        const int cur = tk & 1;

        // Issue DMA for tile tk+1 into the other buffer (no wait, no regs)
        if (tk + 1 < nt) {
            const int nxt = cur ^ 1;
            const unsigned short* ks = kp0 + (size_t)(k0 + 32) * KW;
            const unsigned short* vs = vp0 + (k0 + 32);
#pragma unroll
            for (int it = 0; it < 3; ++it)
                gl2lds16(ks + koff[it], KsL + nxt * (32 * 192) + (w * 3 + it) * 512);
#pragma unroll
            for (int it = 0; it < 2; ++it)
                gl2lds16(vs + voff[it], VtL + nxt * (128 * 32) + (w * 2 + it) * 512);
        }

        if (k0 <= wmax) {
            const unsigned short* Kc = KsL + cur * (32 * 192);
            const unsigned short* Vc = VtL + cur * (128 * 32);

            // ---- scores: S^T[32k][16q] = K @ Q^T (log2 domain), swapped ----
            f32x4 s[2];
#pragma unroll
            for (int j = 0; j < 2; ++j) {
                f32x4 acc = {0.f, 0.f, 0.f, 0.f};
                const unsigned short* kr = Kc + (j * 16 + l15) * 192;
#pragma unroll
                for (int t = 0; t < 6; ++t) {
                    int sblk = (quad + 4 * t) ^ x7;
                    bf16x8 kf = __builtin_bit_cast(bf16x8, *(const uint4*)(kr + sblk * 8));
                    acc = __builtin_amdgcn_mfma_f32_16x16x32_bf16(kf, qf[t], acc, 0, 0, 0);
                }
                s[j] = acc;
            }
            // lane holds S[q = l15][k = k0 + j*16 + quad*4 + i]

            // ---- softmax, fixed m=0, exp2; causal mask; per-lane l ----
            const int qrow = q0w + l15;
#pragma unroll
            for (int j = 0; j < 2; ++j)
#pragma unroll
                for (int i = 0; i < 4; ++i) {
                    int kidx = k0 + j * 16 + quad * 4 + i;
                    float p = (kidx <= qrow) ? __builtin_amdgcn_exp2f(s[j][i]) : 0.f;
                    s[j][i] = p;
                    lp += p;
                }

            // ---- P -> A-frag: pure in-register pack (k-permuted V) ----
            uint4 pk;
            pk.x = (unsigned int)f2bf(s[0][0]) | ((unsigned int)f2bf(s[0][1]) << 16);
            pk.y = (unsigned int)f2bf(s[0][2]) | ((unsigned int)f2bf(s[0][3]) << 16);
            pk.z = (unsigned int)f2bf(s[1][0]) | ((unsigned int)f2bf(s[1][1]) << 16);
            pk.w = (unsigned int)f2bf(s[1][2]) | ((unsigned int)f2bf(s[1][3]) << 16);
            bf16x8 pa = __builtin_bit_cast(bf16x8, pk);

            // ---- PV: 8 MFMAs, swizzled V frags ----
#pragma unroll
            for (int c = 0; c < 8; ++c) {
                bf16x8 vf = __builtin_bit_cast(bf16x8,
                    *(const uint4*)(Vc + (c * 16 + l15) * 32 + ((quad ^ vx) * 8)));
                o[c] = __builtin_amdgcn_mfma_f32_16x16x32_bf16(pa, vf, o[c], 0, 0, 0);
            }
        }

        __syncthreads();   // waves done with buf cur; DMA for tk+1 drained
    }

    // ---- epilogue: total l per q-row, redistribute to C-layout rows ----
    float lt = lp;
    lt += __shfl_xor(lt, 16);
    lt += __shfl_xor(lt, 32);      // all lanes: l for q-row = their l15

#pragma unroll
    for (int i = 0; i < 4; ++i) {
        float inv = 1.0f / __shfl(lt, (lane & 48) | (quad * 4 + i));
        size_t rowoff = (size_t)(b * SEQ + q0w + quad * 4 + i) * AW + h * D_VV + l15;
#pragma unroll
        for (int c = 0; c < 8; ++c)
            attnb[rowoff + c * 16] = f2bf(o[c][i] * inv);
    }
}

// ---------------------------------------------------------------------------
extern "C" void kernel_launch(void* const* d_in, const int* in_sizes, int n_in,
                              void* d_out, int out_size, void* d_ws, size_t ws_size,
                              hipStream_t stream)
{
    const float* X     = (const float*)d_in[0];
    const float* Wqkv  = (const float*)d_in[1];
    const float* Wk_up = (const float*)d_in[2];
    const float* Wv_up = (const float*)d_in[3];
    const float* Wo    = (const float*)d_in[4];
    float* out = (float*)d_out;

    unsigned short* Xb    = (unsigned short*)d_ws;                   // [4096][2048]
    unsigned short* Wqt   = Xb    + (size_t)NTOK * HIDN;             // [3584][2048]
    unsigned short* Wkt   = Wqt   + (size_t)QKV_W * HIDN;            // [768][512]
    unsigned short* Wvt   = Wkt   + (size_t)KW * LORA;               // [512][512]
    unsigned short* Wot   = Wvt   + (size_t)VW * LORA;               // [2048][2048]
    unsigned short* qkvb  = Wot   + (size_t)HIDN * AW;               // [4096][3584]
    unsigned short* kb    = qkvb  + (size_t)NTOK * QKV_W;            // [4096][768]
    unsigned short* vtb   = kb    + (size_t)NTOK * KW;               // [512][4096] (V^T, k-permuted)
    unsigned short* attnb = vtb   + (size_t)VW * NTOK;               // [4096][2048]

    cast_plain<<<NTOK * HIDN / 4 / 256, 256, 0, stream>>>(X, Xb);
    // q columns pre-scaled by (1/sqrt(192)) * log2(e): softmax runs in exp2 domain
    transpose_w<<<dim3(QKV_W / 64, HIDN / 64), 256, 0, stream>>>(
        Wqkv, Wqt, HIDN, QKV_W, NH * D_QKD, QSCALE * LOG2E);
    transpose_w<<<dim3(KW / 64, LORA / 64), 256, 0, stream>>>(Wk_up, Wkt, LORA, KW, 0, 1.0f);
    transpose_w<<<dim3(VW / 64, LORA / 64), 256, 0, stream>>>(Wv_up, Wvt, LORA, VW, 0, 1.0f);
    transpose_w<<<dim3(AW / 64, HIDN / 64), 256, 0, stream>>>(Wo, Wot, HIDN, AW, 0, 1.0f);

    // qkvb = Xb @ Wqt^T (bf16; q cols pre-scaled)
    gemm_bt<1><<<dim3(QKV_W / 128, NTOK / 128), 256, 0, stream>>>(
        Xb, Wqt, qkvb, HIDN, HIDN, HIDN, QKV_W);

    // kb = c_kv @ Wkt^T (bf16) ; vt = (c_kv @ Wvt^T)^T (bf16, k-permuted cols)
    gemm_bt<1><<<dim3(KW / 128, NTOK / 128), 256, 0, stream>>>(
        qkvb + NH * D_QKD, Wkt, kb, LORA, QKV_W, LORA, KW);
    gemm_bt<2><<<dim3(VW / 128, NTOK / 128), 256, 0, stream>>>(
        qkvb + NH * D_QKD, Wvt, vtb, LORA, QKV_W, LORA, NTOK);

    rope_bf16<<<(NTOK * 20 * 32 + 255) / 256, 256, 0, stream>>>(qkvb, kb);

    attn_mfma<<<dim3(1024), 256, 0, stream>>>(qkvb, kb, vtb, attnb);

    gemm_bt<0><<<dim3(HIDN / 128, NTOK / 128), 256, 0, stream>>>(
        attnb, Wot, out, AW, AW, AW, HIDN);
}

// Round 3
// 351.865 us; speedup vs baseline: 1.3510x; 1.1460x over previous
//
#include <hip/hip_runtime.h>
#include <hip/hip_bf16.h>
#include <math.h>

#define HIDN  2048
#define NH    16
#define NKV   4
#define LORA  512
#define D_ROPE 64
#define D_NOPE 128
#define D_VV  128
#define D_QKD 192
#define BATCH 2
#define SEQ   2048
#define NTOK  (BATCH*SEQ)          // 4096
#define QKV_W (NH*D_QKD + LORA)    // 3584
#define KW    (NKV*D_QKD)          // 768
#define VW    (NKV*D_VV)           // 512
#define AW    (NH*D_VV)            // 2048
#define QSCALE 0.07216878364870323f   // 1/sqrt(192)
#define LOG2E  1.4426950408889634f

typedef __attribute__((ext_vector_type(8))) __bf16 bf16x8;
typedef __attribute__((ext_vector_type(4))) float f32x4;

static __device__ __forceinline__ unsigned short f2bf(float f) {
    unsigned int u = __builtin_bit_cast(unsigned int, f);
    u += 0x7fffu + ((u >> 16) & 1u);          // round-to-nearest-even
    return (unsigned short)(u >> 16);
}
static __device__ __forceinline__ float bf2f(unsigned short v) {
    unsigned int u = (unsigned int)v << 16;
    return __builtin_bit_cast(float, u);
}
static __device__ __forceinline__ void gl2lds16(const unsigned short* g, unsigned short* l) {
    __builtin_amdgcn_global_load_lds(
        (const __attribute__((address_space(1))) unsigned int*)g,
        (__attribute__((address_space(3))) unsigned int*)l, 16, 0, 0);
}

// ---------------------------------------------------------------------------
// Transpose + cast: W fp32 [K][N] -> Wt bf16 [N][K]; optional column scale.
// ---------------------------------------------------------------------------
__global__ __launch_bounds__(256) void transpose_w(
    const float* __restrict__ W, unsigned short* __restrict__ Wt,
    int K, int N, int scale_ncols, float scale)
{
    __shared__ float T[64][68];
    const int tid = threadIdx.x;
    const int k0 = blockIdx.y * 64, n0 = blockIdx.x * 64;
    const int rr = tid >> 4;
    const int c4 = (tid & 15) * 4;

#pragma unroll
    for (int i = 0; i < 4; ++i) {
        int r = rr + 16 * i;
        *(float4*)&T[r][c4] = *(const float4*)&W[(size_t)(k0 + r) * N + n0 + c4];
    }
    __syncthreads();
#pragma unroll
    for (int i = 0; i < 4; ++i) {
        int nr = rr + 16 * i;
        float sc = (n0 + nr < scale_ncols) ? scale : 1.0f;
        unsigned short tmp[4];
#pragma unroll
        for (int j = 0; j < 4; ++j) tmp[j] = f2bf(T[c4 + j][nr] * sc);
        unsigned int p0 = (unsigned int)tmp[0] | ((unsigned int)tmp[1] << 16);
        unsigned int p1 = (unsigned int)tmp[2] | ((unsigned int)tmp[3] << 16);
        *(uint2*)&Wt[(size_t)(n0 + nr) * K + k0 + c4] = make_uint2(p0, p1);
    }
}

__global__ __launch_bounds__(256) void cast_plain(const float* __restrict__ src,
                                                  unsigned short* __restrict__ dst)
{
    int idx = blockIdx.x * 256 + threadIdx.x;
    float4 v = *(const float4*)&src[(size_t)idx * 4];
    unsigned int p0 = (unsigned int)f2bf(v.x) | ((unsigned int)f2bf(v.y) << 16);
    unsigned int p1 = (unsigned int)f2bf(v.z) | ((unsigned int)f2bf(v.w) << 16);
    *(uint2*)&dst[(size_t)idx * 4] = make_uint2(p0, p1);
}

// ---------------------------------------------------------------------------
// bf16 MFMA GEMM (m97 structure, 128x128): kept for the small K=512 GEMMs.
// OUT_MODE: 1 = bf16 C[M][N],
//           2 = bf16 transposed Ct[N][M] with k-interleave permutation on M
//               within each 32-row group (attn's in-register P A-frag).
// ---------------------------------------------------------------------------
template<int OUT_MODE>
__global__ __launch_bounds__(256) void gemm_bt(
    const unsigned short* __restrict__ A,
    const unsigned short* __restrict__ Bt,
    void* __restrict__ C,
    int K, int lda, int ldb, int ldc)
{
    __shared__ __align__(16) unsigned short As[128 * 32];
    __shared__ __align__(16) unsigned short Bs[128 * 32];

    const int tid  = threadIdx.x;
    const int w    = tid >> 6;
    const int lane = tid & 63;
    const int quad = lane >> 4;
    const int l15  = lane & 15;
    const int brow = blockIdx.y * 128;
    const int bcol = blockIdx.x * 128;
    const int wr   = (w >> 1) * 64;
    const int wc   = (w & 1) * 64;

    const int srow = lane >> 2;
    const int sseg = (lane & 3) * 8;
    const int r0   = w * 32;

    f32x4 acc[4][4];
#pragma unroll
    for (int mt = 0; mt < 4; ++mt)
#pragma unroll
        for (int nt = 0; nt < 4; ++nt) acc[mt][nt] = (f32x4){0.f, 0.f, 0.f, 0.f};

    const unsigned short* Ab = A  + (size_t)(brow + r0 + srow) * lda + sseg;
    const unsigned short* Bb = Bt + (size_t)(bcol + r0 + srow) * ldb + sseg;

    for (int k0 = 0; k0 < K; k0 += 32) {
        __syncthreads();
        gl2lds16(Ab + k0,                     As + r0 * 32);
        gl2lds16(Ab + k0 + (size_t)16 * lda,  As + (r0 + 16) * 32);
        gl2lds16(Bb + k0,                     Bs + r0 * 32);
        gl2lds16(Bb + k0 + (size_t)16 * ldb,  Bs + (r0 + 16) * 32);
        __syncthreads();

        bf16x8 af[4], bfr[4];
#pragma unroll
        for (int mt = 0; mt < 4; ++mt)
            af[mt] = __builtin_bit_cast(bf16x8,
                *(const uint4*)(As + (wr + mt * 16 + l15) * 32 + quad * 8));
#pragma unroll
        for (int nt = 0; nt < 4; ++nt)
            bfr[nt] = __builtin_bit_cast(bf16x8,
                *(const uint4*)(Bs + (wc + nt * 16 + l15) * 32 + quad * 8));
#pragma unroll
        for (int mt = 0; mt < 4; ++mt)
#pragma unroll
            for (int nt = 0; nt < 4; ++nt)
                acc[mt][nt] = __builtin_amdgcn_mfma_f32_16x16x32_bf16(
                    af[mt], bfr[nt], acc[mt][nt], 0, 0, 0);
    }

    if (OUT_MODE == 2) {
#pragma unroll
        for (int mt = 0; mt < 4; ++mt) {
            int row0 = brow + wr + mt * 16 + quad * 4;   // token base, %4 == 0
            int r5   = row0 & 31;
            int pos  = ((r5 & 15) >> 2) * 8 + ((r5 >> 4) << 2);
            int prow0 = (row0 & ~31) | pos;              // k-interleave permute
#pragma unroll
            for (int nt = 0; nt < 4; ++nt) {
                int col = bcol + wc + nt * 16 + l15;
                unsigned int p0 = (unsigned int)f2bf(acc[mt][nt][0]) |
                                  ((unsigned int)f2bf(acc[mt][nt][1]) << 16);
                unsigned int p1 = (unsigned int)f2bf(acc[mt][nt][2]) |
                                  ((unsigned int)f2bf(acc[mt][nt][3]) << 16);
                *(uint2*)&((unsigned short*)C)[(size_t)col * ldc + prow0] = make_uint2(p0, p1);
            }
        }
    } else {
#pragma unroll
        for (int mt = 0; mt < 4; ++mt)
#pragma unroll
            for (int i = 0; i < 4; ++i) {
                size_t row = (size_t)(brow + wr + mt * 16 + quad * 4 + i);
#pragma unroll
                for (int nt = 0; nt < 4; ++nt) {
                    int col = bcol + wc + nt * 16 + l15;
                    ((unsigned short*)C)[row * ldc + col] = f2bf(acc[mt][nt][i]);
                }
            }
    }
}

// ---------------------------------------------------------------------------
// 8-phase 256-wide GEMM (T2+T3+T4+T5): C = A[M,K] @ Bt[N,K]^T.
// BM=256, BN template (256 or 128), BK=64, 512 threads = 8 waves (2M x 4N).
// Per-wave output 128 x BN/4. LDS: 2 slots x (A 32KB + B BN/4 KB), dynamic.
// A/B tiles XOR-swizzled (colblk ^= row&7): staged via pre-swizzled GLOBAL
// source + linear global_load_lds dest; ds_read_b128 frags land 2-way free.
// Pipeline: stage T(t+2) in a burst right after tile t's last phase barrier
// (slot just freed by that barrier), then counted vmcnt(NLOADS) + barrier
// guarantees T(t+1) resident while T(t+2)'s loads stay in flight (never
// drain to 0 mid-loop). Per phase: ds_read subtile -> barrier -> setprio(1)
// -> MFMA cluster -> setprio(0) -> barrier. B frags cached in regs (read
// once per tile, phase 0); A quadrant read per phase.
// OUT_MODE: 0 = fp32 C, 1 = bf16 C.
// ---------------------------------------------------------------------------
template<int OUT_MODE, int BN>
__global__ __launch_bounds__(512, 2) void gemm8p(
    const unsigned short* __restrict__ A,
    const unsigned short* __restrict__ Bt,
    void* __restrict__ C,
    int K, int lda, int ldb, int ldc)
{
    constexpr int BNF    = BN / 64;        // n-frags per wave (4 or 2)
    constexpr int LB     = BN / 64;        // B chunk-loads per thread
    constexpr int NLOADS = 4 + LB;         // staging loads per thread per tile
    constexpr int ASLOT  = 256 * 64;       // shorts
    constexpr int BSLOT  = BN * 64;
    constexpr int SLOT   = ASLOT + BSLOT;

    extern __shared__ __align__(16) unsigned short lds[];

    const int tid  = threadIdx.x;
    const int w    = tid >> 6;
    const int lane = tid & 63;
    const int quad = lane >> 4;
    const int l15  = lane & 15;
    const int wm   = w >> 2;               // 0..1
    const int wn   = w & 3;                // 0..3

    // XCD-aware bijective swizzle (caller guarantees nwg % 8 == 0)
    int fid = blockIdx.y * gridDim.x + blockIdx.x;
    int nwg = gridDim.x * gridDim.y;
    int cpx = nwg >> 3;
    int swz = (fid & 7) * cpx + (fid >> 3);
    int bx  = swz % gridDim.x;
    int by  = swz / gridDim.x;
    const int brow = by * 256;
    const int bcol = bx * BN;

    // staging source offsets: LDS chunk (row, c) <- global colblk c ^ (row&7)
    int aoff[4], boff[LB];
#pragma unroll
    for (int i = 0; i < 4; ++i) {
        int chunk = (w * 4 + i) * 64 + lane;      // 0..2047
        int row = chunk >> 3, c = chunk & 7;
        aoff[i] = row * lda + (c ^ (row & 7)) * 8;
    }
#pragma unroll
    for (int i = 0; i < LB; ++i) {
        int chunk = (w * LB + i) * 64 + lane;
        int row = chunk >> 3, c = chunk & 7;
        boff[i] = row * ldb + (c ^ (row & 7)) * 8;
    }
    const unsigned short* Ab = A  + (size_t)brow * lda;
    const unsigned short* Bb = Bt + (size_t)bcol * ldb;

    f32x4 acc[8][BNF];
#pragma unroll
    for (int mf = 0; mf < 8; ++mf)
#pragma unroll
        for (int nf = 0; nf < BNF; ++nf) acc[mf][nf] = (f32x4){0.f, 0.f, 0.f, 0.f};

    const int NT = K >> 6;

    auto stage = [&](int slot, int k0) {
        unsigned short* As = lds + slot * SLOT;
        unsigned short* Bs = As + ASLOT;
#pragma unroll
        for (int i = 0; i < 4; ++i)
            gl2lds16(Ab + k0 + aoff[i], As + (w * 4 + i) * 512);
#pragma unroll
        for (int i = 0; i < LB; ++i)
            gl2lds16(Bb + k0 + boff[i], Bs + (w * LB + i) * 512);
    };

    // prologue: T0 -> slot0, T1 -> slot1; wait T0 only (T1 stays in flight)
    stage(0, 0);
    stage(1, 64);
    if constexpr (NLOADS == 8) asm volatile("s_waitcnt vmcnt(8)" ::: "memory");
    else                       asm volatile("s_waitcnt vmcnt(6)" ::: "memory");
    __builtin_amdgcn_s_barrier();
    __builtin_amdgcn_sched_barrier(0);

#pragma unroll 1
    for (int t = 0; t < NT; ++t) {
        const unsigned short* As = lds + (t & 1) * SLOT;
        const unsigned short* Bs = As + ASLOT;
        bf16x8 bq[BNF][2];

#pragma unroll
        for (int ph = 0; ph < 4; ++ph) {
            if (ph == 0) {
#pragma unroll
                for (int nf = 0; nf < BNF; ++nf)
#pragma unroll
                    for (int kk = 0; kk < 2; ++kk) {
                        int r = wn * (BN / 4) + nf * 16 + l15;
                        bq[nf][kk] = __builtin_bit_cast(bf16x8,
                            *(const uint4*)(Bs + r * 64 + (((kk * 4 + quad) ^ (r & 7)) * 8)));
                    }
            }
            bf16x8 af[2][2];
#pragma unroll
            for (int m = 0; m < 2; ++m)
#pragma unroll
                for (int kk = 0; kk < 2; ++kk) {
                    int r = wm * 128 + (ph * 2 + m) * 16 + l15;
                    af[m][kk] = __builtin_bit_cast(bf16x8,
                        *(const uint4*)(As + r * 64 + (((kk * 4 + quad) ^ (r & 7)) * 8)));
                }
            __builtin_amdgcn_s_barrier();
            __builtin_amdgcn_s_setprio(1);
#pragma unroll
            for (int m = 0; m < 2; ++m)
#pragma unroll
                for (int nf = 0; nf < BNF; ++nf)
#pragma unroll
                    for (int kk = 0; kk < 2; ++kk)
                        acc[ph * 2 + m][nf] = __builtin_amdgcn_mfma_f32_16x16x32_bf16(
                            af[m][kk], bq[nf][kk], acc[ph * 2 + m][nf], 0, 0, 0);
            __builtin_amdgcn_s_setprio(0);
            __builtin_amdgcn_s_barrier();
        }

        // tile boundary: slot (t&1) free -> burst-stage T(t+2) into it
        if (t + 2 < NT) {
            stage(t & 1, (t + 2) * 64);
            if constexpr (NLOADS == 8) asm volatile("s_waitcnt vmcnt(8)" ::: "memory");
            else                       asm volatile("s_waitcnt vmcnt(6)" ::: "memory");
            __builtin_amdgcn_s_barrier();
            __builtin_amdgcn_sched_barrier(0);
        } else if (t + 1 < NT) {
            asm volatile("s_waitcnt vmcnt(0)" ::: "memory");   // epilogue drain
            __builtin_amdgcn_s_barrier();
            __builtin_amdgcn_sched_barrier(0);
        }
    }

    // epilogue: per-wave 128 x BN/4 C-write
#pragma unroll
    for (int mf = 0; mf < 8; ++mf) {
#pragma unroll
        for (int i = 0; i < 4; ++i) {
            size_t row = (size_t)(brow + wm * 128 + mf * 16 + quad * 4 + i);
#pragma unroll
            for (int nf = 0; nf < BNF; ++nf) {
                int col = bcol + wn * (BN / 4) + nf * 16 + l15;
                if (OUT_MODE == 1)
                    ((unsigned short*)C)[row * ldc + col] = f2bf(acc[mf][nf][i]);
                else
                    ((float*)C)[row * ldc + col] = acc[mf][nf][i];
            }
        }
    }
}

// ---------------------------------------------------------------------------
// RoPE in-place on bf16 q (inside qkvb) and bf16 k (kb).
// ---------------------------------------------------------------------------
__global__ __launch_bounds__(256) void rope_bf16(unsigned short* __restrict__ qkvb,
                                                 unsigned short* __restrict__ kb)
{
    int idx = blockIdx.x * 256 + threadIdx.x;
    int i    = idx & 31;
    int head = (idx >> 5) % 20;
    int t    = idx / (20 * 32);
    if (t >= NTOK) return;
    int pos = t & (SEQ - 1);

    const float LOG_BASE_OVER_32 = 0.28782313662425572f; // ln(10000)/32
    float ang = (float)pos * __expf(-(float)i * LOG_BASE_OVER_32);
    float c = cosf(ang);
    float sn = sinf(ang);

    unsigned short* p;
    if (head < NH) p = qkvb + (size_t)t * QKV_W + head * D_QKD + D_NOPE;
    else           p = kb   + (size_t)t * KW    + (head - NH) * D_QKD + D_NOPE;

    float x1 = bf2f(p[i]), x2 = bf2f(p[i + 32]);
    p[i]      = f2bf(x1 * c - x2 * sn);
    p[i + 32] = f2bf(x2 * c + x1 * sn);
}

// ---------------------------------------------------------------------------
// MFMA flash attention, causal, GQA. Fixed m=0 softmax in exp2 domain.
// In-register P via swapped QK^T + k-permuted V (see R2 notes). 40 KB LDS,
// 4 blocks/CU: 1024-block grid fully co-resident; balanced qt mapping.
// ---------------------------------------------------------------------------
__global__ __launch_bounds__(256) void attn_mfma(
    const unsigned short* __restrict__ qkvb,
    const unsigned short* __restrict__ kb,
    const unsigned short* __restrict__ vt,
    unsigned short* __restrict__ attnb)
{
    __shared__ __align__(16) unsigned short KsL[2 * 32 * 192];  // 2 x 12 KB
    __shared__ __align__(16) unsigned short VtL[2 * 128 * 32];  // 2 x 8 KB

    const int tid  = threadIdx.x;
    const int w    = tid >> 6;
    const int lane = tid & 63;
    const int quad = lane >> 4;
    const int l15  = lane & 15;

    const int bid = blockIdx.x;
    const int g   = bid >> 5;
    const int jj  = g & 7;
    const int m   = g >> 3;
    int qt;
    if      (m == 0) qt = 31 - jj;
    else if (m == 1) qt = 16 + jj;
    else if (m == 2) qt = 15 - jj;
    else             qt = jj;
    const int hb = bid & 31;
    const int h  = hb & 15;
    const int b  = hb >> 4;
    const int kvh = h >> 2;

    const int x7   = l15 & 7;             // K read swizzle
    const int vx   = (l15 >> 1) & 3;      // V read swizzle

    int koff[3], voff[2];
#pragma unroll
    for (int it = 0; it < 3; ++it) {
        int bidx = (w * 3 + it) * 64 + lane;      // 16B-block index in K tile
        int row  = bidx / 24;
        int sblk = bidx - row * 24;
        int gblk = sblk ^ (row & 7);
        koff[it] = row * KW + gblk * 8;
    }
#pragma unroll
    for (int it = 0; it < 2; ++it) {
        int bidx = (w * 2 + it) * 64 + lane;      // 16B-block index in V tile
        int row  = bidx >> 2;
        int gblk = (bidx & 3) ^ ((row >> 1) & 3);
        voff[it] = row * NTOK + gblk * 8;
    }
    const unsigned short* kp0 = kb + (size_t)(b * SEQ) * KW + kvh * D_QKD;
    const unsigned short* vp0 = vt + (size_t)(kvh * 128) * NTOK + b * SEQ;

    const int q0   = qt * 64;
    const int q0w  = q0 + w * 16;
    const int wmax = q0w + 15;

    bf16x8 qf[6];
    {
        const unsigned short* qp =
            qkvb + (size_t)(b * SEQ + q0w + l15) * QKV_W + h * D_QKD + quad * 8;
#pragma unroll
        for (int t = 0; t < 6; ++t)
            qf[t] = __builtin_bit_cast(bf16x8, *(const uint4*)(qp + t * 32));
    }

    f32x4 o[8];
#pragma unroll
    for (int c = 0; c < 8; ++c) o[c] = (f32x4){0.f, 0.f, 0.f, 0.f};
    float lp = 0.f;     // partial l for q-row l15 over this lane's k-slots

    const int nt = 2 * qt + 2;

    {
#pragma unroll
        for (int it = 0; it < 3; ++it)
            gl2lds16(kp0 + koff[it], KsL + (w * 3 + it) * 512);
#pragma unroll
        for (int it = 0; it < 2; ++it)
            gl2lds16(vp0 + voff[it], VtL + (w * 2 + it) * 512);
    }
    __syncthreads();   // vmcnt drain: tile 0 staged

    for (int tk = 0; tk < nt; ++tk) {
        const int k0  = tk * 32;
        const int cur = tk & 1;

        if (tk + 1 < nt) {
            const int nxt = cur ^ 1;
            const unsigned short* ks = kp0 + (size_t)(k0 + 32) * KW;
            const unsigned short* vs = vp0 + (k0 + 32);
#pragma unroll
            for (int it = 0; it < 3; ++it)
                gl2lds16(ks + koff[it], KsL + nxt * (32 * 192) + (w * 3 + it) * 512);
#pragma unroll
            for (int it = 0; it < 2; ++it)
                gl2lds16(vs + voff[it], VtL + nxt * (128 * 32) + (w * 2 + it) * 512);
        }

        if (k0 <= wmax) {
            const unsigned short* Kc = KsL + cur * (32 * 192);
            const unsigned short* Vc = VtL + cur * (128 * 32);

            // ---- scores: S^T[32k][16q] = K @ Q^T (log2 domain), swapped ----
            f32x4 s[2];
#pragma unroll
            for (int j = 0; j < 2; ++j) {
                f32x4 acc = {0.f, 0.f, 0.f, 0.f};
                const unsigned short* kr = Kc + (j * 16 + l15) * 192;
#pragma unroll
                for (int t = 0; t < 6; ++t) {
                    int sblk = (quad + 4 * t) ^ x7;
                    bf16x8 kf = __builtin_bit_cast(bf16x8, *(const uint4*)(kr + sblk * 8));
                    acc = __builtin_amdgcn_mfma_f32_16x16x32_bf16(kf, qf[t], acc, 0, 0, 0);
                }
                s[j] = acc;
            }

            // ---- softmax, fixed m=0, exp2; causal mask; per-lane l ----
            const int qrow = q0w + l15;
#pragma unroll
            for (int j = 0; j < 2; ++j)
#pragma unroll
                for (int i = 0; i < 4; ++i) {
                    int kidx = k0 + j * 16 + quad * 4 + i;
                    float p = (kidx <= qrow) ? __builtin_amdgcn_exp2f(s[j][i]) : 0.f;
                    s[j][i] = p;
                    lp += p;
                }

            // ---- P -> A-frag: pure in-register pack (k-permuted V) ----
            uint4 pk;
            pk.x = (unsigned int)f2bf(s[0][0]) | ((unsigned int)f2bf(s[0][1]) << 16);
            pk.y = (unsigned int)f2bf(s[0][2]) | ((unsigned int)f2bf(s[0][3]) << 16);
            pk.z = (unsigned int)f2bf(s[1][0]) | ((unsigned int)f2bf(s[1][1]) << 16);
            pk.w = (unsigned int)f2bf(s[1][2]) | ((unsigned int)f2bf(s[1][3]) << 16);
            bf16x8 pa = __builtin_bit_cast(bf16x8, pk);

            // ---- PV: 8 MFMAs, swizzled V frags ----
#pragma unroll
            for (int c = 0; c < 8; ++c) {
                bf16x8 vf = __builtin_bit_cast(bf16x8,
                    *(const uint4*)(Vc + (c * 16 + l15) * 32 + ((quad ^ vx) * 8)));
                o[c] = __builtin_amdgcn_mfma_f32_16x16x32_bf16(pa, vf, o[c], 0, 0, 0);
            }
        }

        __syncthreads();   // waves done with buf cur; DMA for tk+1 drained
    }

    // ---- epilogue: total l per q-row, redistribute to C-layout rows ----
    float lt = lp;
    lt += __shfl_xor(lt, 16);
    lt += __shfl_xor(lt, 32);      // all lanes: l for q-row = their l15

#pragma unroll
    for (int i = 0; i < 4; ++i) {
        float inv = 1.0f / __shfl(lt, (lane & 48) | (quad * 4 + i));
        size_t rowoff = (size_t)(b * SEQ + q0w + quad * 4 + i) * AW + h * D_VV + l15;
#pragma unroll
        for (int c = 0; c < 8; ++c)
            attnb[rowoff + c * 16] = f2bf(o[c][i] * inv);
    }
}

// ---------------------------------------------------------------------------
extern "C" void kernel_launch(void* const* d_in, const int* in_sizes, int n_in,
                              void* d_out, int out_size, void* d_ws, size_t ws_size,
                              hipStream_t stream)
{
    const float* X     = (const float*)d_in[0];
    const float* Wqkv  = (const float*)d_in[1];
    const float* Wk_up = (const float*)d_in[2];
    const float* Wv_up = (const float*)d_in[3];
    const float* Wo    = (const float*)d_in[4];
    float* out = (float*)d_out;

    unsigned short* Xb    = (unsigned short*)d_ws;                   // [4096][2048]
    unsigned short* Wqt   = Xb    + (size_t)NTOK * HIDN;             // [3584][2048]
    unsigned short* Wkt   = Wqt   + (size_t)QKV_W * HIDN;            // [768][512]
    unsigned short* Wvt   = Wkt   + (size_t)KW * LORA;               // [512][512]
    unsigned short* Wot   = Wvt   + (size_t)VW * LORA;               // [2048][2048]
    unsigned short* qkvb  = Wot   + (size_t)HIDN * AW;               // [4096][3584]
    unsigned short* kb    = qkvb  + (size_t)NTOK * QKV_W;            // [4096][768]
    unsigned short* vtb   = kb    + (size_t)NTOK * KW;               // [512][4096] (V^T, k-permuted)
    unsigned short* attnb = vtb   + (size_t)VW * NTOK;               // [4096][2048]

    cast_plain<<<NTOK * HIDN / 4 / 256, 256, 0, stream>>>(X, Xb);
    // q columns pre-scaled by (1/sqrt(192)) * log2(e): softmax runs in exp2 domain
    transpose_w<<<dim3(QKV_W / 64, HIDN / 64), 256, 0, stream>>>(
        Wqkv, Wqt, HIDN, QKV_W, NH * D_QKD, QSCALE * LOG2E);
    transpose_w<<<dim3(KW / 64, LORA / 64), 256, 0, stream>>>(Wk_up, Wkt, LORA, KW, 0, 1.0f);
    transpose_w<<<dim3(VW / 64, LORA / 64), 256, 0, stream>>>(Wv_up, Wvt, LORA, VW, 0, 1.0f);
    transpose_w<<<dim3(AW / 64, HIDN / 64), 256, 0, stream>>>(Wo, Wot, HIDN, AW, 0, 1.0f);

    // qkvb = Xb @ Wqt^T (bf16; q cols pre-scaled) — 8-phase 256x256
    gemm8p<1, 256><<<dim3(QKV_W / 256, NTOK / 256), 512, 131072, stream>>>(
        Xb, Wqt, qkvb, HIDN, HIDN, HIDN, QKV_W);

    // kb = c_kv @ Wkt^T (bf16) ; vt = (c_kv @ Wvt^T)^T (bf16, k-permuted cols)
    gemm_bt<1><<<dim3(KW / 128, NTOK / 128), 256, 0, stream>>>(
        qkvb + NH * D_QKD, Wkt, kb, LORA, QKV_W, LORA, KW);
    gemm_bt<2><<<dim3(VW / 128, NTOK / 128), 256, 0, stream>>>(
        qkvb + NH * D_QKD, Wvt, vtb, LORA, QKV_W, LORA, NTOK);

    rope_bf16<<<(NTOK * 20 * 32 + 255) / 256, 256, 0, stream>>>(qkvb, kb);

    attn_mfma<<<dim3(1024), 256, 0, stream>>>(qkvb, kb, vtb, attnb);

    // out = attnb @ Wot^T (fp32) — 8-phase 256x128 (grid 256 = full CU fill)
    gemm8p<0, 128><<<dim3(HIDN / 128, NTOK / 256), 512, 98304, stream>>>(
        attnb, Wot, out, AW, AW, AW, HIDN);
}

// Round 4
// 349.745 us; speedup vs baseline: 1.3592x; 1.0061x over previous
//
#include <hip/hip_runtime.h>
#include <hip/hip_bf16.h>
#include <math.h>

#define HIDN  2048
#define NH    16
#define NKV   4
#define LORA  512
#define D_ROPE 64
#define D_NOPE 128
#define D_VV  128
#define D_QKD 192
#define BATCH 2
#define SEQ   2048
#define NTOK  (BATCH*SEQ)          // 4096
#define QKV_W (NH*D_QKD + LORA)    // 3584
#define KW    (NKV*D_QKD)          // 768
#define VW    (NKV*D_VV)           // 512
#define AW    (NH*D_VV)            // 2048
#define QSCALE 0.07216878364870323f   // 1/sqrt(192)
#define LOG2E  1.4426950408889634f

typedef __attribute__((ext_vector_type(8))) __bf16 bf16x8;
typedef __attribute__((ext_vector_type(4))) float f32x4;

static __device__ __forceinline__ unsigned short f2bf(float f) {
    unsigned int u = __builtin_bit_cast(unsigned int, f);
    u += 0x7fffu + ((u >> 16) & 1u);          // round-to-nearest-even
    return (unsigned short)(u >> 16);
}
static __device__ __forceinline__ float bf2f(unsigned short v) {
    unsigned int u = (unsigned int)v << 16;
    return __builtin_bit_cast(float, u);
}
static __device__ __forceinline__ unsigned int cvt_pk_bf16(float lo, float hi) {
    unsigned int r;
    asm("v_cvt_pk_bf16_f32 %0, %1, %2" : "=v"(r) : "v"(lo), "v"(hi));
    return r;
}
static __device__ __forceinline__ void gl2lds16(const unsigned short* g, unsigned short* l) {
    __builtin_amdgcn_global_load_lds(
        (const __attribute__((address_space(1))) unsigned int*)g,
        (__attribute__((address_space(3))) unsigned int*)l, 16, 0, 0);
}

// ---------------------------------------------------------------------------
// Transpose + cast: W fp32 [K][N] -> Wt bf16 [N][K]; optional column scale.
// ---------------------------------------------------------------------------
__global__ __launch_bounds__(256) void transpose_w(
    const float* __restrict__ W, unsigned short* __restrict__ Wt,
    int K, int N, int scale_ncols, float scale)
{
    __shared__ float T[64][68];
    const int tid = threadIdx.x;
    const int k0 = blockIdx.y * 64, n0 = blockIdx.x * 64;
    const int rr = tid >> 4;
    const int c4 = (tid & 15) * 4;

#pragma unroll
    for (int i = 0; i < 4; ++i) {
        int r = rr + 16 * i;
        *(float4*)&T[r][c4] = *(const float4*)&W[(size_t)(k0 + r) * N + n0 + c4];
    }
    __syncthreads();
#pragma unroll
    for (int i = 0; i < 4; ++i) {
        int nr = rr + 16 * i;
        float sc = (n0 + nr < scale_ncols) ? scale : 1.0f;
        unsigned short tmp[4];
#pragma unroll
        for (int j = 0; j < 4; ++j) tmp[j] = f2bf(T[c4 + j][nr] * sc);
        unsigned int p0 = (unsigned int)tmp[0] | ((unsigned int)tmp[1] << 16);
        unsigned int p1 = (unsigned int)tmp[2] | ((unsigned int)tmp[3] << 16);
        *(uint2*)&Wt[(size_t)(n0 + nr) * K + k0 + c4] = make_uint2(p0, p1);
    }
}

__global__ __launch_bounds__(256) void cast_plain(const float* __restrict__ src,
                                                  unsigned short* __restrict__ dst)
{
    int idx = blockIdx.x * 256 + threadIdx.x;
    float4 v = *(const float4*)&src[(size_t)idx * 4];
    unsigned int p0 = (unsigned int)f2bf(v.x) | ((unsigned int)f2bf(v.y) << 16);
    unsigned int p1 = (unsigned int)f2bf(v.z) | ((unsigned int)f2bf(v.w) << 16);
    *(uint2*)&dst[(size_t)idx * 4] = make_uint2(p0, p1);
}

// ---------------------------------------------------------------------------
// bf16 MFMA GEMM (m97 structure, 128x128): kept for the small K=512 GEMMs.
// OUT_MODE: 1 = bf16 C[M][N],
//           2 = bf16 transposed Ct[N][M] with k-interleave permutation on M
//               within each 32-row group (attn's in-register P A-frag).
// ---------------------------------------------------------------------------
template<int OUT_MODE>
__global__ __launch_bounds__(256) void gemm_bt(
    const unsigned short* __restrict__ A,
    const unsigned short* __restrict__ Bt,
    void* __restrict__ C,
    int K, int lda, int ldb, int ldc)
{
    __shared__ __align__(16) unsigned short As[128 * 32];
    __shared__ __align__(16) unsigned short Bs[128 * 32];

    const int tid  = threadIdx.x;
    const int w    = tid >> 6;
    const int lane = tid & 63;
    const int quad = lane >> 4;
    const int l15  = lane & 15;
    const int brow = blockIdx.y * 128;
    const int bcol = blockIdx.x * 128;
    const int wr   = (w >> 1) * 64;
    const int wc   = (w & 1) * 64;

    const int srow = lane >> 2;
    const int sseg = (lane & 3) * 8;
    const int r0   = w * 32;

    f32x4 acc[4][4];
#pragma unroll
    for (int mt = 0; mt < 4; ++mt)
#pragma unroll
        for (int nt = 0; nt < 4; ++nt) acc[mt][nt] = (f32x4){0.f, 0.f, 0.f, 0.f};

    const unsigned short* Ab = A  + (size_t)(brow + r0 + srow) * lda + sseg;
    const unsigned short* Bb = Bt + (size_t)(bcol + r0 + srow) * ldb + sseg;

    for (int k0 = 0; k0 < K; k0 += 32) {
        __syncthreads();
        gl2lds16(Ab + k0,                     As + r0 * 32);
        gl2lds16(Ab + k0 + (size_t)16 * lda,  As + (r0 + 16) * 32);
        gl2lds16(Bb + k0,                     Bs + r0 * 32);
        gl2lds16(Bb + k0 + (size_t)16 * ldb,  Bs + (r0 + 16) * 32);
        __syncthreads();

        bf16x8 af[4], bfr[4];
#pragma unroll
        for (int mt = 0; mt < 4; ++mt)
            af[mt] = __builtin_bit_cast(bf16x8,
                *(const uint4*)(As + (wr + mt * 16 + l15) * 32 + quad * 8));
#pragma unroll
        for (int nt = 0; nt < 4; ++nt)
            bfr[nt] = __builtin_bit_cast(bf16x8,
                *(const uint4*)(Bs + (wc + nt * 16 + l15) * 32 + quad * 8));
#pragma unroll
        for (int mt = 0; mt < 4; ++mt)
#pragma unroll
            for (int nt = 0; nt < 4; ++nt)
                acc[mt][nt] = __builtin_amdgcn_mfma_f32_16x16x32_bf16(
                    af[mt], bfr[nt], acc[mt][nt], 0, 0, 0);
    }

    if (OUT_MODE == 2) {
#pragma unroll
        for (int mt = 0; mt < 4; ++mt) {
            int row0 = brow + wr + mt * 16 + quad * 4;   // token base, %4 == 0
            int r5   = row0 & 31;
            int pos  = ((r5 & 15) >> 2) * 8 + ((r5 >> 4) << 2);
            int prow0 = (row0 & ~31) | pos;              // k-interleave permute
#pragma unroll
            for (int nt = 0; nt < 4; ++nt) {
                int col = bcol + wc + nt * 16 + l15;
                unsigned int p0 = (unsigned int)f2bf(acc[mt][nt][0]) |
                                  ((unsigned int)f2bf(acc[mt][nt][1]) << 16);
                unsigned int p1 = (unsigned int)f2bf(acc[mt][nt][2]) |
                                  ((unsigned int)f2bf(acc[mt][nt][3]) << 16);
                *(uint2*)&((unsigned short*)C)[(size_t)col * ldc + prow0] = make_uint2(p0, p1);
            }
        }
    } else {
#pragma unroll
        for (int mt = 0; mt < 4; ++mt)
#pragma unroll
            for (int i = 0; i < 4; ++i) {
                size_t row = (size_t)(brow + wr + mt * 16 + quad * 4 + i);
#pragma unroll
                for (int nt = 0; nt < 4; ++nt) {
                    int col = bcol + wc + nt * 16 + l15;
                    ((unsigned short*)C)[row * ldc + col] = f2bf(acc[mt][nt][i]);
                }
            }
    }
}

// ---------------------------------------------------------------------------
// 8-phase 256-wide GEMM (T2+T3+T4+T5): C = A[M,K] @ Bt[N,K]^T.
// See R3 notes. OUT_MODE: 0 = fp32 C, 1 = bf16 C.
// ---------------------------------------------------------------------------
template<int OUT_MODE, int BN>
__global__ __launch_bounds__(512, 2) void gemm8p(
    const unsigned short* __restrict__ A,
    const unsigned short* __restrict__ Bt,
    void* __restrict__ C,
    int K, int lda, int ldb, int ldc)
{
    constexpr int BNF    = BN / 64;        // n-frags per wave (4 or 2)
    constexpr int LB     = BN / 64;        // B chunk-loads per thread
    constexpr int NLOADS = 4 + LB;         // staging loads per thread per tile
    constexpr int ASLOT  = 256 * 64;       // shorts
    constexpr int BSLOT  = BN * 64;
    constexpr int SLOT   = ASLOT + BSLOT;

    extern __shared__ __align__(16) unsigned short lds[];

    const int tid  = threadIdx.x;
    const int w    = tid >> 6;
    const int lane = tid & 63;
    const int quad = lane >> 4;
    const int l15  = lane & 15;
    const int wm   = w >> 2;               // 0..1
    const int wn   = w & 3;                // 0..3

    // XCD-aware bijective swizzle (caller guarantees nwg % 8 == 0)
    int fid = blockIdx.y * gridDim.x + blockIdx.x;
    int nwg = gridDim.x * gridDim.y;
    int cpx = nwg >> 3;
    int swz = (fid & 7) * cpx + (fid >> 3);
    int bx  = swz % gridDim.x;
    int by  = swz / gridDim.x;
    const int brow = by * 256;
    const int bcol = bx * BN;

    // staging source offsets: LDS chunk (row, c) <- global colblk c ^ (row&7)
    int aoff[4], boff[LB];
#pragma unroll
    for (int i = 0; i < 4; ++i) {
        int chunk = (w * 4 + i) * 64 + lane;      // 0..2047
        int row = chunk >> 3, c = chunk & 7;
        aoff[i] = row * lda + (c ^ (row & 7)) * 8;
    }
#pragma unroll
    for (int i = 0; i < LB; ++i) {
        int chunk = (w * LB + i) * 64 + lane;
        int row = chunk >> 3, c = chunk & 7;
        boff[i] = row * ldb + (c ^ (row & 7)) * 8;
    }
    const unsigned short* Ab = A  + (size_t)brow * lda;
    const unsigned short* Bb = Bt + (size_t)bcol * ldb;

    f32x4 acc[8][BNF];
#pragma unroll
    for (int mf = 0; mf < 8; ++mf)
#pragma unroll
        for (int nf = 0; nf < BNF; ++nf) acc[mf][nf] = (f32x4){0.f, 0.f, 0.f, 0.f};

    const int NT = K >> 6;

    auto stage = [&](int slot, int k0) {
        unsigned short* As = lds + slot * SLOT;
        unsigned short* Bs = As + ASLOT;
#pragma unroll
        for (int i = 0; i < 4; ++i)
            gl2lds16(Ab + k0 + aoff[i], As + (w * 4 + i) * 512);
#pragma unroll
        for (int i = 0; i < LB; ++i)
            gl2lds16(Bb + k0 + boff[i], Bs + (w * LB + i) * 512);
    };

    // prologue: T0 -> slot0, T1 -> slot1; wait T0 only (T1 stays in flight)
    stage(0, 0);
    stage(1, 64);
    if constexpr (NLOADS == 8) asm volatile("s_waitcnt vmcnt(8)" ::: "memory");
    else                       asm volatile("s_waitcnt vmcnt(6)" ::: "memory");
    __builtin_amdgcn_s_barrier();
    __builtin_amdgcn_sched_barrier(0);

#pragma unroll 1
    for (int t = 0; t < NT; ++t) {
        const unsigned short* As = lds + (t & 1) * SLOT;
        const unsigned short* Bs = As + ASLOT;
        bf16x8 bq[BNF][2];

#pragma unroll
        for (int ph = 0; ph < 4; ++ph) {
            if (ph == 0) {
#pragma unroll
                for (int nf = 0; nf < BNF; ++nf)
#pragma unroll
                    for (int kk = 0; kk < 2; ++kk) {
                        int r = wn * (BN / 4) + nf * 16 + l15;
                        bq[nf][kk] = __builtin_bit_cast(bf16x8,
                            *(const uint4*)(Bs + r * 64 + (((kk * 4 + quad) ^ (r & 7)) * 8)));
                    }
            }
            bf16x8 af[2][2];
#pragma unroll
            for (int m = 0; m < 2; ++m)
#pragma unroll
                for (int kk = 0; kk < 2; ++kk) {
                    int r = wm * 128 + (ph * 2 + m) * 16 + l15;
                    af[m][kk] = __builtin_bit_cast(bf16x8,
                        *(const uint4*)(As + r * 64 + (((kk * 4 + quad) ^ (r & 7)) * 8)));
                }
            __builtin_amdgcn_s_barrier();
            __builtin_amdgcn_s_setprio(1);
#pragma unroll
            for (int m = 0; m < 2; ++m)
#pragma unroll
                for (int nf = 0; nf < BNF; ++nf)
#pragma unroll
                    for (int kk = 0; kk < 2; ++kk)
                        acc[ph * 2 + m][nf] = __builtin_amdgcn_mfma_f32_16x16x32_bf16(
                            af[m][kk], bq[nf][kk], acc[ph * 2 + m][nf], 0, 0, 0);
            __builtin_amdgcn_s_setprio(0);
            __builtin_amdgcn_s_barrier();
        }

        // tile boundary: slot (t&1) free -> burst-stage T(t+2) into it
        if (t + 2 < NT) {
            stage(t & 1, (t + 2) * 64);
            if constexpr (NLOADS == 8) asm volatile("s_waitcnt vmcnt(8)" ::: "memory");
            else                       asm volatile("s_waitcnt vmcnt(6)" ::: "memory");
            __builtin_amdgcn_s_barrier();
            __builtin_amdgcn_sched_barrier(0);
        } else if (t + 1 < NT) {
            asm volatile("s_waitcnt vmcnt(0)" ::: "memory");   // epilogue drain
            __builtin_amdgcn_s_barrier();
            __builtin_amdgcn_sched_barrier(0);
        }
    }

    // epilogue: per-wave 128 x BN/4 C-write
#pragma unroll
    for (int mf = 0; mf < 8; ++mf) {
#pragma unroll
        for (int i = 0; i < 4; ++i) {
            size_t row = (size_t)(brow + wm * 128 + mf * 16 + quad * 4 + i);
#pragma unroll
            for (int nf = 0; nf < BNF; ++nf) {
                int col = bcol + wn * (BN / 4) + nf * 16 + l15;
                if (OUT_MODE == 1)
                    ((unsigned short*)C)[row * ldc + col] = f2bf(acc[mf][nf][i]);
                else
                    ((float*)C)[row * ldc + col] = acc[mf][nf][i];
            }
        }
    }
}

// ---------------------------------------------------------------------------
// RoPE in-place on bf16 q (inside qkvb) and bf16 k (kb).
// ---------------------------------------------------------------------------
__global__ __launch_bounds__(256) void rope_bf16(unsigned short* __restrict__ qkvb,
                                                 unsigned short* __restrict__ kb)
{
    int idx = blockIdx.x * 256 + threadIdx.x;
    int i    = idx & 31;
    int head = (idx >> 5) % 20;
    int t    = idx / (20 * 32);
    if (t >= NTOK) return;
    int pos = t & (SEQ - 1);

    const float LOG_BASE_OVER_32 = 0.28782313662425572f; // ln(10000)/32
    float ang = (float)pos * __expf(-(float)i * LOG_BASE_OVER_32);
    float c = cosf(ang);
    float sn = sinf(ang);

    unsigned short* p;
    if (head < NH) p = qkvb + (size_t)t * QKV_W + head * D_QKD + D_NOPE;
    else           p = kb   + (size_t)t * KW    + (head - NH) * D_QKD + D_NOPE;

    float x1 = bf2f(p[i]), x2 = bf2f(p[i + 32]);
    p[i]      = f2bf(x1 * c - x2 * sn);
    p[i + 32] = f2bf(x2 * c + x1 * sn);
}

// ---------------------------------------------------------------------------
// MFMA flash attention, causal, GQA. Fixed m=0 softmax in exp2 domain.
// In-register P via swapped QK^T + k-permuted V (see R2 notes). 40 KB LDS,
// 4 blocks/CU: 1024-block grid fully co-resident; balanced qt mapping.
// R4: wave-uniform causal-mask skip (mask active on exactly 1 tile/wave),
//     v_cvt_pk_bf16_f32 P-pack (4 HW packs replace ~28 VALU ops),
//     s_setprio(1) around MFMA clusters (T5).
// ---------------------------------------------------------------------------
__global__ __launch_bounds__(256) void attn_mfma(
    const unsigned short* __restrict__ qkvb,
    const unsigned short* __restrict__ kb,
    const unsigned short* __restrict__ vt,
    unsigned short* __restrict__ attnb)
{
    __shared__ __align__(16) unsigned short KsL[2 * 32 * 192];  // 2 x 12 KB
    __shared__ __align__(16) unsigned short VtL[2 * 128 * 32];  // 2 x 8 KB

    const int tid  = threadIdx.x;
    const int w    = tid >> 6;
    const int lane = tid & 63;
    const int quad = lane >> 4;
    const int l15  = lane & 15;

    const int bid = blockIdx.x;
    const int g   = bid >> 5;
    const int jj  = g & 7;
    const int m   = g >> 3;
    int qt;
    if      (m == 0) qt = 31 - jj;
    else if (m == 1) qt = 16 + jj;
    else if (m == 2) qt = 15 - jj;
    else             qt = jj;
    const int hb = bid & 31;
    const int h  = hb & 15;
    const int b  = hb >> 4;
    const int kvh = h >> 2;

    const int x7   = l15 & 7;             // K read swizzle
    const int vx   = (l15 >> 1) & 3;      // V read swizzle

    int koff[3], voff[2];
#pragma unroll
    for (int it = 0; it < 3; ++it) {
        int bidx = (w * 3 + it) * 64 + lane;      // 16B-block index in K tile
        int row  = bidx / 24;
        int sblk = bidx - row * 24;
        int gblk = sblk ^ (row & 7);
        koff[it] = row * KW + gblk * 8;
    }
#pragma unroll
    for (int it = 0; it < 2; ++it) {
        int bidx = (w * 2 + it) * 64 + lane;      // 16B-block index in V tile
        int row  = bidx >> 2;
        int gblk = (bidx & 3) ^ ((row >> 1) & 3);
        voff[it] = row * NTOK + gblk * 8;
    }
    const unsigned short* kp0 = kb + (size_t)(b * SEQ) * KW + kvh * D_QKD;
    const unsigned short* vp0 = vt + (size_t)(kvh * 128) * NTOK + b * SEQ;

    const int q0   = qt * 64;
    const int q0w  = q0 + w * 16;
    const int wmax = q0w + 15;

    bf16x8 qf[6];
    {
        const unsigned short* qp =
            qkvb + (size_t)(b * SEQ + q0w + l15) * QKV_W + h * D_QKD + quad * 8;
#pragma unroll
        for (int t = 0; t < 6; ++t)
            qf[t] = __builtin_bit_cast(bf16x8, *(const uint4*)(qp + t * 32));
    }

    f32x4 o[8];
#pragma unroll
    for (int c = 0; c < 8; ++c) o[c] = (f32x4){0.f, 0.f, 0.f, 0.f};
    float lp = 0.f;     // partial l for q-row l15 over this lane's k-slots

    const int nt = 2 * qt + 2;

    {
#pragma unroll
        for (int it = 0; it < 3; ++it)
            gl2lds16(kp0 + koff[it], KsL + (w * 3 + it) * 512);
#pragma unroll
        for (int it = 0; it < 2; ++it)
            gl2lds16(vp0 + voff[it], VtL + (w * 2 + it) * 512);
    }
    __syncthreads();   // vmcnt drain: tile 0 staged

    for (int tk = 0; tk < nt; ++tk) {
        const int k0  = tk * 32;
        const int cur = tk & 1;

        if (tk + 1 < nt) {
            const int nxt = cur ^ 1;
            const unsigned short* ks = kp0 + (size_t)(k0 + 32) * KW;
            const unsigned short* vs = vp0 + (k0 + 32);
#pragma unroll
            for (int it = 0; it < 3; ++it)
                gl2lds16(ks + koff[it], KsL + nxt * (32 * 192) + (w * 3 + it) * 512);
#pragma unroll
            for (int it = 0; it < 2; ++it)
                gl2lds16(vs + voff[it], VtL + nxt * (128 * 32) + (w * 2 + it) * 512);
        }

        if (k0 <= wmax) {
            const unsigned short* Kc = KsL + cur * (32 * 192);
            const unsigned short* Vc = VtL + cur * (128 * 32);

            // ---- scores: S^T[32k][16q] = K @ Q^T (log2 domain), swapped ----
            f32x4 s[2];
            __builtin_amdgcn_s_setprio(1);
#pragma unroll
            for (int j = 0; j < 2; ++j) {
                f32x4 acc = {0.f, 0.f, 0.f, 0.f};
                const unsigned short* kr = Kc + (j * 16 + l15) * 192;
#pragma unroll
                for (int t = 0; t < 6; ++t) {
                    int sblk = (quad + 4 * t) ^ x7;
                    bf16x8 kf = __builtin_bit_cast(bf16x8, *(const uint4*)(kr + sblk * 8));
                    acc = __builtin_amdgcn_mfma_f32_16x16x32_bf16(kf, qf[t], acc, 0, 0, 0);
                }
                s[j] = acc;
            }
            __builtin_amdgcn_s_setprio(0);
            // lane holds S[q = l15][k = k0 + j*16 + quad*4 + i]

            // ---- softmax, fixed m=0, exp2; wave-uniform mask skip ----
            if (k0 + 31 <= q0w) {
                // fully unmasked tile (vast majority)
#pragma unroll
                for (int j = 0; j < 2; ++j)
#pragma unroll
                    for (int i = 0; i < 4; ++i) {
                        float p = __builtin_amdgcn_exp2f(s[j][i]);
                        s[j][i] = p;
                        lp += p;
                    }
            } else {
                // diagonal tile: causal mask active (exactly 1 per wave)
                const int qrow = q0w + l15;
#pragma unroll
                for (int j = 0; j < 2; ++j)
#pragma unroll
                    for (int i = 0; i < 4; ++i) {
                        int kidx = k0 + j * 16 + quad * 4 + i;
                        float p = (kidx <= qrow) ? __builtin_amdgcn_exp2f(s[j][i]) : 0.f;
                        s[j][i] = p;
                        lp += p;
                    }
            }

            // ---- P -> A-frag: HW pack, pure in-register (k-permuted V) ----
            uint4 pk;
            pk.x = cvt_pk_bf16(s[0][0], s[0][1]);
            pk.y = cvt_pk_bf16(s[0][2], s[0][3]);
            pk.z = cvt_pk_bf16(s[1][0], s[1][1]);
            pk.w = cvt_pk_bf16(s[1][2], s[1][3]);
            bf16x8 pa = __builtin_bit_cast(bf16x8, pk);

            // ---- PV: 8 MFMAs, swizzled V frags ----
            __builtin_amdgcn_s_setprio(1);
#pragma unroll
            for (int c = 0; c < 8; ++c) {
                bf16x8 vf = __builtin_bit_cast(bf16x8,
                    *(const uint4*)(Vc + (c * 16 + l15) * 32 + ((quad ^ vx) * 8)));
                o[c] = __builtin_amdgcn_mfma_f32_16x16x32_bf16(pa, vf, o[c], 0, 0, 0);
            }
            __builtin_amdgcn_s_setprio(0);
        }

        __syncthreads();   // waves done with buf cur; DMA for tk+1 drained
    }

    // ---- epilogue: total l per q-row, redistribute to C-layout rows ----
    float lt = lp;
    lt += __shfl_xor(lt, 16);
    lt += __shfl_xor(lt, 32);      // all lanes: l for q-row = their l15

#pragma unroll
    for (int i = 0; i < 4; ++i) {
        float inv = 1.0f / __shfl(lt, (lane & 48) | (quad * 4 + i));
        size_t rowoff = (size_t)(b * SEQ + q0w + quad * 4 + i) * AW + h * D_VV + l15;
#pragma unroll
        for (int c = 0; c < 8; ++c)
            attnb[rowoff + c * 16] = f2bf(o[c][i] * inv);
    }
}

// ---------------------------------------------------------------------------
extern "C" void kernel_launch(void* const* d_in, const int* in_sizes, int n_in,
                              void* d_out, int out_size, void* d_ws, size_t ws_size,
                              hipStream_t stream)
{
    const float* X     = (const float*)d_in[0];
    const float* Wqkv  = (const float*)d_in[1];
    const float* Wk_up = (const float*)d_in[2];
    const float* Wv_up = (const float*)d_in[3];
    const float* Wo    = (const float*)d_in[4];
    float* out = (float*)d_out;

    unsigned short* Xb    = (unsigned short*)d_ws;                   // [4096][2048]
    unsigned short* Wqt   = Xb    + (size_t)NTOK * HIDN;             // [3584][2048]
    unsigned short* Wkt   = Wqt   + (size_t)QKV_W * HIDN;            // [768][512]
    unsigned short* Wvt   = Wkt   + (size_t)KW * LORA;               // [512][512]
    unsigned short* Wot   = Wvt   + (size_t)VW * LORA;               // [2048][2048]
    unsigned short* qkvb  = Wot   + (size_t)HIDN * AW;               // [4096][3584]
    unsigned short* kb    = qkvb  + (size_t)NTOK * QKV_W;            // [4096][768]
    unsigned short* vtb   = kb    + (size_t)NTOK * KW;               // [512][4096] (V^T, k-permuted)
    unsigned short* attnb = vtb   + (size_t)VW * NTOK;               // [4096][2048]

    cast_plain<<<NTOK * HIDN / 4 / 256, 256, 0, stream>>>(X, Xb);
    // q columns pre-scaled by (1/sqrt(192)) * log2(e): softmax runs in exp2 domain
    transpose_w<<<dim3(QKV_W / 64, HIDN / 64), 256, 0, stream>>>(
        Wqkv, Wqt, HIDN, QKV_W, NH * D_QKD, QSCALE * LOG2E);
    transpose_w<<<dim3(KW / 64, LORA / 64), 256, 0, stream>>>(Wk_up, Wkt, LORA, KW, 0, 1.0f);
    transpose_w<<<dim3(VW / 64, LORA / 64), 256, 0, stream>>>(Wv_up, Wvt, LORA, VW, 0, 1.0f);
    transpose_w<<<dim3(AW / 64, HIDN / 64), 256, 0, stream>>>(Wo, Wot, HIDN, AW, 0, 1.0f);

    // qkvb = Xb @ Wqt^T (bf16; q cols pre-scaled) — 8-phase 256x256
    gemm8p<1, 256><<<dim3(QKV_W / 256, NTOK / 256), 512, 131072, stream>>>(
        Xb, Wqt, qkvb, HIDN, HIDN, HIDN, QKV_W);

    // kb = c_kv @ Wkt^T (bf16) ; vt = (c_kv @ Wvt^T)^T (bf16, k-permuted cols)
    gemm_bt<1><<<dim3(KW / 128, NTOK / 128), 256, 0, stream>>>(
        qkvb + NH * D_QKD, Wkt, kb, LORA, QKV_W, LORA, KW);
    gemm_bt<2><<<dim3(VW / 128, NTOK / 128), 256, 0, stream>>>(
        qkvb + NH * D_QKD, Wvt, vtb, LORA, QKV_W, LORA, NTOK);

    rope_bf16<<<(NTOK * 20 * 32 + 255) / 256, 256, 0, stream>>>(qkvb, kb);

    attn_mfma<<<dim3(1024), 256, 0, stream>>>(qkvb, kb, vtb, attnb);

    // out = attnb @ Wot^T (fp32) — 8-phase 256x128 (grid 256 = full CU fill)
    gemm8p<0, 128><<<dim3(HIDN / 128, NTOK / 256), 512, 98304, stream>>>(
        attnb, Wot, out, AW, AW, AW, HIDN);
}

// Round 5
// 336.126 us; speedup vs baseline: 1.4142x; 1.0405x over previous
//
#include <hip/hip_runtime.h>
#include <hip/hip_bf16.h>
#include <math.h>

#define HIDN  2048
#define NH    16
#define NKV   4
#define LORA  512
#define D_ROPE 64
#define D_NOPE 128
#define D_VV  128
#define D_QKD 192
#define BATCH 2
#define SEQ   2048
#define NTOK  (BATCH*SEQ)          // 4096
#define QKV_W (NH*D_QKD + LORA)    // 3584
#define KW    (NKV*D_QKD)          // 768
#define VW    (NKV*D_VV)           // 512
#define AW    (NH*D_VV)            // 2048
#define QSCALE 0.07216878364870323f   // 1/sqrt(192)
#define LOG2E  1.4426950408889634f

typedef __attribute__((ext_vector_type(8))) __bf16 bf16x8;
typedef __attribute__((ext_vector_type(4))) float f32x4;

static __device__ __forceinline__ unsigned short f2bf(float f) {
    unsigned int u = __builtin_bit_cast(unsigned int, f);
    u += 0x7fffu + ((u >> 16) & 1u);          // round-to-nearest-even
    return (unsigned short)(u >> 16);
}
static __device__ __forceinline__ float bf2f(unsigned short v) {
    unsigned int u = (unsigned int)v << 16;
    return __builtin_bit_cast(float, u);
}
static __device__ __forceinline__ unsigned int cvt_pk_bf16(float lo, float hi) {
    unsigned int r;
    asm("v_cvt_pk_bf16_f32 %0, %1, %2" : "=v"(r) : "v"(lo), "v"(hi));
    return r;
}
static __device__ __forceinline__ void gl2lds16(const unsigned short* g, unsigned short* l) {
    __builtin_amdgcn_global_load_lds(
        (const __attribute__((address_space(1))) unsigned int*)g,
        (__attribute__((address_space(3))) unsigned int*)l, 16, 0, 0);
}

// ---------------------------------------------------------------------------
// Transpose + cast: W fp32 [K][N] -> Wt bf16 [N][K]; optional column scale.
// ---------------------------------------------------------------------------
__global__ __launch_bounds__(256) void transpose_w(
    const float* __restrict__ W, unsigned short* __restrict__ Wt,
    int K, int N, int scale_ncols, float scale)
{
    __shared__ float T[64][68];
    const int tid = threadIdx.x;
    const int k0 = blockIdx.y * 64, n0 = blockIdx.x * 64;
    const int rr = tid >> 4;
    const int c4 = (tid & 15) * 4;

#pragma unroll
    for (int i = 0; i < 4; ++i) {
        int r = rr + 16 * i;
        *(float4*)&T[r][c4] = *(const float4*)&W[(size_t)(k0 + r) * N + n0 + c4];
    }
    __syncthreads();
#pragma unroll
    for (int i = 0; i < 4; ++i) {
        int nr = rr + 16 * i;
        float sc = (n0 + nr < scale_ncols) ? scale : 1.0f;
        unsigned short tmp[4];
#pragma unroll
        for (int j = 0; j < 4; ++j) tmp[j] = f2bf(T[c4 + j][nr] * sc);
        unsigned int p0 = (unsigned int)tmp[0] | ((unsigned int)tmp[1] << 16);
        unsigned int p1 = (unsigned int)tmp[2] | ((unsigned int)tmp[3] << 16);
        *(uint2*)&Wt[(size_t)(n0 + nr) * K + k0 + c4] = make_uint2(p0, p1);
    }
}

__global__ __launch_bounds__(256) void cast_plain(const float* __restrict__ src,
                                                  unsigned short* __restrict__ dst)
{
    int idx = blockIdx.x * 256 + threadIdx.x;
    float4 v = *(const float4*)&src[(size_t)idx * 4];
    unsigned int p0 = (unsigned int)f2bf(v.x) | ((unsigned int)f2bf(v.y) << 16);
    unsigned int p1 = (unsigned int)f2bf(v.z) | ((unsigned int)f2bf(v.w) << 16);
    *(uint2*)&dst[(size_t)idx * 4] = make_uint2(p0, p1);
}

// ---------------------------------------------------------------------------
// bf16 MFMA GEMM (m97 structure, 128x128): kept for the small K=512 GEMMs.
// OUT_MODE: 1 = bf16 C[M][N],
//           2 = bf16 transposed Ct[N][M] with k-interleave permutation on M
//               within each 32-row group (attn's in-register P A-frag).
// ---------------------------------------------------------------------------
template<int OUT_MODE>
__global__ __launch_bounds__(256) void gemm_bt(
    const unsigned short* __restrict__ A,
    const unsigned short* __restrict__ Bt,
    void* __restrict__ C,
    int K, int lda, int ldb, int ldc)
{
    __shared__ __align__(16) unsigned short As[128 * 32];
    __shared__ __align__(16) unsigned short Bs[128 * 32];

    const int tid  = threadIdx.x;
    const int w    = tid >> 6;
    const int lane = tid & 63;
    const int quad = lane >> 4;
    const int l15  = lane & 15;
    const int brow = blockIdx.y * 128;
    const int bcol = blockIdx.x * 128;
    const int wr   = (w >> 1) * 64;
    const int wc   = (w & 1) * 64;

    const int srow = lane >> 2;
    const int sseg = (lane & 3) * 8;
    const int r0   = w * 32;

    f32x4 acc[4][4];
#pragma unroll
    for (int mt = 0; mt < 4; ++mt)
#pragma unroll
        for (int nt = 0; nt < 4; ++nt) acc[mt][nt] = (f32x4){0.f, 0.f, 0.f, 0.f};

    const unsigned short* Ab = A  + (size_t)(brow + r0 + srow) * lda + sseg;
    const unsigned short* Bb = Bt + (size_t)(bcol + r0 + srow) * ldb + sseg;

    for (int k0 = 0; k0 < K; k0 += 32) {
        __syncthreads();
        gl2lds16(Ab + k0,                     As + r0 * 32);
        gl2lds16(Ab + k0 + (size_t)16 * lda,  As + (r0 + 16) * 32);
        gl2lds16(Bb + k0,                     Bs + r0 * 32);
        gl2lds16(Bb + k0 + (size_t)16 * ldb,  Bs + (r0 + 16) * 32);
        __syncthreads();

        bf16x8 af[4], bfr[4];
#pragma unroll
        for (int mt = 0; mt < 4; ++mt)
            af[mt] = __builtin_bit_cast(bf16x8,
                *(const uint4*)(As + (wr + mt * 16 + l15) * 32 + quad * 8));
#pragma unroll
        for (int nt = 0; nt < 4; ++nt)
            bfr[nt] = __builtin_bit_cast(bf16x8,
                *(const uint4*)(Bs + (wc + nt * 16 + l15) * 32 + quad * 8));
#pragma unroll
        for (int mt = 0; mt < 4; ++mt)
#pragma unroll
            for (int nt = 0; nt < 4; ++nt)
                acc[mt][nt] = __builtin_amdgcn_mfma_f32_16x16x32_bf16(
                    af[mt], bfr[nt], acc[mt][nt], 0, 0, 0);
    }

    if (OUT_MODE == 2) {
#pragma unroll
        for (int mt = 0; mt < 4; ++mt) {
            int row0 = brow + wr + mt * 16 + quad * 4;   // token base, %4 == 0
            int r5   = row0 & 31;
            int pos  = ((r5 & 15) >> 2) * 8 + ((r5 >> 4) << 2);
            int prow0 = (row0 & ~31) | pos;              // k-interleave permute
#pragma unroll
            for (int nt = 0; nt < 4; ++nt) {
                int col = bcol + wc + nt * 16 + l15;
                unsigned int p0 = (unsigned int)f2bf(acc[mt][nt][0]) |
                                  ((unsigned int)f2bf(acc[mt][nt][1]) << 16);
                unsigned int p1 = (unsigned int)f2bf(acc[mt][nt][2]) |
                                  ((unsigned int)f2bf(acc[mt][nt][3]) << 16);
                *(uint2*)&((unsigned short*)C)[(size_t)col * ldc + prow0] = make_uint2(p0, p1);
            }
        }
    } else {
#pragma unroll
        for (int mt = 0; mt < 4; ++mt)
#pragma unroll
            for (int i = 0; i < 4; ++i) {
                size_t row = (size_t)(brow + wr + mt * 16 + quad * 4 + i);
#pragma unroll
                for (int nt = 0; nt < 4; ++nt) {
                    int col = bcol + wc + nt * 16 + l15;
                    ((unsigned short*)C)[row * ldc + col] = f2bf(acc[mt][nt][i]);
                }
            }
    }
}

// ---------------------------------------------------------------------------
// 8-phase 256-wide GEMM, per-phase interleaved staging (true m201 schedule):
// C = A[M,K] @ Bt[N,K]^T. BM=256, BN in {256,128}, BK=64, 512 thr = 8 waves.
//
// Staging pieces (1KB chunks, gl2lds16 = 64 lanes x 16B, linear dest):
//   A piece p = the 64 rows phase p reads ({32p..32p+31} u {128+32p..+31}),
//     8 chunks = 1/wave.  B half h = rows h*BN/2..+BN/2-1, LB/2 chunks/wave.
// Schedule (tile t, slot s=t&1; pieces go to regions dead >= 1 barrier):
//   ph0: stage A3(t+1)->s^1          | ph1: B0(t+2)->s, A0(t+1)->s^1
//   ph2: B1(t+2)->s, A1(t+1)->s^1    | ph3: A2(t+1)->s^1
// Counted vmcnt (per-wave FIFO simulation, never 0 in-loop):
//   after ph0: vmcnt(2); after ph1: vmcnt(V1); after ph3: vmcnt(V3).
//   Each piece is >=3 phases old at first read. Tail stages wrapped (t+x)%NT
//   pieces into dead regions to keep counts uniform (no under-wait).
// OUT_MODE: 0 = fp32 C, 1 = bf16 C.
// ---------------------------------------------------------------------------
template<int OUT_MODE, int BN>
__global__ __launch_bounds__(512, 2) void gemm8p(
    const unsigned short* __restrict__ A,
    const unsigned short* __restrict__ Bt,
    void* __restrict__ C,
    int K, int lda, int ldb, int ldc)
{
    constexpr int BNF = BN / 64;        // n-frags per wave
    constexpr int LB  = BN / 64;        // B loads/wave/tile
    constexpr int HB  = LB / 2;         // B loads/wave per half
    constexpr int ASLOT = 256 * 64;
    constexpr int BSLOT = BN * 64;
    constexpr int SLOT  = ASLOT + BSLOT;
    constexpr int V0 = 2;
    constexpr int V1 = (LB == 4) ? 4 : 3;
    constexpr int V3 = (LB == 4) ? 4 : 3;

    extern __shared__ __align__(16) unsigned short lds[];

    const int tid  = threadIdx.x;
    const int w    = tid >> 6;
    const int lane = tid & 63;
    const int quad = lane >> 4;
    const int l15  = lane & 15;
    const int wm   = w >> 2;            // 0..1
    const int wn   = w & 3;             // 0..3

    // XCD-aware bijective swizzle (nwg % 8 == 0 guaranteed by caller)
    int fid = blockIdx.y * gridDim.x + blockIdx.x;
    int nwg = gridDim.x * gridDim.y;
    int cpx = nwg >> 3;
    int swz = (fid & 7) * cpx + (fid >> 3);
    int bx  = swz % gridDim.x;
    int by  = swz / gridDim.x;
    const int brow = by * 256;
    const int bcol = bx * BN;

    const unsigned short* Ab = A  + (size_t)brow * lda;
    const unsigned short* Bb = Bt + (size_t)bcol * ldb;

    // chunk geometry: 8 rows x 8 col-blks; all chunk base rows are %8==0,
    // so row&7 == lane>>3 for every piece -> one swizzle term serves all.
    const int lr   = lane >> 3;
    const int lswz = ((lane & 7) ^ lr) * 8;
    const int arow0 = (w < 4) ? (w * 8) : (128 + (w - 4) * 8);
    const int asrc  = (arow0 + lr) * lda + lswz;
    int brow0[HB], bsrc[HB];
#pragma unroll
    for (int c = 0; c < HB; ++c) {
        brow0[c] = (w * HB + c) * 8;
        bsrc[c]  = (brow0[c] + lr) * ldb + lswz;
    }

    f32x4 acc[8][BNF];
#pragma unroll
    for (int mf = 0; mf < 8; ++mf)
#pragma unroll
        for (int nf = 0; nf < BNF; ++nf) acc[mf][nf] = (f32x4){0.f, 0.f, 0.f, 0.f};

    const int NT = K >> 6;

    auto stageA = [&](int s, int tt, int p) {
        gl2lds16(Ab + tt * 64 + p * 32 * lda + asrc,
                 lds + s * SLOT + (arow0 + p * 32) * 64);
    };
    auto stageB = [&](int s, int tt, int h) {
#pragma unroll
        for (int c = 0; c < HB; ++c)
            gl2lds16(Bb + tt * 64 + h * (BN / 2) * ldb + bsrc[c],
                     lds + s * SLOT + ASLOT + (brow0[c] + h * (BN / 2)) * 64);
    };

    // prologue: T0 fully into slot0; B(T1) into slot1 (A(T1) staged in-loop)
#pragma unroll
    for (int p = 0; p < 4; ++p) stageA(0, 0, p);
    stageB(0, 0, 0); stageB(0, 0, 1);
    stageB(1, 1, 0); stageB(1, 1, 1);
    asm volatile("s_waitcnt vmcnt(%0)" :: "i"(LB) : "memory");  // T0 resident
    __builtin_amdgcn_s_barrier();

#pragma unroll 1
    for (int t = 0; t < NT; ++t) {
        const int s  = t & 1;
        const int s1 = s ^ 1;
        const int t1 = (t + 1 < NT) ? t + 1 : 0;            // wrap: dead-region
        const int t2 = (t + 2 < NT) ? t + 2 : t + 2 - NT;   // keep-alive stages
        const unsigned short* As = lds + s * SLOT;
        const unsigned short* Bs = As + ASLOT;

        bf16x8 bq[BNF][2], af[2][2];

        // ---------------- ph0 ----------------
#pragma unroll
        for (int nf = 0; nf < BNF; ++nf)
#pragma unroll
            for (int kk = 0; kk < 2; ++kk) {
                int r = wn * (BN / 4) + nf * 16 + l15;
                bq[nf][kk] = __builtin_bit_cast(bf16x8,
                    *(const uint4*)(Bs + r * 64 + (((kk * 4 + quad) ^ (r & 7)) * 8)));
            }
#pragma unroll
        for (int m = 0; m < 2; ++m)
#pragma unroll
            for (int kk = 0; kk < 2; ++kk) {
                int r = wm * 128 + (0 * 2 + m) * 16 + l15;
                af[m][kk] = __builtin_bit_cast(bf16x8,
                    *(const uint4*)(As + r * 64 + (((kk * 4 + quad) ^ (r & 7)) * 8)));
            }
        stageA(s1, t1, 3);
        __builtin_amdgcn_s_barrier();
        __builtin_amdgcn_s_setprio(1);
#pragma unroll
        for (int m = 0; m < 2; ++m)
#pragma unroll
            for (int nf = 0; nf < BNF; ++nf)
#pragma unroll
                for (int kk = 0; kk < 2; ++kk)
                    acc[0 + m][nf] = __builtin_amdgcn_mfma_f32_16x16x32_bf16(
                        af[m][kk], bq[nf][kk], acc[0 + m][nf], 0, 0, 0);
        __builtin_amdgcn_s_setprio(0);
        asm volatile("s_waitcnt vmcnt(%0)" :: "i"(V0) : "memory");
        __builtin_amdgcn_s_barrier();

        // ---------------- ph1 ----------------
#pragma unroll
        for (int m = 0; m < 2; ++m)
#pragma unroll
            for (int kk = 0; kk < 2; ++kk) {
                int r = wm * 128 + (1 * 2 + m) * 16 + l15;
                af[m][kk] = __builtin_bit_cast(bf16x8,
                    *(const uint4*)(As + r * 64 + (((kk * 4 + quad) ^ (r & 7)) * 8)));
            }
        stageB(s, t2, 0);
        stageA(s1, t1, 0);
        __builtin_amdgcn_s_barrier();
        __builtin_amdgcn_s_setprio(1);
#pragma unroll
        for (int m = 0; m < 2; ++m)
#pragma unroll
            for (int nf = 0; nf < BNF; ++nf)
#pragma unroll
                for (int kk = 0; kk < 2; ++kk)
                    acc[2 + m][nf] = __builtin_amdgcn_mfma_f32_16x16x32_bf16(
                        af[m][kk], bq[nf][kk], acc[2 + m][nf], 0, 0, 0);
        __builtin_amdgcn_s_setprio(0);
        asm volatile("s_waitcnt vmcnt(%0)" :: "i"(V1) : "memory");
        __builtin_amdgcn_s_barrier();

        // ---------------- ph2 ----------------
#pragma unroll
        for (int m = 0; m < 2; ++m)
#pragma unroll
            for (int kk = 0; kk < 2; ++kk) {
                int r = wm * 128 + (2 * 2 + m) * 16 + l15;
                af[m][kk] = __builtin_bit_cast(bf16x8,
                    *(const uint4*)(As + r * 64 + (((kk * 4 + quad) ^ (r & 7)) * 8)));
            }
        stageB(s, t2, 1);
        stageA(s1, t1, 1);
        __builtin_amdgcn_s_barrier();
        __builtin_amdgcn_s_setprio(1);
#pragma unroll
        for (int m = 0; m < 2; ++m)
#pragma unroll
            for (int nf = 0; nf < BNF; ++nf)
#pragma unroll
                for (int kk = 0; kk < 2; ++kk)
                    acc[4 + m][nf] = __builtin_amdgcn_mfma_f32_16x16x32_bf16(
                        af[m][kk], bq[nf][kk], acc[4 + m][nf], 0, 0, 0);
        __builtin_amdgcn_s_setprio(0);
        __builtin_amdgcn_s_barrier();

        // ---------------- ph3 ----------------
#pragma unroll
        for (int m = 0; m < 2; ++m)
#pragma unroll
            for (int kk = 0; kk < 2; ++kk) {
                int r = wm * 128 + (3 * 2 + m) * 16 + l15;
                af[m][kk] = __builtin_bit_cast(bf16x8,
                    *(const uint4*)(As + r * 64 + (((kk * 4 + quad) ^ (r & 7)) * 8)));
            }
        stageA(s1, t1, 2);
        __builtin_amdgcn_s_barrier();
        __builtin_amdgcn_s_setprio(1);
#pragma unroll
        for (int m = 0; m < 2; ++m)
#pragma unroll
            for (int nf = 0; nf < BNF; ++nf)
#pragma unroll
                for (int kk = 0; kk < 2; ++kk)
                    acc[6 + m][nf] = __builtin_amdgcn_mfma_f32_16x16x32_bf16(
                        af[m][kk], bq[nf][kk], acc[6 + m][nf], 0, 0, 0);
        __builtin_amdgcn_s_setprio(0);
        asm volatile("s_waitcnt vmcnt(%0)" :: "i"(V3) : "memory");
        __builtin_amdgcn_s_barrier();
    }
    asm volatile("s_waitcnt vmcnt(0)" ::: "memory");   // drain wrap stages

    // epilogue: per-wave 128 x BN/4 C-write
#pragma unroll
    for (int mf = 0; mf < 8; ++mf) {
#pragma unroll
        for (int i = 0; i < 4; ++i) {
            size_t row = (size_t)(brow + wm * 128 + mf * 16 + quad * 4 + i);
#pragma unroll
            for (int nf = 0; nf < BNF; ++nf) {
                int col = bcol + wn * (BN / 4) + nf * 16 + l15;
                if (OUT_MODE == 1)
                    ((unsigned short*)C)[row * ldc + col] = f2bf(acc[mf][nf][i]);
                else
                    ((float*)C)[row * ldc + col] = acc[mf][nf][i];
            }
        }
    }
}

// ---------------------------------------------------------------------------
// RoPE in-place on bf16 q (inside qkvb) and bf16 k (kb).
// ---------------------------------------------------------------------------
__global__ __launch_bounds__(256) void rope_bf16(unsigned short* __restrict__ qkvb,
                                                 unsigned short* __restrict__ kb)
{
    int idx = blockIdx.x * 256 + threadIdx.x;
    int i    = idx & 31;
    int head = (idx >> 5) % 20;
    int t    = idx / (20 * 32);
    if (t >= NTOK) return;
    int pos = t & (SEQ - 1);

    const float LOG_BASE_OVER_32 = 0.28782313662425572f; // ln(10000)/32
    float ang = (float)pos * __expf(-(float)i * LOG_BASE_OVER_32);
    float c = cosf(ang);
    float sn = sinf(ang);

    unsigned short* p;
    if (head < NH) p = qkvb + (size_t)t * QKV_W + head * D_QKD + D_NOPE;
    else           p = kb   + (size_t)t * KW    + (head - NH) * D_QKD + D_NOPE;

    float x1 = bf2f(p[i]), x2 = bf2f(p[i + 32]);
    p[i]      = f2bf(x1 * c - x2 * sn);
    p[i + 32] = f2bf(x2 * c + x1 * sn);
}

// ---------------------------------------------------------------------------
// MFMA flash attention, causal, GQA. Fixed m=0 softmax in exp2 domain.
// In-register P via swapped QK^T + k-permuted V. 40 KB LDS, 4 blocks/CU:
// 1024-block grid fully co-resident; balanced qt mapping. Wave-uniform
// causal-mask skip; v_cvt_pk_bf16_f32 P-pack; setprio around MFMA clusters.
// ---------------------------------------------------------------------------
__global__ __launch_bounds__(256) void attn_mfma(
    const unsigned short* __restrict__ qkvb,
    const unsigned short* __restrict__ kb,
    const unsigned short* __restrict__ vt,
    unsigned short* __restrict__ attnb)
{
    __shared__ __align__(16) unsigned short KsL[2 * 32 * 192];  // 2 x 12 KB
    __shared__ __align__(16) unsigned short VtL[2 * 128 * 32];  // 2 x 8 KB

    const int tid  = threadIdx.x;
    const int w    = tid >> 6;
    const int lane = tid & 63;
    const int quad = lane >> 4;
    const int l15  = lane & 15;

    const int bid = blockIdx.x;
    const int g   = bid >> 5;
    const int jj  = g & 7;
    const int m   = g >> 3;
    int qt;
    if      (m == 0) qt = 31 - jj;
    else if (m == 1) qt = 16 + jj;
    else if (m == 2) qt = 15 - jj;
    else             qt = jj;
    const int hb = bid & 31;
    const int h  = hb & 15;
    const int b  = hb >> 4;
    const int kvh = h >> 2;

    const int x7   = l15 & 7;             // K read swizzle
    const int vx   = (l15 >> 1) & 3;      // V read swizzle

    int koff[3], voff[2];
#pragma unroll
    for (int it = 0; it < 3; ++it) {
        int bidx = (w * 3 + it) * 64 + lane;      // 16B-block index in K tile
        int row  = bidx / 24;
        int sblk = bidx - row * 24;
        int gblk = sblk ^ (row & 7);
        koff[it] = row * KW + gblk * 8;
    }
#pragma unroll
    for (int it = 0; it < 2; ++it) {
        int bidx = (w * 2 + it) * 64 + lane;      // 16B-block index in V tile
        int row  = bidx >> 2;
        int gblk = (bidx & 3) ^ ((row >> 1) & 3);
        voff[it] = row * NTOK + gblk * 8;
    }
    const unsigned short* kp0 = kb + (size_t)(b * SEQ) * KW + kvh * D_QKD;
    const unsigned short* vp0 = vt + (size_t)(kvh * 128) * NTOK + b * SEQ;

    const int q0   = qt * 64;
    const int q0w  = q0 + w * 16;
    const int wmax = q0w + 15;

    bf16x8 qf[6];
    {
        const unsigned short* qp =
            qkvb + (size_t)(b * SEQ + q0w + l15) * QKV_W + h * D_QKD + quad * 8;
#pragma unroll
        for (int t = 0; t < 6; ++t)
            qf[t] = __builtin_bit_cast(bf16x8, *(const uint4*)(qp + t * 32));
    }

    f32x4 o[8];
#pragma unroll
    for (int c = 0; c < 8; ++c) o[c] = (f32x4){0.f, 0.f, 0.f, 0.f};
    float lp = 0.f;     // partial l for q-row l15 over this lane's k-slots

    const int nt = 2 * qt + 2;

    {
#pragma unroll
        for (int it = 0; it < 3; ++it)
            gl2lds16(kp0 + koff[it], KsL + (w * 3 + it) * 512);
#pragma unroll
        for (int it = 0; it < 2; ++it)
            gl2lds16(vp0 + voff[it], VtL + (w * 2 + it) * 512);
    }
    __syncthreads();   // vmcnt drain: tile 0 staged

    for (int tk = 0; tk < nt; ++tk) {
        const int k0  = tk * 32;
        const int cur = tk & 1;

        if (tk + 1 < nt) {
            const int nxt = cur ^ 1;
            const unsigned short* ks = kp0 + (size_t)(k0 + 32) * KW;
            const unsigned short* vs = vp0 + (k0 + 32);
#pragma unroll
            for (int it = 0; it < 3; ++it)
                gl2lds16(ks + koff[it], KsL + nxt * (32 * 192) + (w * 3 + it) * 512);
#pragma unroll
            for (int it = 0; it < 2; ++it)
                gl2lds16(vs + voff[it], VtL + nxt * (128 * 32) + (w * 2 + it) * 512);
        }

        if (k0 <= wmax) {
            const unsigned short* Kc = KsL + cur * (32 * 192);
            const unsigned short* Vc = VtL + cur * (128 * 32);

            // ---- scores: S^T[32k][16q] = K @ Q^T (log2 domain), swapped ----
            f32x4 s[2];
            __builtin_amdgcn_s_setprio(1);
#pragma unroll
            for (int j = 0; j < 2; ++j) {
                f32x4 acc = {0.f, 0.f, 0.f, 0.f};
                const unsigned short* kr = Kc + (j * 16 + l15) * 192;
#pragma unroll
                for (int t = 0; t < 6; ++t) {
                    int sblk = (quad + 4 * t) ^ x7;
                    bf16x8 kf = __builtin_bit_cast(bf16x8, *(const uint4*)(kr + sblk * 8));
                    acc = __builtin_amdgcn_mfma_f32_16x16x32_bf16(kf, qf[t], acc, 0, 0, 0);
                }
                s[j] = acc;
            }
            __builtin_amdgcn_s_setprio(0);
            // lane holds S[q = l15][k = k0 + j*16 + quad*4 + i]

            // ---- softmax, fixed m=0, exp2; wave-uniform mask skip ----
            if (k0 + 31 <= q0w) {
#pragma unroll
                for (int j = 0; j < 2; ++j)
#pragma unroll
                    for (int i = 0; i < 4; ++i) {
                        float p = __builtin_amdgcn_exp2f(s[j][i]);
                        s[j][i] = p;
                        lp += p;
                    }
            } else {
                const int qrow = q0w + l15;
#pragma unroll
                for (int j = 0; j < 2; ++j)
#pragma unroll
                    for (int i = 0; i < 4; ++i) {
                        int kidx = k0 + j * 16 + quad * 4 + i;
                        float p = (kidx <= qrow) ? __builtin_amdgcn_exp2f(s[j][i]) : 0.f;
                        s[j][i] = p;
                        lp += p;
                    }
            }

            // ---- P -> A-frag: HW pack, pure in-register (k-permuted V) ----
            uint4 pk;
            pk.x = cvt_pk_bf16(s[0][0], s[0][1]);
            pk.y = cvt_pk_bf16(s[0][2], s[0][3]);
            pk.z = cvt_pk_bf16(s[1][0], s[1][1]);
            pk.w = cvt_pk_bf16(s[1][2], s[1][3]);
            bf16x8 pa = __builtin_bit_cast(bf16x8, pk);

            // ---- PV: 8 MFMAs, swizzled V frags ----
            __builtin_amdgcn_s_setprio(1);
#pragma unroll
            for (int c = 0; c < 8; ++c) {
                bf16x8 vf = __builtin_bit_cast(bf16x8,
                    *(const uint4*)(Vc + (c * 16 + l15) * 32 + ((quad ^ vx) * 8)));
                o[c] = __builtin_amdgcn_mfma_f32_16x16x32_bf16(pa, vf, o[c], 0, 0, 0);
            }
            __builtin_amdgcn_s_setprio(0);
        }

        __syncthreads();   // waves done with buf cur; DMA for tk+1 drained
    }

    // ---- epilogue: total l per q-row, redistribute to C-layout rows ----
    float lt = lp;
    lt += __shfl_xor(lt, 16);
    lt += __shfl_xor(lt, 32);      // all lanes: l for q-row = their l15

#pragma unroll
    for (int i = 0; i < 4; ++i) {
        float inv = 1.0f / __shfl(lt, (lane & 48) | (quad * 4 + i));
        size_t rowoff = (size_t)(b * SEQ + q0w + quad * 4 + i) * AW + h * D_VV + l15;
#pragma unroll
        for (int c = 0; c < 8; ++c)
            attnb[rowoff + c * 16] = f2bf(o[c][i] * inv);
    }
}

// ---------------------------------------------------------------------------
extern "C" void kernel_launch(void* const* d_in, const int* in_sizes, int n_in,
                              void* d_out, int out_size, void* d_ws, size_t ws_size,
                              hipStream_t stream)
{
    const float* X     = (const float*)d_in[0];
    const float* Wqkv  = (const float*)d_in[1];
    const float* Wk_up = (const float*)d_in[2];
    const float* Wv_up = (const float*)d_in[3];
    const float* Wo    = (const float*)d_in[4];
    float* out = (float*)d_out;

    unsigned short* Xb    = (unsigned short*)d_ws;                   // [4096][2048]
    unsigned short* Wqt   = Xb    + (size_t)NTOK * HIDN;             // [3584][2048]
    unsigned short* Wkt   = Wqt   + (size_t)QKV_W * HIDN;            // [768][512]
    unsigned short* Wvt   = Wkt   + (size_t)KW * LORA;               // [512][512]
    unsigned short* Wot   = Wvt   + (size_t)VW * LORA;               // [2048][2048]
    unsigned short* qkvb  = Wot   + (size_t)HIDN * AW;               // [4096][3584]
    unsigned short* kb    = qkvb  + (size_t)NTOK * QKV_W;            // [4096][768]
    unsigned short* vtb   = kb    + (size_t)NTOK * KW;               // [512][4096] (V^T, k-permuted)
    unsigned short* attnb = vtb   + (size_t)VW * NTOK;               // [4096][2048]

    cast_plain<<<NTOK * HIDN / 4 / 256, 256, 0, stream>>>(X, Xb);
    // q columns pre-scaled by (1/sqrt(192)) * log2(e): softmax runs in exp2 domain
    transpose_w<<<dim3(QKV_W / 64, HIDN / 64), 256, 0, stream>>>(
        Wqkv, Wqt, HIDN, QKV_W, NH * D_QKD, QSCALE * LOG2E);
    transpose_w<<<dim3(KW / 64, LORA / 64), 256, 0, stream>>>(Wk_up, Wkt, LORA, KW, 0, 1.0f);
    transpose_w<<<dim3(VW / 64, LORA / 64), 256, 0, stream>>>(Wv_up, Wvt, LORA, VW, 0, 1.0f);
    transpose_w<<<dim3(AW / 64, HIDN / 64), 256, 0, stream>>>(Wo, Wot, HIDN, AW, 0, 1.0f);

    // qkvb = Xb @ Wqt^T (bf16; q cols pre-scaled) — 8-phase 256x256
    gemm8p<1, 256><<<dim3(QKV_W / 256, NTOK / 256), 512, 131072, stream>>>(
        Xb, Wqt, qkvb, HIDN, HIDN, HIDN, QKV_W);

    // kb = c_kv @ Wkt^T (bf16) ; vt = (c_kv @ Wvt^T)^T (bf16, k-permuted cols)
    gemm_bt<1><<<dim3(KW / 128, NTOK / 128), 256, 0, stream>>>(
        qkvb + NH * D_QKD, Wkt, kb, LORA, QKV_W, LORA, KW);
    gemm_bt<2><<<dim3(VW / 128, NTOK / 128), 256, 0, stream>>>(
        qkvb + NH * D_QKD, Wvt, vtb, LORA, QKV_W, LORA, NTOK);

    rope_bf16<<<(NTOK * 20 * 32 + 255) / 256, 256, 0, stream>>>(qkvb, kb);

    attn_mfma<<<dim3(1024), 256, 0, stream>>>(qkvb, kb, vtb, attnb);

    // out = attnb @ Wot^T (fp32) — 8-phase 256x128 (grid 256 = full CU fill)
    gemm8p<0, 128><<<dim3(HIDN / 128, NTOK / 256), 512, 98304, stream>>>(
        attnb, Wot, out, AW, AW, AW, HIDN);
}

// Round 6
// 334.945 us; speedup vs baseline: 1.4192x; 1.0035x over previous
//
#include <hip/hip_runtime.h>
#include <hip/hip_bf16.h>
#include <math.h>

#define HIDN  2048
#define NH    16
#define NKV   4
#define LORA  512
#define D_ROPE 64
#define D_NOPE 128
#define D_VV  128
#define D_QKD 192
#define BATCH 2
#define SEQ   2048
#define NTOK  (BATCH*SEQ)          // 4096
#define QKV_W (NH*D_QKD + LORA)    // 3584
#define KW    (NKV*D_QKD)          // 768
#define VW    (NKV*D_VV)           // 512
#define AW    (NH*D_VV)            // 2048
#define QSCALE 0.07216878364870323f   // 1/sqrt(192)
#define LOG2E  1.4426950408889634f

typedef __attribute__((ext_vector_type(8))) __bf16 bf16x8;
typedef __attribute__((ext_vector_type(4))) float f32x4;

static __device__ __forceinline__ unsigned short f2bf(float f) {
    unsigned int u = __builtin_bit_cast(unsigned int, f);
    u += 0x7fffu + ((u >> 16) & 1u);          // round-to-nearest-even
    return (unsigned short)(u >> 16);
}
static __device__ __forceinline__ float bf2f(unsigned short v) {
    unsigned int u = (unsigned int)v << 16;
    return __builtin_bit_cast(float, u);
}
static __device__ __forceinline__ unsigned int cvt_pk_bf16(float lo, float hi) {
    unsigned int r;
    asm("v_cvt_pk_bf16_f32 %0, %1, %2" : "=v"(r) : "v"(lo), "v"(hi));
    return r;
}
static __device__ __forceinline__ void gl2lds16(const unsigned short* g, unsigned short* l) {
    __builtin_amdgcn_global_load_lds(
        (const __attribute__((address_space(1))) unsigned int*)g,
        (__attribute__((address_space(3))) unsigned int*)l, 16, 0, 0);
}

// ---------------------------------------------------------------------------
// Transpose + cast: W fp32 [K][N] -> Wt bf16 [N][K]; optional column scale.
// ---------------------------------------------------------------------------
__global__ __launch_bounds__(256) void transpose_w(
    const float* __restrict__ W, unsigned short* __restrict__ Wt,
    int K, int N, int scale_ncols, float scale)
{
    __shared__ float T[64][68];
    const int tid = threadIdx.x;
    const int k0 = blockIdx.y * 64, n0 = blockIdx.x * 64;
    const int rr = tid >> 4;
    const int c4 = (tid & 15) * 4;

#pragma unroll
    for (int i = 0; i < 4; ++i) {
        int r = rr + 16 * i;
        *(float4*)&T[r][c4] = *(const float4*)&W[(size_t)(k0 + r) * N + n0 + c4];
    }
    __syncthreads();
#pragma unroll
    for (int i = 0; i < 4; ++i) {
        int nr = rr + 16 * i;
        float sc = (n0 + nr < scale_ncols) ? scale : 1.0f;
        unsigned short tmp[4];
#pragma unroll
        for (int j = 0; j < 4; ++j) tmp[j] = f2bf(T[c4 + j][nr] * sc);
        unsigned int p0 = (unsigned int)tmp[0] | ((unsigned int)tmp[1] << 16);
        unsigned int p1 = (unsigned int)tmp[2] | ((unsigned int)tmp[3] << 16);
        *(uint2*)&Wt[(size_t)(n0 + nr) * K + k0 + c4] = make_uint2(p0, p1);
    }
}

__global__ __launch_bounds__(256) void cast_plain(const float* __restrict__ src,
                                                  unsigned short* __restrict__ dst)
{
    int idx = blockIdx.x * 256 + threadIdx.x;
    float4 v = *(const float4*)&src[(size_t)idx * 4];
    unsigned int p0 = (unsigned int)f2bf(v.x) | ((unsigned int)f2bf(v.y) << 16);
    unsigned int p1 = (unsigned int)f2bf(v.z) | ((unsigned int)f2bf(v.w) << 16);
    *(uint2*)&dst[(size_t)idx * 4] = make_uint2(p0, p1);
}

// ---------------------------------------------------------------------------
// bf16 MFMA GEMM (m97 structure, 128x128): kept for the small K=512 GEMMs.
// OUT_MODE: 1 = bf16 C[M][N],
//           2 = bf16 transposed Ct[N][M] with k-interleave permutation on M
//               within each 32-row group (attn's in-register P A-frag).
// ---------------------------------------------------------------------------
template<int OUT_MODE>
__global__ __launch_bounds__(256) void gemm_bt(
    const unsigned short* __restrict__ A,
    const unsigned short* __restrict__ Bt,
    void* __restrict__ C,
    int K, int lda, int ldb, int ldc)
{
    __shared__ __align__(16) unsigned short As[128 * 32];
    __shared__ __align__(16) unsigned short Bs[128 * 32];

    const int tid  = threadIdx.x;
    const int w    = tid >> 6;
    const int lane = tid & 63;
    const int quad = lane >> 4;
    const int l15  = lane & 15;
    const int brow = blockIdx.y * 128;
    const int bcol = blockIdx.x * 128;
    const int wr   = (w >> 1) * 64;
    const int wc   = (w & 1) * 64;

    const int srow = lane >> 2;
    const int sseg = (lane & 3) * 8;
    const int r0   = w * 32;

    f32x4 acc[4][4];
#pragma unroll
    for (int mt = 0; mt < 4; ++mt)
#pragma unroll
        for (int nt = 0; nt < 4; ++nt) acc[mt][nt] = (f32x4){0.f, 0.f, 0.f, 0.f};

    const unsigned short* Ab = A  + (size_t)(brow + r0 + srow) * lda + sseg;
    const unsigned short* Bb = Bt + (size_t)(bcol + r0 + srow) * ldb + sseg;

    for (int k0 = 0; k0 < K; k0 += 32) {
        __syncthreads();
        gl2lds16(Ab + k0,                     As + r0 * 32);
        gl2lds16(Ab + k0 + (size_t)16 * lda,  As + (r0 + 16) * 32);
        gl2lds16(Bb + k0,                     Bs + r0 * 32);
        gl2lds16(Bb + k0 + (size_t)16 * ldb,  Bs + (r0 + 16) * 32);
        __syncthreads();

        bf16x8 af[4], bfr[4];
#pragma unroll
        for (int mt = 0; mt < 4; ++mt)
            af[mt] = __builtin_bit_cast(bf16x8,
                *(const uint4*)(As + (wr + mt * 16 + l15) * 32 + quad * 8));
#pragma unroll
        for (int nt = 0; nt < 4; ++nt)
            bfr[nt] = __builtin_bit_cast(bf16x8,
                *(const uint4*)(Bs + (wc + nt * 16 + l15) * 32 + quad * 8));
#pragma unroll
        for (int mt = 0; mt < 4; ++mt)
#pragma unroll
            for (int nt = 0; nt < 4; ++nt)
                acc[mt][nt] = __builtin_amdgcn_mfma_f32_16x16x32_bf16(
                    af[mt], bfr[nt], acc[mt][nt], 0, 0, 0);
    }

    if (OUT_MODE == 2) {
#pragma unroll
        for (int mt = 0; mt < 4; ++mt) {
            int row0 = brow + wr + mt * 16 + quad * 4;   // token base, %4 == 0
            int r5   = row0 & 31;
            int pos  = ((r5 & 15) >> 2) * 8 + ((r5 >> 4) << 2);
            int prow0 = (row0 & ~31) | pos;              // k-interleave permute
#pragma unroll
            for (int nt = 0; nt < 4; ++nt) {
                int col = bcol + wc + nt * 16 + l15;
                unsigned int p0 = (unsigned int)f2bf(acc[mt][nt][0]) |
                                  ((unsigned int)f2bf(acc[mt][nt][1]) << 16);
                unsigned int p1 = (unsigned int)f2bf(acc[mt][nt][2]) |
                                  ((unsigned int)f2bf(acc[mt][nt][3]) << 16);
                *(uint2*)&((unsigned short*)C)[(size_t)col * ldc + prow0] = make_uint2(p0, p1);
            }
        }
    } else {
#pragma unroll
        for (int mt = 0; mt < 4; ++mt)
#pragma unroll
            for (int i = 0; i < 4; ++i) {
                size_t row = (size_t)(brow + wr + mt * 16 + quad * 4 + i);
#pragma unroll
                for (int nt = 0; nt < 4; ++nt) {
                    int col = bcol + wc + nt * 16 + l15;
                    ((unsigned short*)C)[row * ldc + col] = f2bf(acc[mt][nt][i]);
                }
            }
    }
}

// ---------------------------------------------------------------------------
// 8-phase 256-wide GEMM, deadline-ordered staging + uniform counted vmcnt:
// C = A[M,K] @ Bt[N,K]^T. BM=256, BN in {256,128}, BK=64, 512 thr = 8 waves.
//
// Staging (1KB chunks via gl2lds16, linear LDS dest, pre-swizzled source):
//   A piece p of tile t+1 is issued at phase p of tile t  (slot s^1; that
//     region's last read was tile t-1 phase p -> >=4 barriers dead).
//   B half h of tile t+2 is issued at phase 2+h of tile t (slot s; B of
//     tile t is fully reg-cached at ph0 -> region dead after ph0 barrier).
// Issue order == deadline order, so the FIFO vmcnt never forces a load
// younger than 3 phases (~600+ cyc flight, covers HBM/L2 latency).
// Per-wave FIFO simulation gives ONE wait count for every phase end:
//   NW = 3 + 2*HB  (BN=256 -> vmcnt(7), BN=128 -> vmcnt(5)); never 0 in-loop.
// Prologue issues in steady-state order: B(T0),A0-A2(T0),B0(T1),A3(T0),B1(T1)
// then vmcnt(NW): completes exactly {B(T0), A0(T0)}, leaving the invariant.
// Tail: wrapped (t+1)%NT / (t+2)%NT stages land in dead regions; final
// vmcnt(0) drains before epilogue. OUT_MODE: 0 = fp32 C, 1 = bf16 C.
// ---------------------------------------------------------------------------
template<int OUT_MODE, int BN>
__global__ __launch_bounds__(512, 2) void gemm8p(
    const unsigned short* __restrict__ A,
    const unsigned short* __restrict__ Bt,
    void* __restrict__ C,
    int K, int lda, int ldb, int ldc)
{
    constexpr int BNF = BN / 64;        // n-frags per wave
    constexpr int LB  = BN / 64;        // B loads/wave/tile
    constexpr int HB  = LB / 2;         // B loads/wave per half
    constexpr int ASLOT = 256 * 64;
    constexpr int BSLOT = BN * 64;
    constexpr int SLOT  = ASLOT + BSLOT;
    constexpr int NW  = 3 + 2 * HB;     // uniform counted wait

    extern __shared__ __align__(16) unsigned short lds[];

    const int tid  = threadIdx.x;
    const int w    = tid >> 6;
    const int lane = tid & 63;
    const int quad = lane >> 4;
    const int l15  = lane & 15;
    const int wm   = w >> 2;            // 0..1
    const int wn   = w & 3;             // 0..3

    // XCD-aware bijective swizzle (nwg % 8 == 0 guaranteed by caller)
    int fid = blockIdx.y * gridDim.x + blockIdx.x;
    int nwg = gridDim.x * gridDim.y;
    int cpx = nwg >> 3;
    int swz = (fid & 7) * cpx + (fid >> 3);
    int bx  = swz % gridDim.x;
    int by  = swz / gridDim.x;
    const int brow = by * 256;
    const int bcol = bx * BN;

    const unsigned short* Ab = A  + (size_t)brow * lda;
    const unsigned short* Bb = Bt + (size_t)bcol * ldb;

    // chunk geometry: 8 rows x 8 col-blks; all chunk base rows are %8==0,
    // so row&7 == lane>>3 for every piece -> one swizzle term serves all.
    const int lr   = lane >> 3;
    const int lswz = ((lane & 7) ^ lr) * 8;
    const int arow0 = (w < 4) ? (w * 8) : (128 + (w - 4) * 8);
    const int asrc  = (arow0 + lr) * lda + lswz;
    int brow0[HB], bsrc[HB];
#pragma unroll
    for (int c = 0; c < HB; ++c) {
        brow0[c] = (w * HB + c) * 8;
        bsrc[c]  = (brow0[c] + lr) * ldb + lswz;
    }

    f32x4 acc[8][BNF];
#pragma unroll
    for (int mf = 0; mf < 8; ++mf)
#pragma unroll
        for (int nf = 0; nf < BNF; ++nf) acc[mf][nf] = (f32x4){0.f, 0.f, 0.f, 0.f};

    const int NT = K >> 6;

    auto stageA = [&](int s, int tt, int p) {
        gl2lds16(Ab + tt * 64 + p * 32 * lda + asrc,
                 lds + s * SLOT + (arow0 + p * 32) * 64);
    };
    auto stageB = [&](int s, int tt, int h) {
#pragma unroll
        for (int c = 0; c < HB; ++c)
            gl2lds16(Bb + tt * 64 + h * (BN / 2) * ldb + bsrc[c],
                     lds + s * SLOT + ASLOT + (brow0[c] + h * (BN / 2)) * 64);
    };

    // prologue: steady-state issue order
    stageB(0, 0, 0); stageB(0, 0, 1);           // B(T0)
    stageA(0, 0, 0); stageA(0, 0, 1); stageA(0, 0, 2);
    stageB(1, 1, 0);                            // B0(T1)
    stageA(0, 0, 3);
    stageB(1, 1, 1);                            // B1(T1)
    asm volatile("s_waitcnt vmcnt(%0)" :: "i"(NW) : "memory");
    __builtin_amdgcn_s_barrier();

#pragma unroll 1
    for (int t = 0; t < NT; ++t) {
        const int s  = t & 1;
        const int s1 = s ^ 1;
        const int t1 = (t + 1 < NT) ? t + 1 : 0;            // wrap: dead-region
        const int t2 = (t + 2 < NT) ? t + 2 : t + 2 - NT;   // keep-alive stages
        const unsigned short* As = lds + s * SLOT;
        const unsigned short* Bs = As + ASLOT;

        bf16x8 bq[BNF][2], af[2][2];

#pragma unroll
        for (int ph = 0; ph < 4; ++ph) {
            if (ph == 0) {
#pragma unroll
                for (int nf = 0; nf < BNF; ++nf)
#pragma unroll
                    for (int kk = 0; kk < 2; ++kk) {
                        int r = wn * (BN / 4) + nf * 16 + l15;
                        bq[nf][kk] = __builtin_bit_cast(bf16x8,
                            *(const uint4*)(Bs + r * 64 + (((kk * 4 + quad) ^ (r & 7)) * 8)));
                    }
            }
#pragma unroll
            for (int m = 0; m < 2; ++m)
#pragma unroll
                for (int kk = 0; kk < 2; ++kk) {
                    int r = wm * 128 + (ph * 2 + m) * 16 + l15;
                    af[m][kk] = __builtin_bit_cast(bf16x8,
                        *(const uint4*)(As + r * 64 + (((kk * 4 + quad) ^ (r & 7)) * 8)));
                }
            // deadline-ordered staging: A piece ph of t+1; B halves of t+2
            stageA(s1, t1, ph);
            if (ph == 2) stageB(s, t2, 0);
            if (ph == 3) stageB(s, t2, 1);
            __builtin_amdgcn_s_barrier();
            __builtin_amdgcn_s_setprio(1);
#pragma unroll
            for (int m = 0; m < 2; ++m)
#pragma unroll
                for (int nf = 0; nf < BNF; ++nf)
#pragma unroll
                    for (int kk = 0; kk < 2; ++kk)
                        acc[ph * 2 + m][nf] = __builtin_amdgcn_mfma_f32_16x16x32_bf16(
                            af[m][kk], bq[nf][kk], acc[ph * 2 + m][nf], 0, 0, 0);
            __builtin_amdgcn_s_setprio(0);
            asm volatile("s_waitcnt vmcnt(%0)" :: "i"(NW) : "memory");
            __builtin_amdgcn_s_barrier();
        }
    }
    asm volatile("s_waitcnt vmcnt(0)" ::: "memory");   // drain wrap stages

    // epilogue: per-wave 128 x BN/4 C-write
#pragma unroll
    for (int mf = 0; mf < 8; ++mf) {
#pragma unroll
        for (int i = 0; i < 4; ++i) {
            size_t row = (size_t)(brow + wm * 128 + mf * 16 + quad * 4 + i);
#pragma unroll
            for (int nf = 0; nf < BNF; ++nf) {
                int col = bcol + wn * (BN / 4) + nf * 16 + l15;
                if (OUT_MODE == 1)
                    ((unsigned short*)C)[row * ldc + col] = f2bf(acc[mf][nf][i]);
                else
                    ((float*)C)[row * ldc + col] = acc[mf][nf][i];
            }
        }
    }
}

// ---------------------------------------------------------------------------
// RoPE in-place on bf16 q (inside qkvb) and bf16 k (kb).
// ---------------------------------------------------------------------------
__global__ __launch_bounds__(256) void rope_bf16(unsigned short* __restrict__ qkvb,
                                                 unsigned short* __restrict__ kb)
{
    int idx = blockIdx.x * 256 + threadIdx.x;
    int i    = idx & 31;
    int head = (idx >> 5) % 20;
    int t    = idx / (20 * 32);
    if (t >= NTOK) return;
    int pos = t & (SEQ - 1);

    const float LOG_BASE_OVER_32 = 0.28782313662425572f; // ln(10000)/32
    float ang = (float)pos * __expf(-(float)i * LOG_BASE_OVER_32);
    float c = cosf(ang);
    float sn = sinf(ang);

    unsigned short* p;
    if (head < NH) p = qkvb + (size_t)t * QKV_W + head * D_QKD + D_NOPE;
    else           p = kb   + (size_t)t * KW    + (head - NH) * D_QKD + D_NOPE;

    float x1 = bf2f(p[i]), x2 = bf2f(p[i + 32]);
    p[i]      = f2bf(x1 * c - x2 * sn);
    p[i + 32] = f2bf(x2 * c + x1 * sn);
}

// ---------------------------------------------------------------------------
// MFMA flash attention, causal, GQA. Fixed m=0 softmax in exp2 domain.
// In-register P via swapped QK^T + k-permuted V. 40 KB LDS, 4 blocks/CU:
// 1024-block grid fully co-resident; balanced qt mapping. Wave-uniform
// causal-mask skip; v_cvt_pk_bf16_f32 P-pack; setprio around MFMA clusters.
// ---------------------------------------------------------------------------
__global__ __launch_bounds__(256) void attn_mfma(
    const unsigned short* __restrict__ qkvb,
    const unsigned short* __restrict__ kb,
    const unsigned short* __restrict__ vt,
    unsigned short* __restrict__ attnb)
{
    __shared__ __align__(16) unsigned short KsL[2 * 32 * 192];  // 2 x 12 KB
    __shared__ __align__(16) unsigned short VtL[2 * 128 * 32];  // 2 x 8 KB

    const int tid  = threadIdx.x;
    const int w    = tid >> 6;
    const int lane = tid & 63;
    const int quad = lane >> 4;
    const int l15  = lane & 15;

    const int bid = blockIdx.x;
    const int g   = bid >> 5;
    const int jj  = g & 7;
    const int m   = g >> 3;
    int qt;
    if      (m == 0) qt = 31 - jj;
    else if (m == 1) qt = 16 + jj;
    else if (m == 2) qt = 15 - jj;
    else             qt = jj;
    const int hb = bid & 31;
    const int h  = hb & 15;
    const int b  = hb >> 4;
    const int kvh = h >> 2;

    const int x7   = l15 & 7;             // K read swizzle
    const int vx   = (l15 >> 1) & 3;      // V read swizzle

    int koff[3], voff[2];
#pragma unroll
    for (int it = 0; it < 3; ++it) {
        int bidx = (w * 3 + it) * 64 + lane;      // 16B-block index in K tile
        int row  = bidx / 24;
        int sblk = bidx - row * 24;
        int gblk = sblk ^ (row & 7);
        koff[it] = row * KW + gblk * 8;
    }
#pragma unroll
    for (int it = 0; it < 2; ++it) {
        int bidx = (w * 2 + it) * 64 + lane;      // 16B-block index in V tile
        int row  = bidx >> 2;
        int gblk = (bidx & 3) ^ ((row >> 1) & 3);
        voff[it] = row * NTOK + gblk * 8;
    }
    const unsigned short* kp0 = kb + (size_t)(b * SEQ) * KW + kvh * D_QKD;
    const unsigned short* vp0 = vt + (size_t)(kvh * 128) * NTOK + b * SEQ;

    const int q0   = qt * 64;
    const int q0w  = q0 + w * 16;
    const int wmax = q0w + 15;

    bf16x8 qf[6];
    {
        const unsigned short* qp =
            qkvb + (size_t)(b * SEQ + q0w + l15) * QKV_W + h * D_QKD + quad * 8;
#pragma unroll
        for (int t = 0; t < 6; ++t)
            qf[t] = __builtin_bit_cast(bf16x8, *(const uint4*)(qp + t * 32));
    }

    f32x4 o[8];
#pragma unroll
    for (int c = 0; c < 8; ++c) o[c] = (f32x4){0.f, 0.f, 0.f, 0.f};
    float lp = 0.f;     // partial l for q-row l15 over this lane's k-slots

    const int nt = 2 * qt + 2;

    {
#pragma unroll
        for (int it = 0; it < 3; ++it)
            gl2lds16(kp0 + koff[it], KsL + (w * 3 + it) * 512);
#pragma unroll
        for (int it = 0; it < 2; ++it)
            gl2lds16(vp0 + voff[it], VtL + (w * 2 + it) * 512);
    }
    __syncthreads();   // vmcnt drain: tile 0 staged

    for (int tk = 0; tk < nt; ++tk) {
        const int k0  = tk * 32;
        const int cur = tk & 1;

        if (tk + 1 < nt) {
            const int nxt = cur ^ 1;
            const unsigned short* ks = kp0 + (size_t)(k0 + 32) * KW;
            const unsigned short* vs = vp0 + (k0 + 32);
#pragma unroll
            for (int it = 0; it < 3; ++it)
                gl2lds16(ks + koff[it], KsL + nxt * (32 * 192) + (w * 3 + it) * 512);
#pragma unroll
            for (int it = 0; it < 2; ++it)
                gl2lds16(vs + voff[it], VtL + nxt * (128 * 32) + (w * 2 + it) * 512);
        }

        if (k0 <= wmax) {
            const unsigned short* Kc = KsL + cur * (32 * 192);
            const unsigned short* Vc = VtL + cur * (128 * 32);

            // ---- scores: S^T[32k][16q] = K @ Q^T (log2 domain), swapped ----
            f32x4 s[2];
            __builtin_amdgcn_s_setprio(1);
#pragma unroll
            for (int j = 0; j < 2; ++j) {
                f32x4 acc = {0.f, 0.f, 0.f, 0.f};
                const unsigned short* kr = Kc + (j * 16 + l15) * 192;
#pragma unroll
                for (int t = 0; t < 6; ++t) {
                    int sblk = (quad + 4 * t) ^ x7;
                    bf16x8 kf = __builtin_bit_cast(bf16x8, *(const uint4*)(kr + sblk * 8));
                    acc = __builtin_amdgcn_mfma_f32_16x16x32_bf16(kf, qf[t], acc, 0, 0, 0);
                }
                s[j] = acc;
            }
            __builtin_amdgcn_s_setprio(0);
            // lane holds S[q = l15][k = k0 + j*16 + quad*4 + i]

            // ---- softmax, fixed m=0, exp2; wave-uniform mask skip ----
            if (k0 + 31 <= q0w) {
#pragma unroll
                for (int j = 0; j < 2; ++j)
#pragma unroll
                    for (int i = 0; i < 4; ++i) {
                        float p = __builtin_amdgcn_exp2f(s[j][i]);
                        s[j][i] = p;
                        lp += p;
                    }
            } else {
                const int qrow = q0w + l15;
#pragma unroll
                for (int j = 0; j < 2; ++j)
#pragma unroll
                    for (int i = 0; i < 4; ++i) {
                        int kidx = k0 + j * 16 + quad * 4 + i;
                        float p = (kidx <= qrow) ? __builtin_amdgcn_exp2f(s[j][i]) : 0.f;
                        s[j][i] = p;
                        lp += p;
                    }
            }

            // ---- P -> A-frag: HW pack, pure in-register (k-permuted V) ----
            uint4 pk;
            pk.x = cvt_pk_bf16(s[0][0], s[0][1]);
            pk.y = cvt_pk_bf16(s[0][2], s[0][3]);
            pk.z = cvt_pk_bf16(s[1][0], s[1][1]);
            pk.w = cvt_pk_bf16(s[1][2], s[1][3]);
            bf16x8 pa = __builtin_bit_cast(bf16x8, pk);

            // ---- PV: 8 MFMAs, swizzled V frags ----
            __builtin_amdgcn_s_setprio(1);
#pragma unroll
            for (int c = 0; c < 8; ++c) {
                bf16x8 vf = __builtin_bit_cast(bf16x8,
                    *(const uint4*)(Vc + (c * 16 + l15) * 32 + ((quad ^ vx) * 8)));
                o[c] = __builtin_amdgcn_mfma_f32_16x16x32_bf16(pa, vf, o[c], 0, 0, 0);
            }
            __builtin_amdgcn_s_setprio(0);
        }

        __syncthreads();   // waves done with buf cur; DMA for tk+1 drained
    }

    // ---- epilogue: total l per q-row, redistribute to C-layout rows ----
    float lt = lp;
    lt += __shfl_xor(lt, 16);
    lt += __shfl_xor(lt, 32);      // all lanes: l for q-row = their l15

#pragma unroll
    for (int i = 0; i < 4; ++i) {
        float inv = 1.0f / __shfl(lt, (lane & 48) | (quad * 4 + i));
        size_t rowoff = (size_t)(b * SEQ + q0w + quad * 4 + i) * AW + h * D_VV + l15;
#pragma unroll
        for (int c = 0; c < 8; ++c)
            attnb[rowoff + c * 16] = f2bf(o[c][i] * inv);
    }
}

// ---------------------------------------------------------------------------
extern "C" void kernel_launch(void* const* d_in, const int* in_sizes, int n_in,
                              void* d_out, int out_size, void* d_ws, size_t ws_size,
                              hipStream_t stream)
{
    const float* X     = (const float*)d_in[0];
    const float* Wqkv  = (const float*)d_in[1];
    const float* Wk_up = (const float*)d_in[2];
    const float* Wv_up = (const float*)d_in[3];
    const float* Wo    = (const float*)d_in[4];
    float* out = (float*)d_out;

    unsigned short* Xb    = (unsigned short*)d_ws;                   // [4096][2048]
    unsigned short* Wqt   = Xb    + (size_t)NTOK * HIDN;             // [3584][2048]
    unsigned short* Wkt   = Wqt   + (size_t)QKV_W * HIDN;            // [768][512]
    unsigned short* Wvt   = Wkt   + (size_t)KW * LORA;               // [512][512]
    unsigned short* Wot   = Wvt   + (size_t)VW * LORA;               // [2048][2048]
    unsigned short* qkvb  = Wot   + (size_t)HIDN * AW;               // [4096][3584]
    unsigned short* kb    = qkvb  + (size_t)NTOK * QKV_W;            // [4096][768]
    unsigned short* vtb   = kb    + (size_t)NTOK * KW;               // [512][4096] (V^T, k-permuted)
    unsigned short* attnb = vtb   + (size_t)VW * NTOK;               // [4096][2048]

    cast_plain<<<NTOK * HIDN / 4 / 256, 256, 0, stream>>>(X, Xb);
    // q columns pre-scaled by (1/sqrt(192)) * log2(e): softmax runs in exp2 domain
    transpose_w<<<dim3(QKV_W / 64, HIDN / 64), 256, 0, stream>>>(
        Wqkv, Wqt, HIDN, QKV_W, NH * D_QKD, QSCALE * LOG2E);
    transpose_w<<<dim3(KW / 64, LORA / 64), 256, 0, stream>>>(Wk_up, Wkt, LORA, KW, 0, 1.0f);
    transpose_w<<<dim3(VW / 64, LORA / 64), 256, 0, stream>>>(Wv_up, Wvt, LORA, VW, 0, 1.0f);
    transpose_w<<<dim3(AW / 64, HIDN / 64), 256, 0, stream>>>(Wo, Wot, HIDN, AW, 0, 1.0f);

    // qkvb = Xb @ Wqt^T (bf16; q cols pre-scaled) — 8-phase 256x256
    gemm8p<1, 256><<<dim3(QKV_W / 256, NTOK / 256), 512, 131072, stream>>>(
        Xb, Wqt, qkvb, HIDN, HIDN, HIDN, QKV_W);

    // kb = c_kv @ Wkt^T (bf16) ; vt = (c_kv @ Wvt^T)^T (bf16, k-permuted cols)
    gemm_bt<1><<<dim3(KW / 128, NTOK / 128), 256, 0, stream>>>(
        qkvb + NH * D_QKD, Wkt, kb, LORA, QKV_W, LORA, KW);
    gemm_bt<2><<<dim3(VW / 128, NTOK / 128), 256, 0, stream>>>(
        qkvb + NH * D_QKD, Wvt, vtb, LORA, QKV_W, LORA, NTOK);

    rope_bf16<<<(NTOK * 20 * 32 + 255) / 256, 256, 0, stream>>>(qkvb, kb);

    attn_mfma<<<dim3(1024), 256, 0, stream>>>(qkvb, kb, vtb, attnb);

    // out = attnb @ Wot^T (fp32) — 8-phase 256x128 (grid 256 = full CU fill)
    gemm8p<0, 128><<<dim3(HIDN / 128, NTOK / 256), 512, 98304, stream>>>(
        attnb, Wot, out, AW, AW, AW, HIDN);
}

// Round 7
// 326.220 us; speedup vs baseline: 1.4572x; 1.0267x over previous
//
#include <hip/hip_runtime.h>
#include <hip/hip_bf16.h>
#include <math.h>

#define HIDN  2048
#define NH    16
#define NKV   4
#define LORA  512
#define D_ROPE 64
#define D_NOPE 128
#define D_VV  128
#define D_QKD 192
#define BATCH 2
#define SEQ   2048
#define NTOK  (BATCH*SEQ)          // 4096
#define QKV_W (NH*D_QKD + LORA)    // 3584
#define KW    (NKV*D_QKD)          // 768
#define VW    (NKV*D_VV)           // 512
#define AW    (NH*D_VV)            // 2048
#define QSCALE 0.07216878364870323f   // 1/sqrt(192)
#define LOG2E  1.4426950408889634f

typedef __attribute__((ext_vector_type(8))) __bf16 bf16x8;
typedef __attribute__((ext_vector_type(4))) float f32x4;

static __device__ __forceinline__ unsigned short f2bf(float f) {
    unsigned int u = __builtin_bit_cast(unsigned int, f);
    u += 0x7fffu + ((u >> 16) & 1u);          // round-to-nearest-even
    return (unsigned short)(u >> 16);
}
static __device__ __forceinline__ float bf2f(unsigned short v) {
    unsigned int u = (unsigned int)v << 16;
    return __builtin_bit_cast(float, u);
}
static __device__ __forceinline__ unsigned int cvt_pk_bf16(float lo, float hi) {
    unsigned int r;
    asm("v_cvt_pk_bf16_f32 %0, %1, %2" : "=v"(r) : "v"(lo), "v"(hi));
    return r;
}
static __device__ __forceinline__ void gl2lds16(const unsigned short* g, unsigned short* l) {
    __builtin_amdgcn_global_load_lds(
        (const __attribute__((address_space(1))) unsigned int*)g,
        (__attribute__((address_space(3))) unsigned int*)l, 16, 0, 0);
}

// ---------------------------------------------------------------------------
// Transpose + cast: W fp32 [K][N] -> Wt bf16 [N][K]; optional column scale.
// ---------------------------------------------------------------------------
__global__ __launch_bounds__(256) void transpose_w(
    const float* __restrict__ W, unsigned short* __restrict__ Wt,
    int K, int N, int scale_ncols, float scale)
{
    __shared__ float T[64][68];
    const int tid = threadIdx.x;
    const int k0 = blockIdx.y * 64, n0 = blockIdx.x * 64;
    const int rr = tid >> 4;
    const int c4 = (tid & 15) * 4;

#pragma unroll
    for (int i = 0; i < 4; ++i) {
        int r = rr + 16 * i;
        *(float4*)&T[r][c4] = *(const float4*)&W[(size_t)(k0 + r) * N + n0 + c4];
    }
    __syncthreads();
#pragma unroll
    for (int i = 0; i < 4; ++i) {
        int nr = rr + 16 * i;
        float sc = (n0 + nr < scale_ncols) ? scale : 1.0f;
        unsigned short tmp[4];
#pragma unroll
        for (int j = 0; j < 4; ++j) tmp[j] = f2bf(T[c4 + j][nr] * sc);
        unsigned int p0 = (unsigned int)tmp[0] | ((unsigned int)tmp[1] << 16);
        unsigned int p1 = (unsigned int)tmp[2] | ((unsigned int)tmp[3] << 16);
        *(uint2*)&Wt[(size_t)(n0 + nr) * K + k0 + c4] = make_uint2(p0, p1);
    }
}

__global__ __launch_bounds__(256) void cast_plain(const float* __restrict__ src,
                                                  unsigned short* __restrict__ dst)
{
    int idx = blockIdx.x * 256 + threadIdx.x;
    float4 v = *(const float4*)&src[(size_t)idx * 4];
    unsigned int p0 = (unsigned int)f2bf(v.x) | ((unsigned int)f2bf(v.y) << 16);
    unsigned int p1 = (unsigned int)f2bf(v.z) | ((unsigned int)f2bf(v.w) << 16);
    *(uint2*)&dst[(size_t)idx * 4] = make_uint2(p0, p1);
}

// ---------------------------------------------------------------------------
// bf16 MFMA GEMM (m97 structure, 128x128): kept for the small K=512 GEMMs.
// OUT_MODE: 1 = bf16 C[M][N],
//           2 = bf16 transposed Ct[N][M] with k-interleave permutation on M
//               within each 32-row group (attn's in-register P A-frag).
// ---------------------------------------------------------------------------
template<int OUT_MODE>
__global__ __launch_bounds__(256) void gemm_bt(
    const unsigned short* __restrict__ A,
    const unsigned short* __restrict__ Bt,
    void* __restrict__ C,
    int K, int lda, int ldb, int ldc)
{
    __shared__ __align__(16) unsigned short As[128 * 32];
    __shared__ __align__(16) unsigned short Bs[128 * 32];

    const int tid  = threadIdx.x;
    const int w    = tid >> 6;
    const int lane = tid & 63;
    const int quad = lane >> 4;
    const int l15  = lane & 15;
    const int brow = blockIdx.y * 128;
    const int bcol = blockIdx.x * 128;
    const int wr   = (w >> 1) * 64;
    const int wc   = (w & 1) * 64;

    const int srow = lane >> 2;
    const int sseg = (lane & 3) * 8;
    const int r0   = w * 32;

    f32x4 acc[4][4];
#pragma unroll
    for (int mt = 0; mt < 4; ++mt)
#pragma unroll
        for (int nt = 0; nt < 4; ++nt) acc[mt][nt] = (f32x4){0.f, 0.f, 0.f, 0.f};

    const unsigned short* Ab = A  + (size_t)(brow + r0 + srow) * lda + sseg;
    const unsigned short* Bb = Bt + (size_t)(bcol + r0 + srow) * ldb + sseg;

    for (int k0 = 0; k0 < K; k0 += 32) {
        __syncthreads();
        gl2lds16(Ab + k0,                     As + r0 * 32);
        gl2lds16(Ab + k0 + (size_t)16 * lda,  As + (r0 + 16) * 32);
        gl2lds16(Bb + k0,                     Bs + r0 * 32);
        gl2lds16(Bb + k0 + (size_t)16 * ldb,  Bs + (r0 + 16) * 32);
        __syncthreads();

        bf16x8 af[4], bfr[4];
#pragma unroll
        for (int mt = 0; mt < 4; ++mt)
            af[mt] = __builtin_bit_cast(bf16x8,
                *(const uint4*)(As + (wr + mt * 16 + l15) * 32 + quad * 8));
#pragma unroll
        for (int nt = 0; nt < 4; ++nt)
            bfr[nt] = __builtin_bit_cast(bf16x8,
                *(const uint4*)(Bs + (wc + nt * 16 + l15) * 32 + quad * 8));
#pragma unroll
        for (int mt = 0; mt < 4; ++mt)
#pragma unroll
            for (int nt = 0; nt < 4; ++nt)
                acc[mt][nt] = __builtin_amdgcn_mfma_f32_16x16x32_bf16(
                    af[mt], bfr[nt], acc[mt][nt], 0, 0, 0);
    }

    if (OUT_MODE == 2) {
#pragma unroll
        for (int mt = 0; mt < 4; ++mt) {
            int row0 = brow + wr + mt * 16 + quad * 4;   // token base, %4 == 0
            int r5   = row0 & 31;
            int pos  = ((r5 & 15) >> 2) * 8 + ((r5 >> 4) << 2);
            int prow0 = (row0 & ~31) | pos;              // k-interleave permute
#pragma unroll
            for (int nt = 0; nt < 4; ++nt) {
                int col = bcol + wc + nt * 16 + l15;
                unsigned int p0 = (unsigned int)f2bf(acc[mt][nt][0]) |
                                  ((unsigned int)f2bf(acc[mt][nt][1]) << 16);
                unsigned int p1 = (unsigned int)f2bf(acc[mt][nt][2]) |
                                  ((unsigned int)f2bf(acc[mt][nt][3]) << 16);
                *(uint2*)&((unsigned short*)C)[(size_t)col * ldc + prow0] = make_uint2(p0, p1);
            }
        }
    } else {
#pragma unroll
        for (int mt = 0; mt < 4; ++mt)
#pragma unroll
            for (int i = 0; i < 4; ++i) {
                size_t row = (size_t)(brow + wr + mt * 16 + quad * 4 + i);
#pragma unroll
                for (int nt = 0; nt < 4; ++nt) {
                    int col = bcol + wc + nt * 16 + l15;
                    ((unsigned short*)C)[row * ldc + col] = f2bf(acc[mt][nt][i]);
                }
            }
    }
}

// ---------------------------------------------------------------------------
// 8-phase 256-wide GEMM, deadline-ordered staging + uniform counted vmcnt
// (unchanged from R6 — two scheduling variants measured neutral; frozen).
// OUT_MODE: 0 = fp32 C, 1 = bf16 C.
// ---------------------------------------------------------------------------
template<int OUT_MODE, int BN>
__global__ __launch_bounds__(512, 2) void gemm8p(
    const unsigned short* __restrict__ A,
    const unsigned short* __restrict__ Bt,
    void* __restrict__ C,
    int K, int lda, int ldb, int ldc)
{
    constexpr int BNF = BN / 64;        // n-frags per wave
    constexpr int LB  = BN / 64;        // B loads/wave/tile
    constexpr int HB  = LB / 2;         // B loads/wave per half
    constexpr int ASLOT = 256 * 64;
    constexpr int BSLOT = BN * 64;
    constexpr int SLOT  = ASLOT + BSLOT;
    constexpr int NW  = 3 + 2 * HB;     // uniform counted wait

    extern __shared__ __align__(16) unsigned short lds[];

    const int tid  = threadIdx.x;
    const int w    = tid >> 6;
    const int lane = tid & 63;
    const int quad = lane >> 4;
    const int l15  = lane & 15;
    const int wm   = w >> 2;            // 0..1
    const int wn   = w & 3;             // 0..3

    // XCD-aware bijective swizzle (nwg % 8 == 0 guaranteed by caller)
    int fid = blockIdx.y * gridDim.x + blockIdx.x;
    int nwg = gridDim.x * gridDim.y;
    int cpx = nwg >> 3;
    int swz = (fid & 7) * cpx + (fid >> 3);
    int bx  = swz % gridDim.x;
    int by  = swz / gridDim.x;
    const int brow = by * 256;
    const int bcol = bx * BN;

    const unsigned short* Ab = A  + (size_t)brow * lda;
    const unsigned short* Bb = Bt + (size_t)bcol * ldb;

    // chunk geometry: 8 rows x 8 col-blks; all chunk base rows are %8==0,
    // so row&7 == lane>>3 for every piece -> one swizzle term serves all.
    const int lr   = lane >> 3;
    const int lswz = ((lane & 7) ^ lr) * 8;
    const int arow0 = (w < 4) ? (w * 8) : (128 + (w - 4) * 8);
    const int asrc  = (arow0 + lr) * lda + lswz;
    int brow0[HB], bsrc[HB];
#pragma unroll
    for (int c = 0; c < HB; ++c) {
        brow0[c] = (w * HB + c) * 8;
        bsrc[c]  = (brow0[c] + lr) * ldb + lswz;
    }

    f32x4 acc[8][BNF];
#pragma unroll
    for (int mf = 0; mf < 8; ++mf)
#pragma unroll
        for (int nf = 0; nf < BNF; ++nf) acc[mf][nf] = (f32x4){0.f, 0.f, 0.f, 0.f};

    const int NT = K >> 6;

    auto stageA = [&](int s, int tt, int p) {
        gl2lds16(Ab + tt * 64 + p * 32 * lda + asrc,
                 lds + s * SLOT + (arow0 + p * 32) * 64);
    };
    auto stageB = [&](int s, int tt, int h) {
#pragma unroll
        for (int c = 0; c < HB; ++c)
            gl2lds16(Bb + tt * 64 + h * (BN / 2) * ldb + bsrc[c],
                     lds + s * SLOT + ASLOT + (brow0[c] + h * (BN / 2)) * 64);
    };

    // prologue: steady-state issue order
    stageB(0, 0, 0); stageB(0, 0, 1);           // B(T0)
    stageA(0, 0, 0); stageA(0, 0, 1); stageA(0, 0, 2);
    stageB(1, 1, 0);                            // B0(T1)
    stageA(0, 0, 3);
    stageB(1, 1, 1);                            // B1(T1)
    asm volatile("s_waitcnt vmcnt(%0)" :: "i"(NW) : "memory");
    __builtin_amdgcn_s_barrier();

#pragma unroll 1
    for (int t = 0; t < NT; ++t) {
        const int s  = t & 1;
        const int s1 = s ^ 1;
        const int t1 = (t + 1 < NT) ? t + 1 : 0;            // wrap: dead-region
        const int t2 = (t + 2 < NT) ? t + 2 : t + 2 - NT;   // keep-alive stages
        const unsigned short* As = lds + s * SLOT;
        const unsigned short* Bs = As + ASLOT;

        bf16x8 bq[BNF][2], af[2][2];

#pragma unroll
        for (int ph = 0; ph < 4; ++ph) {
            if (ph == 0) {
#pragma unroll
                for (int nf = 0; nf < BNF; ++nf)
#pragma unroll
                    for (int kk = 0; kk < 2; ++kk) {
                        int r = wn * (BN / 4) + nf * 16 + l15;
                        bq[nf][kk] = __builtin_bit_cast(bf16x8,
                            *(const uint4*)(Bs + r * 64 + (((kk * 4 + quad) ^ (r & 7)) * 8)));
                    }
            }
#pragma unroll
            for (int m = 0; m < 2; ++m)
#pragma unroll
                for (int kk = 0; kk < 2; ++kk) {
                    int r = wm * 128 + (ph * 2 + m) * 16 + l15;
                    af[m][kk] = __builtin_bit_cast(bf16x8,
                        *(const uint4*)(As + r * 64 + (((kk * 4 + quad) ^ (r & 7)) * 8)));
                }
            // deadline-ordered staging: A piece ph of t+1; B halves of t+2
            stageA(s1, t1, ph);
            if (ph == 2) stageB(s, t2, 0);
            if (ph == 3) stageB(s, t2, 1);
            __builtin_amdgcn_s_barrier();
            __builtin_amdgcn_s_setprio(1);
#pragma unroll
            for (int m = 0; m < 2; ++m)
#pragma unroll
                for (int nf = 0; nf < BNF; ++nf)
#pragma unroll
                    for (int kk = 0; kk < 2; ++kk)
                        acc[ph * 2 + m][nf] = __builtin_amdgcn_mfma_f32_16x16x32_bf16(
                            af[m][kk], bq[nf][kk], acc[ph * 2 + m][nf], 0, 0, 0);
            __builtin_amdgcn_s_setprio(0);
            asm volatile("s_waitcnt vmcnt(%0)" :: "i"(NW) : "memory");
            __builtin_amdgcn_s_barrier();
        }
    }
    asm volatile("s_waitcnt vmcnt(0)" ::: "memory");   // drain wrap stages

    // epilogue: per-wave 128 x BN/4 C-write
#pragma unroll
    for (int mf = 0; mf < 8; ++mf) {
#pragma unroll
        for (int i = 0; i < 4; ++i) {
            size_t row = (size_t)(brow + wm * 128 + mf * 16 + quad * 4 + i);
#pragma unroll
            for (int nf = 0; nf < BNF; ++nf) {
                int col = bcol + wn * (BN / 4) + nf * 16 + l15;
                if (OUT_MODE == 1)
                    ((unsigned short*)C)[row * ldc + col] = f2bf(acc[mf][nf][i]);
                else
                    ((float*)C)[row * ldc + col] = acc[mf][nf][i];
            }
        }
    }
}

// ---------------------------------------------------------------------------
// RoPE in-place on bf16 q (inside qkvb) and bf16 k (kb).
// ---------------------------------------------------------------------------
__global__ __launch_bounds__(256) void rope_bf16(unsigned short* __restrict__ qkvb,
                                                 unsigned short* __restrict__ kb)
{
    int idx = blockIdx.x * 256 + threadIdx.x;
    int i    = idx & 31;
    int head = (idx >> 5) % 20;
    int t    = idx / (20 * 32);
    if (t >= NTOK) return;
    int pos = t & (SEQ - 1);

    const float LOG_BASE_OVER_32 = 0.28782313662425572f; // ln(10000)/32
    float ang = (float)pos * __expf(-(float)i * LOG_BASE_OVER_32);
    float c = cosf(ang);
    float sn = sinf(ang);

    unsigned short* p;
    if (head < NH) p = qkvb + (size_t)t * QKV_W + head * D_QKD + D_NOPE;
    else           p = kb   + (size_t)t * KW    + (head - NH) * D_QKD + D_NOPE;

    float x1 = bf2f(p[i]), x2 = bf2f(p[i + 32]);
    p[i]      = f2bf(x1 * c - x2 * sn);
    p[i + 32] = f2bf(x2 * c + x1 * sn);
}

// ---------------------------------------------------------------------------
// MFMA flash attention, causal, GQA. Fixed m=0 softmax in exp2 domain.
// R7: 8 waves / 512 threads per block covering 128 q-rows — halves the
// grid-wide tile-iteration count (DMA issues, addressing, barriers per
// q-row all halve; MFMA/exp2 per q-row unchanged). K/V LDS tiles are the
// same 40 KB -> 2 blocks/CU, all 512 blocks co-resident.
// Staging roles: waves 0-1 (lightest causal load) stage V (4 loads each),
// waves 2-7 stage K (2 loads each).
// XCD mapping: bid&7 = (kvh*2+b) -> all 64 blocks sharing one K/V land on
// one XCD (round-robin dispatch) => K/V (1.3 MB) L2-resident per XCD.
// Balanced qt pairing: CU gets g and g+8 -> qt {15-g, g}, constant work.
// In-register P via swapped QK^T + k-permuted V; wave-uniform mask skip;
// v_cvt_pk_bf16_f32 P-pack; setprio around MFMA clusters.
// ---------------------------------------------------------------------------
__global__ __launch_bounds__(512) void attn_mfma(
    const unsigned short* __restrict__ qkvb,
    const unsigned short* __restrict__ kb,
    const unsigned short* __restrict__ vt,
    unsigned short* __restrict__ attnb)
{
    __shared__ __align__(16) unsigned short KsL[2 * 32 * 192];  // 2 x 12 KB
    __shared__ __align__(16) unsigned short VtL[2 * 128 * 32];  // 2 x 8 KB

    const int tid  = threadIdx.x;
    const int w    = tid >> 6;            // 0..7
    const int lane = tid & 63;
    const int quad = lane >> 4;
    const int l15  = lane & 15;

    const int bid = blockIdx.x;           // 512 blocks
    const int xcd = bid & 7;
    const int kvh = xcd >> 1;
    const int b   = xcd & 1;
    const int rest = bid >> 3;            // 0..63
    const int h   = kvh * 4 + (rest & 3);
    const int g   = rest >> 2;            // 0..15
    const int qt  = (g < 8) ? (15 - g) : (g - 8);   // balanced pairing
    const int q0  = qt * 128;

    const int x7   = l15 & 7;             // K read swizzle
    const int vx   = (l15 >> 1) & 3;      // V read swizzle

    // Per-lane DMA source offsets (shorts), tile-invariant.
    // waves 2..7: K stagers (2 x 16B-blocks); waves 0..1: V stagers (4).
    int koff[2], voff[4];
#pragma unroll
    for (int it = 0; it < 2; ++it) {
        int bidx = ((w - 2) * 2 + it) * 64 + lane;    // 0..767 for w in [2,8)
        int row  = bidx / 24;
        int sblk = bidx - row * 24;
        int gblk = sblk ^ (row & 7);
        koff[it] = row * KW + gblk * 8;
    }
#pragma unroll
    for (int it = 0; it < 4; ++it) {
        int bidx = (w * 4 + it) * 64 + lane;          // 0..511 for w in [0,2)
        int row  = bidx >> 2;
        int gblk = (bidx & 3) ^ ((row >> 1) & 3);
        voff[it] = row * NTOK + gblk * 8;
    }
    const unsigned short* kp0 = kb + (size_t)(b * SEQ) * KW + kvh * D_QKD;
    const unsigned short* vp0 = vt + (size_t)(kvh * 128) * NTOK + b * SEQ;

    const int q0w  = q0 + w * 16;
    const int wmax = q0w + 15;

    bf16x8 qf[6];
    {
        const unsigned short* qp =
            qkvb + (size_t)(b * SEQ + q0w + l15) * QKV_W + h * D_QKD + quad * 8;
#pragma unroll
        for (int t = 0; t < 6; ++t)
            qf[t] = __builtin_bit_cast(bf16x8, *(const uint4*)(qp + t * 32));
    }

    f32x4 o[8];
#pragma unroll
    for (int c = 0; c < 8; ++c) o[c] = (f32x4){0.f, 0.f, 0.f, 0.f};
    float lp = 0.f;     // partial l for q-row l15 over this lane's k-slots

    const int nt = 4 * qt + 4;

    // DMA tile 0 into buffer 0 (role-split staging)
    if (w >= 2) {
#pragma unroll
        for (int it = 0; it < 2; ++it)
            gl2lds16(kp0 + koff[it], KsL + ((w - 2) * 2 + it) * 512);
    } else {
#pragma unroll
        for (int it = 0; it < 4; ++it)
            gl2lds16(vp0 + voff[it], VtL + (w * 4 + it) * 512);
    }
    __syncthreads();   // vmcnt drain: tile 0 staged

    for (int tk = 0; tk < nt; ++tk) {
        const int k0  = tk * 32;
        const int cur = tk & 1;

        // Issue DMA for tile tk+1 into the other buffer (no wait, no regs)
        if (tk + 1 < nt) {
            const int nxt = cur ^ 1;
            if (w >= 2) {
                const unsigned short* ks = kp0 + (size_t)(k0 + 32) * KW;
#pragma unroll
                for (int it = 0; it < 2; ++it)
                    gl2lds16(ks + koff[it], KsL + nxt * (32 * 192) + ((w - 2) * 2 + it) * 512);
            } else {
                const unsigned short* vs = vp0 + (k0 + 32);
#pragma unroll
                for (int it = 0; it < 4; ++it)
                    gl2lds16(vs + voff[it], VtL + nxt * (128 * 32) + (w * 4 + it) * 512);
            }
        }

        if (k0 <= wmax) {
            const unsigned short* Kc = KsL + cur * (32 * 192);
            const unsigned short* Vc = VtL + cur * (128 * 32);

            // ---- scores: S^T[32k][16q] = K @ Q^T (log2 domain), swapped ----
            f32x4 s[2];
            __builtin_amdgcn_s_setprio(1);
#pragma unroll
            for (int j = 0; j < 2; ++j) {
                f32x4 acc = {0.f, 0.f, 0.f, 0.f};
                const unsigned short* kr = Kc + (j * 16 + l15) * 192;
#pragma unroll
                for (int t = 0; t < 6; ++t) {
                    int sblk = (quad + 4 * t) ^ x7;
                    bf16x8 kf = __builtin_bit_cast(bf16x8, *(const uint4*)(kr + sblk * 8));
                    acc = __builtin_amdgcn_mfma_f32_16x16x32_bf16(kf, qf[t], acc, 0, 0, 0);
                }
                s[j] = acc;
            }
            __builtin_amdgcn_s_setprio(0);
            // lane holds S[q = l15][k = k0 + j*16 + quad*4 + i]

            // ---- softmax, fixed m=0, exp2; wave-uniform mask skip ----
            if (k0 + 31 <= q0w) {
#pragma unroll
                for (int j = 0; j < 2; ++j)
#pragma unroll
                    for (int i = 0; i < 4; ++i) {
                        float p = __builtin_amdgcn_exp2f(s[j][i]);
                        s[j][i] = p;
                        lp += p;
                    }
            } else {
                const int qrow = q0w + l15;
#pragma unroll
                for (int j = 0; j < 2; ++j)
#pragma unroll
                    for (int i = 0; i < 4; ++i) {
                        int kidx = k0 + j * 16 + quad * 4 + i;
                        float p = (kidx <= qrow) ? __builtin_amdgcn_exp2f(s[j][i]) : 0.f;
                        s[j][i] = p;
                        lp += p;
                    }
            }

            // ---- P -> A-frag: HW pack, pure in-register (k-permuted V) ----
            uint4 pk;
            pk.x = cvt_pk_bf16(s[0][0], s[0][1]);
            pk.y = cvt_pk_bf16(s[0][2], s[0][3]);
            pk.z = cvt_pk_bf16(s[1][0], s[1][1]);
            pk.w = cvt_pk_bf16(s[1][2], s[1][3]);
            bf16x8 pa = __builtin_bit_cast(bf16x8, pk);

            // ---- PV: 8 MFMAs, swizzled V frags ----
            __builtin_amdgcn_s_setprio(1);
#pragma unroll
            for (int c = 0; c < 8; ++c) {
                bf16x8 vf = __builtin_bit_cast(bf16x8,
                    *(const uint4*)(Vc + (c * 16 + l15) * 32 + ((quad ^ vx) * 8)));
                o[c] = __builtin_amdgcn_mfma_f32_16x16x32_bf16(pa, vf, o[c], 0, 0, 0);
            }
            __builtin_amdgcn_s_setprio(0);
        }

        __syncthreads();   // waves done with buf cur; DMA for tk+1 drained
    }

    // ---- epilogue: total l per q-row, redistribute to C-layout rows ----
    float lt = lp;
    lt += __shfl_xor(lt, 16);
    lt += __shfl_xor(lt, 32);      // all lanes: l for q-row = their l15

#pragma unroll
    for (int i = 0; i < 4; ++i) {
        float inv = 1.0f / __shfl(lt, (lane & 48) | (quad * 4 + i));
        size_t rowoff = (size_t)(b * SEQ + q0w + quad * 4 + i) * AW + h * D_VV + l15;
#pragma unroll
        for (int c = 0; c < 8; ++c)
            attnb[rowoff + c * 16] = f2bf(o[c][i] * inv);
    }
}

// ---------------------------------------------------------------------------
extern "C" void kernel_launch(void* const* d_in, const int* in_sizes, int n_in,
                              void* d_out, int out_size, void* d_ws, size_t ws_size,
                              hipStream_t stream)
{
    const float* X     = (const float*)d_in[0];
    const float* Wqkv  = (const float*)d_in[1];
    const float* Wk_up = (const float*)d_in[2];
    const float* Wv_up = (const float*)d_in[3];
    const float* Wo    = (const float*)d_in[4];
    float* out = (float*)d_out;

    unsigned short* Xb    = (unsigned short*)d_ws;                   // [4096][2048]
    unsigned short* Wqt   = Xb    + (size_t)NTOK * HIDN;             // [3584][2048]
    unsigned short* Wkt   = Wqt   + (size_t)QKV_W * HIDN;            // [768][512]
    unsigned short* Wvt   = Wkt   + (size_t)KW * LORA;               // [512][512]
    unsigned short* Wot   = Wvt   + (size_t)VW * LORA;               // [2048][2048]
    unsigned short* qkvb  = Wot   + (size_t)HIDN * AW;               // [4096][3584]
    unsigned short* kb    = qkvb  + (size_t)NTOK * QKV_W;            // [4096][768]
    unsigned short* vtb   = kb    + (size_t)NTOK * KW;               // [512][4096] (V^T, k-permuted)
    unsigned short* attnb = vtb   + (size_t)VW * NTOK;               // [4096][2048]

    cast_plain<<<NTOK * HIDN / 4 / 256, 256, 0, stream>>>(X, Xb);
    // q columns pre-scaled by (1/sqrt(192)) * log2(e): softmax runs in exp2 domain
    transpose_w<<<dim3(QKV_W / 64, HIDN / 64), 256, 0, stream>>>(
        Wqkv, Wqt, HIDN, QKV_W, NH * D_QKD, QSCALE * LOG2E);
    transpose_w<<<dim3(KW / 64, LORA / 64), 256, 0, stream>>>(Wk_up, Wkt, LORA, KW, 0, 1.0f);
    transpose_w<<<dim3(VW / 64, LORA / 64), 256, 0, stream>>>(Wv_up, Wvt, LORA, VW, 0, 1.0f);
    transpose_w<<<dim3(AW / 64, HIDN / 64), 256, 0, stream>>>(Wo, Wot, HIDN, AW, 0, 1.0f);

    // qkvb = Xb @ Wqt^T (bf16; q cols pre-scaled) — 8-phase 256x256
    gemm8p<1, 256><<<dim3(QKV_W / 256, NTOK / 256), 512, 131072, stream>>>(
        Xb, Wqt, qkvb, HIDN, HIDN, HIDN, QKV_W);

    // kb = c_kv @ Wkt^T (bf16) ; vt = (c_kv @ Wvt^T)^T (bf16, k-permuted cols)
    gemm_bt<1><<<dim3(KW / 128, NTOK / 128), 256, 0, stream>>>(
        qkvb + NH * D_QKD, Wkt, kb, LORA, QKV_W, LORA, KW);
    gemm_bt<2><<<dim3(VW / 128, NTOK / 128), 256, 0, stream>>>(
        qkvb + NH * D_QKD, Wvt, vtb, LORA, QKV_W, LORA, NTOK);

    rope_bf16<<<(NTOK * 20 * 32 + 255) / 256, 256, 0, stream>>>(qkvb, kb);

    attn_mfma<<<dim3(512), 512, 0, stream>>>(qkvb, kb, vtb, attnb);

    // out = attnb @ Wot^T (fp32) — 8-phase 256x128 (grid 256 = full CU fill)
    gemm8p<0, 128><<<dim3(HIDN / 128, NTOK / 256), 512, 98304, stream>>>(
        attnb, Wot, out, AW, AW, AW, HIDN);
}

// Round 8
// 317.843 us; speedup vs baseline: 1.4956x; 1.0264x over previous
//
#include <hip/hip_runtime.h>
#include <hip/hip_bf16.h>
#include <math.h>

#define HIDN  2048
#define NH    16
#define NKV   4
#define LORA  512
#define D_ROPE 64
#define D_NOPE 128
#define D_VV  128
#define D_QKD 192
#define BATCH 2
#define SEQ   2048
#define NTOK  (BATCH*SEQ)          // 4096
#define QKV_W (NH*D_QKD + LORA)    // 3584
#define KW    (NKV*D_QKD)          // 768
#define VW    (NKV*D_VV)           // 512
#define AW    (NH*D_VV)            // 2048
#define QSCALE 0.07216878364870323f   // 1/sqrt(192)
#define LOG2E  1.4426950408889634f

typedef __attribute__((ext_vector_type(8))) __bf16 bf16x8;
typedef __attribute__((ext_vector_type(4))) float f32x4;

static __device__ __forceinline__ unsigned short f2bf(float f) {
    unsigned int u = __builtin_bit_cast(unsigned int, f);
    u += 0x7fffu + ((u >> 16) & 1u);          // round-to-nearest-even
    return (unsigned short)(u >> 16);
}
static __device__ __forceinline__ float bf2f(unsigned short v) {
    unsigned int u = (unsigned int)v << 16;
    return __builtin_bit_cast(float, u);
}
static __device__ __forceinline__ unsigned int cvt_pk_bf16(float lo, float hi) {
    unsigned int r;
    asm("v_cvt_pk_bf16_f32 %0, %1, %2" : "=v"(r) : "v"(lo), "v"(hi));
    return r;
}
static __device__ __forceinline__ void gl2lds16(const unsigned short* g, unsigned short* l) {
    __builtin_amdgcn_global_load_lds(
        (const __attribute__((address_space(1))) unsigned int*)g,
        (__attribute__((address_space(3))) unsigned int*)l, 16, 0, 0);
}

// ---------------------------------------------------------------------------
// Transpose + cast: W fp32 [K][N] -> Wt bf16 [N][K]; optional column scale.
// ---------------------------------------------------------------------------
__global__ __launch_bounds__(256) void transpose_w(
    const float* __restrict__ W, unsigned short* __restrict__ Wt,
    int K, int N, int scale_ncols, float scale)
{
    __shared__ float T[64][68];
    const int tid = threadIdx.x;
    const int k0 = blockIdx.y * 64, n0 = blockIdx.x * 64;
    const int rr = tid >> 4;
    const int c4 = (tid & 15) * 4;

#pragma unroll
    for (int i = 0; i < 4; ++i) {
        int r = rr + 16 * i;
        *(float4*)&T[r][c4] = *(const float4*)&W[(size_t)(k0 + r) * N + n0 + c4];
    }
    __syncthreads();
#pragma unroll
    for (int i = 0; i < 4; ++i) {
        int nr = rr + 16 * i;
        float sc = (n0 + nr < scale_ncols) ? scale : 1.0f;
        unsigned short tmp[4];
#pragma unroll
        for (int j = 0; j < 4; ++j) tmp[j] = f2bf(T[c4 + j][nr] * sc);
        unsigned int p0 = (unsigned int)tmp[0] | ((unsigned int)tmp[1] << 16);
        unsigned int p1 = (unsigned int)tmp[2] | ((unsigned int)tmp[3] << 16);
        *(uint2*)&Wt[(size_t)(n0 + nr) * K + k0 + c4] = make_uint2(p0, p1);
    }
}

__global__ __launch_bounds__(256) void cast_plain(const float* __restrict__ src,
                                                  unsigned short* __restrict__ dst)
{
    int idx = blockIdx.x * 256 + threadIdx.x;
    float4 v = *(const float4*)&src[(size_t)idx * 4];
    unsigned int p0 = (unsigned int)f2bf(v.x) | ((unsigned int)f2bf(v.y) << 16);
    unsigned int p1 = (unsigned int)f2bf(v.z) | ((unsigned int)f2bf(v.w) << 16);
    *(uint2*)&dst[(size_t)idx * 4] = make_uint2(p0, p1);
}

// ---------------------------------------------------------------------------
// bf16 MFMA GEMM (m97 structure, 128x128): kept for the small K=512 GEMMs.
// OUT_MODE: 1 = bf16 C[M][N],
//           2 = bf16 transposed Ct[N][M] with k-interleave permutation on M
//               within each 32-row group (attn's in-register P A-frag).
// ---------------------------------------------------------------------------
template<int OUT_MODE>
__global__ __launch_bounds__(256) void gemm_bt(
    const unsigned short* __restrict__ A,
    const unsigned short* __restrict__ Bt,
    void* __restrict__ C,
    int K, int lda, int ldb, int ldc)
{
    __shared__ __align__(16) unsigned short As[128 * 32];
    __shared__ __align__(16) unsigned short Bs[128 * 32];

    const int tid  = threadIdx.x;
    const int w    = tid >> 6;
    const int lane = tid & 63;
    const int quad = lane >> 4;
    const int l15  = lane & 15;
    const int brow = blockIdx.y * 128;
    const int bcol = blockIdx.x * 128;
    const int wr   = (w >> 1) * 64;
    const int wc   = (w & 1) * 64;

    const int srow = lane >> 2;
    const int sseg = (lane & 3) * 8;
    const int r0   = w * 32;

    f32x4 acc[4][4];
#pragma unroll
    for (int mt = 0; mt < 4; ++mt)
#pragma unroll
        for (int nt = 0; nt < 4; ++nt) acc[mt][nt] = (f32x4){0.f, 0.f, 0.f, 0.f};

    const unsigned short* Ab = A  + (size_t)(brow + r0 + srow) * lda + sseg;
    const unsigned short* Bb = Bt + (size_t)(bcol + r0 + srow) * ldb + sseg;

    for (int k0 = 0; k0 < K; k0 += 32) {
        __syncthreads();
        gl2lds16(Ab + k0,                     As + r0 * 32);
        gl2lds16(Ab + k0 + (size_t)16 * lda,  As + (r0 + 16) * 32);
        gl2lds16(Bb + k0,                     Bs + r0 * 32);
        gl2lds16(Bb + k0 + (size_t)16 * ldb,  Bs + (r0 + 16) * 32);
        __syncthreads();

        bf16x8 af[4], bfr[4];
#pragma unroll
        for (int mt = 0; mt < 4; ++mt)
            af[mt] = __builtin_bit_cast(bf16x8,
                *(const uint4*)(As + (wr + mt * 16 + l15) * 32 + quad * 8));
#pragma unroll
        for (int nt = 0; nt < 4; ++nt)
            bfr[nt] = __builtin_bit_cast(bf16x8,
                *(const uint4*)(Bs + (wc + nt * 16 + l15) * 32 + quad * 8));
#pragma unroll
        for (int mt = 0; mt < 4; ++mt)
#pragma unroll
            for (int nt = 0; nt < 4; ++nt)
                acc[mt][nt] = __builtin_amdgcn_mfma_f32_16x16x32_bf16(
                    af[mt], bfr[nt], acc[mt][nt], 0, 0, 0);
    }

    if (OUT_MODE == 2) {
#pragma unroll
        for (int mt = 0; mt < 4; ++mt) {
            int row0 = brow + wr + mt * 16 + quad * 4;   // token base, %4 == 0
            int r5   = row0 & 31;
            int pos  = ((r5 & 15) >> 2) * 8 + ((r5 >> 4) << 2);
            int prow0 = (row0 & ~31) | pos;              // k-interleave permute
#pragma unroll
            for (int nt = 0; nt < 4; ++nt) {
                int col = bcol + wc + nt * 16 + l15;
                unsigned int p0 = (unsigned int)f2bf(acc[mt][nt][0]) |
                                  ((unsigned int)f2bf(acc[mt][nt][1]) << 16);
                unsigned int p1 = (unsigned int)f2bf(acc[mt][nt][2]) |
                                  ((unsigned int)f2bf(acc[mt][nt][3]) << 16);
                *(uint2*)&((unsigned short*)C)[(size_t)col * ldc + prow0] = make_uint2(p0, p1);
            }
        }
    } else {
#pragma unroll
        for (int mt = 0; mt < 4; ++mt)
#pragma unroll
            for (int i = 0; i < 4; ++i) {
                size_t row = (size_t)(brow + wr + mt * 16 + quad * 4 + i);
#pragma unroll
                for (int nt = 0; nt < 4; ++nt) {
                    int col = bcol + wc + nt * 16 + l15;
                    ((unsigned short*)C)[row * ldc + col] = f2bf(acc[mt][nt][i]);
                }
            }
    }
}

// ---------------------------------------------------------------------------
// 8-phase 256-wide GEMM, LEAN-SYNC schedule (R8): C = A[M,K] @ Bt[N,K]^T.
// BM=256, BN in {256,128}, BK=64, 512 thr = 8 waves. 1 block/CU (128/96 KB
// LDS) -> sync stalls are unhidden, so minimize sync ops per K-tile:
//   2 barriers + 1 counted vmcnt per tile (was 8 + 4).
// Staging (issue order == FIFO deadline order):
//   ph0: A0,A1(t+1)->s^1   ph1: A2,A3(t+1)->s^1   [barrier: B-region protect]
//   ph2: B0(t+2)->s        ph3: B1(t+2)->s        [vmcnt(2*HB); barrier]
// FIFO proof: tile-end outstanding = B(t+1)[2HB old] + A(t+1)[4] + B(t+2)[2HB]
//   -> vmcnt(2*HB) completes exactly {B(t+1), A(t+1)} (what t+1 reads) and
//   leaves B(t+2) in flight. Never drains; >=3 phases of flight per load.
// Safety: A stages always write the non-read slot (no barrier needed);
//   B(t+2) overwrites slot-s B which is dead after ph0's reg-cache reads --
//   the ph1-end barrier orders all waves past ph0 before any ph2 stage.
// OUT_MODE: 0 = fp32 C, 1 = bf16 C.
// ---------------------------------------------------------------------------
template<int OUT_MODE, int BN>
__global__ __launch_bounds__(512, 2) void gemm8p(
    const unsigned short* __restrict__ A,
    const unsigned short* __restrict__ Bt,
    void* __restrict__ C,
    int K, int lda, int ldb, int ldc)
{
    constexpr int BNF = BN / 64;        // n-frags per wave
    constexpr int HB  = BN / 128;       // loads per stageB call
    constexpr int NWT = 2 * HB;         // tile-end counted wait
    constexpr int ASLOT = 256 * 64;
    constexpr int BSLOT = BN * 64;
    constexpr int SLOT  = ASLOT + BSLOT;

    extern __shared__ __align__(16) unsigned short lds[];

    const int tid  = threadIdx.x;
    const int w    = tid >> 6;
    const int lane = tid & 63;
    const int quad = lane >> 4;
    const int l15  = lane & 15;
    const int wm   = w >> 2;            // 0..1
    const int wn   = w & 3;             // 0..3

    // XCD-aware bijective swizzle (nwg % 8 == 0 guaranteed by caller)
    int fid = blockIdx.y * gridDim.x + blockIdx.x;
    int nwg = gridDim.x * gridDim.y;
    int cpx = nwg >> 3;
    int swz = (fid & 7) * cpx + (fid >> 3);
    int bx  = swz % gridDim.x;
    int by  = swz / gridDim.x;
    const int brow = by * 256;
    const int bcol = bx * BN;

    const unsigned short* Ab = A  + (size_t)brow * lda;
    const unsigned short* Bb = Bt + (size_t)bcol * ldb;

    // chunk geometry: 8 rows x 8 col-blks; all chunk base rows are %8==0,
    // so row&7 == lane>>3 for every piece -> one swizzle term serves all.
    const int lr   = lane >> 3;
    const int lswz = ((lane & 7) ^ lr) * 8;
    const int arow0 = (w < 4) ? (w * 8) : (128 + (w - 4) * 8);
    const int asrc  = (arow0 + lr) * lda + lswz;
    int brow0[HB], bsrc[HB];
#pragma unroll
    for (int c = 0; c < HB; ++c) {
        brow0[c] = (w * HB + c) * 8;
        bsrc[c]  = (brow0[c] + lr) * ldb + lswz;
    }

    f32x4 acc[8][BNF];
#pragma unroll
    for (int mf = 0; mf < 8; ++mf)
#pragma unroll
        for (int nf = 0; nf < BNF; ++nf) acc[mf][nf] = (f32x4){0.f, 0.f, 0.f, 0.f};

    const int NT = K >> 6;

    auto stageA = [&](int s, int tt, int p) {
        gl2lds16(Ab + tt * 64 + p * 32 * lda + asrc,
                 lds + s * SLOT + (arow0 + p * 32) * 64);
    };
    auto stageB = [&](int s, int tt, int h) {
#pragma unroll
        for (int c = 0; c < HB; ++c)
            gl2lds16(Bb + tt * 64 + h * (BN / 2) * ldb + bsrc[c],
                     lds + s * SLOT + ASLOT + (brow0[c] + h * (BN / 2)) * 64);
    };

    // prologue: B(T0), A(T0), B(T1); wait leaves B(T1) in flight
    stageB(0, 0, 0); stageB(0, 0, 1);
    stageA(0, 0, 0); stageA(0, 0, 1); stageA(0, 0, 2); stageA(0, 0, 3);
    stageB(1, 1, 0); stageB(1, 1, 1);
    asm volatile("s_waitcnt vmcnt(%0)" :: "i"(NWT) : "memory");
    __builtin_amdgcn_s_barrier();

#pragma unroll 1
    for (int t = 0; t < NT; ++t) {
        const int s  = t & 1;
        const int s1 = s ^ 1;
        const int t1 = (t + 1 < NT) ? t + 1 : 0;            // wrap: dead-region
        const int t2 = (t + 2 < NT) ? t + 2 : t + 2 - NT;   // keep-alive stages
        const unsigned short* As = lds + s * SLOT;
        const unsigned short* Bs = As + ASLOT;

        bf16x8 bq[BNF][2], af[2][2];

        // ---- ph0: B frags + A quadrant 0; stage A0,A1(t+1) ----
#pragma unroll
        for (int nf = 0; nf < BNF; ++nf)
#pragma unroll
            for (int kk = 0; kk < 2; ++kk) {
                int r = wn * (BN / 4) + nf * 16 + l15;
                bq[nf][kk] = __builtin_bit_cast(bf16x8,
                    *(const uint4*)(Bs + r * 64 + (((kk * 4 + quad) ^ (r & 7)) * 8)));
            }
#pragma unroll
        for (int m = 0; m < 2; ++m)
#pragma unroll
            for (int kk = 0; kk < 2; ++kk) {
                int r = wm * 128 + m * 16 + l15;
                af[m][kk] = __builtin_bit_cast(bf16x8,
                    *(const uint4*)(As + r * 64 + (((kk * 4 + quad) ^ (r & 7)) * 8)));
            }
        stageA(s1, t1, 0); stageA(s1, t1, 1);
        __builtin_amdgcn_s_setprio(1);
#pragma unroll
        for (int m = 0; m < 2; ++m)
#pragma unroll
            for (int nf = 0; nf < BNF; ++nf)
#pragma unroll
                for (int kk = 0; kk < 2; ++kk)
                    acc[m][nf] = __builtin_amdgcn_mfma_f32_16x16x32_bf16(
                        af[m][kk], bq[nf][kk], acc[m][nf], 0, 0, 0);
        __builtin_amdgcn_s_setprio(0);

        // ---- ph1: A quadrant 1; stage A2,A3(t+1) ----
#pragma unroll
        for (int m = 0; m < 2; ++m)
#pragma unroll
            for (int kk = 0; kk < 2; ++kk) {
                int r = wm * 128 + (2 + m) * 16 + l15;
                af[m][kk] = __builtin_bit_cast(bf16x8,
                    *(const uint4*)(As + r * 64 + (((kk * 4 + quad) ^ (r & 7)) * 8)));
            }
        stageA(s1, t1, 2); stageA(s1, t1, 3);
        __builtin_amdgcn_s_setprio(1);
#pragma unroll
        for (int m = 0; m < 2; ++m)
#pragma unroll
            for (int nf = 0; nf < BNF; ++nf)
#pragma unroll
                for (int kk = 0; kk < 2; ++kk)
                    acc[2 + m][nf] = __builtin_amdgcn_mfma_f32_16x16x32_bf16(
                        af[m][kk], bq[nf][kk], acc[2 + m][nf], 0, 0, 0);
        __builtin_amdgcn_s_setprio(0);
        __builtin_amdgcn_s_barrier();      // all waves past ph0 B-reads

        // ---- ph2: A quadrant 2; stage B0(t+2) into freed slot-s B ----
#pragma unroll
        for (int m = 0; m < 2; ++m)
#pragma unroll
            for (int kk = 0; kk < 2; ++kk) {
                int r = wm * 128 + (4 + m) * 16 + l15;
                af[m][kk] = __builtin_bit_cast(bf16x8,
                    *(const uint4*)(As + r * 64 + (((kk * 4 + quad) ^ (r & 7)) * 8)));
            }
        stageB(s, t2, 0);
        __builtin_amdgcn_s_setprio(1);
#pragma unroll
        for (int m = 0; m < 2; ++m)
#pragma unroll
            for (int nf = 0; nf < BNF; ++nf)
#pragma unroll
                for (int kk = 0; kk < 2; ++kk)
                    acc[4 + m][nf] = __builtin_amdgcn_mfma_f32_16x16x32_bf16(
                        af[m][kk], bq[nf][kk], acc[4 + m][nf], 0, 0, 0);
        __builtin_amdgcn_s_setprio(0);

        // ---- ph3: A quadrant 3; stage B1(t+2); tile-end wait ----
#pragma unroll
        for (int m = 0; m < 2; ++m)
#pragma unroll
            for (int kk = 0; kk < 2; ++kk) {
                int r = wm * 128 + (6 + m) * 16 + l15;
                af[m][kk] = __builtin_bit_cast(bf16x8,
                    *(const uint4*)(As + r * 64 + (((kk * 4 + quad) ^ (r & 7)) * 8)));
            }
        stageB(s, t2, 1);
        __builtin_amdgcn_s_setprio(1);
#pragma unroll
        for (int m = 0; m < 2; ++m)
#pragma unroll
            for (int nf = 0; nf < BNF; ++nf)
#pragma unroll
                for (int kk = 0; kk < 2; ++kk)
                    acc[6 + m][nf] = __builtin_amdgcn_mfma_f32_16x16x32_bf16(
                        af[m][kk], bq[nf][kk], acc[6 + m][nf], 0, 0, 0);
        __builtin_amdgcn_s_setprio(0);
        asm volatile("s_waitcnt vmcnt(%0)" :: "i"(NWT) : "memory");
        __builtin_amdgcn_s_barrier();      // A(t+1)+B(t+1) resident for all
    }
    asm volatile("s_waitcnt vmcnt(0)" ::: "memory");   // drain wrap stages

    // epilogue: per-wave 128 x BN/4 C-write
#pragma unroll
    for (int mf = 0; mf < 8; ++mf) {
#pragma unroll
        for (int i = 0; i < 4; ++i) {
            size_t row = (size_t)(brow + wm * 128 + mf * 16 + quad * 4 + i);
#pragma unroll
            for (int nf = 0; nf < BNF; ++nf) {
                int col = bcol + wn * (BN / 4) + nf * 16 + l15;
                if (OUT_MODE == 1)
                    ((unsigned short*)C)[row * ldc + col] = f2bf(acc[mf][nf][i]);
                else
                    ((float*)C)[row * ldc + col] = acc[mf][nf][i];
            }
        }
    }
}

// ---------------------------------------------------------------------------
// RoPE in-place on bf16 q (inside qkvb) and bf16 k (kb).
// ---------------------------------------------------------------------------
__global__ __launch_bounds__(256) void rope_bf16(unsigned short* __restrict__ qkvb,
                                                 unsigned short* __restrict__ kb)
{
    int idx = blockIdx.x * 256 + threadIdx.x;
    int i    = idx & 31;
    int head = (idx >> 5) % 20;
    int t    = idx / (20 * 32);
    if (t >= NTOK) return;
    int pos = t & (SEQ - 1);

    const float LOG_BASE_OVER_32 = 0.28782313662425572f; // ln(10000)/32
    float ang = (float)pos * __expf(-(float)i * LOG_BASE_OVER_32);
    float c = cosf(ang);
    float sn = sinf(ang);

    unsigned short* p;
    if (head < NH) p = qkvb + (size_t)t * QKV_W + head * D_QKD + D_NOPE;
    else           p = kb   + (size_t)t * KW    + (head - NH) * D_QKD + D_NOPE;

    float x1 = bf2f(p[i]), x2 = bf2f(p[i + 32]);
    p[i]      = f2bf(x1 * c - x2 * sn);
    p[i + 32] = f2bf(x2 * c + x1 * sn);
}

// ---------------------------------------------------------------------------
// MFMA flash attention, causal, GQA (R7 structure, unchanged):
// 8 waves / 512 threads / 128 q-rows per block; 40 KB LDS; 512-block grid
// fully co-resident; XCD-local K/V mapping; balanced qt pairing;
// in-register P via swapped QK^T + k-permuted V; wave-uniform mask skip;
// v_cvt_pk_bf16_f32 P-pack; setprio around MFMA clusters.
// ---------------------------------------------------------------------------
__global__ __launch_bounds__(512) void attn_mfma(
    const unsigned short* __restrict__ qkvb,
    const unsigned short* __restrict__ kb,
    const unsigned short* __restrict__ vt,
    unsigned short* __restrict__ attnb)
{
    __shared__ __align__(16) unsigned short KsL[2 * 32 * 192];  // 2 x 12 KB
    __shared__ __align__(16) unsigned short VtL[2 * 128 * 32];  // 2 x 8 KB

    const int tid  = threadIdx.x;
    const int w    = tid >> 6;            // 0..7
    const int lane = tid & 63;
    const int quad = lane >> 4;
    const int l15  = lane & 15;

    const int bid = blockIdx.x;           // 512 blocks
    const int xcd = bid & 7;
    const int kvh = xcd >> 1;
    const int b   = xcd & 1;
    const int rest = bid >> 3;            // 0..63
    const int h   = kvh * 4 + (rest & 3);
    const int g   = rest >> 2;            // 0..15
    const int qt  = (g < 8) ? (15 - g) : (g - 8);   // balanced pairing
    const int q0  = qt * 128;

    const int x7   = l15 & 7;             // K read swizzle
    const int vx   = (l15 >> 1) & 3;      // V read swizzle

    // Per-lane DMA source offsets (shorts), tile-invariant.
    // waves 2..7: K stagers (2 x 16B-blocks); waves 0..1: V stagers (4).
    int koff[2], voff[4];
#pragma unroll
    for (int it = 0; it < 2; ++it) {
        int bidx = ((w - 2) * 2 + it) * 64 + lane;    // 0..767 for w in [2,8)
        int row  = bidx / 24;
        int sblk = bidx - row * 24;
        int gblk = sblk ^ (row & 7);
        koff[it] = row * KW + gblk * 8;
    }
#pragma unroll
    for (int it = 0; it < 4; ++it) {
        int bidx = (w * 4 + it) * 64 + lane;          // 0..511 for w in [0,2)
        int row  = bidx >> 2;
        int gblk = (bidx & 3) ^ ((row >> 1) & 3);
        voff[it] = row * NTOK + gblk * 8;
    }
    const unsigned short* kp0 = kb + (size_t)(b * SEQ) * KW + kvh * D_QKD;
    const unsigned short* vp0 = vt + (size_t)(kvh * 128) * NTOK + b * SEQ;

    const int q0w  = q0 + w * 16;
    const int wmax = q0w + 15;

    bf16x8 qf[6];
    {
        const unsigned short* qp =
            qkvb + (size_t)(b * SEQ + q0w + l15) * QKV_W + h * D_QKD + quad * 8;
#pragma unroll
        for (int t = 0; t < 6; ++t)
            qf[t] = __builtin_bit_cast(bf16x8, *(const uint4*)(qp + t * 32));
    }

    f32x4 o[8];
#pragma unroll
    for (int c = 0; c < 8; ++c) o[c] = (f32x4){0.f, 0.f, 0.f, 0.f};
    float lp = 0.f;     // partial l for q-row l15 over this lane's k-slots

    const int nt = 4 * qt + 4;

    // DMA tile 0 into buffer 0 (role-split staging)
    if (w >= 2) {
#pragma unroll
        for (int it = 0; it < 2; ++it)
            gl2lds16(kp0 + koff[it], KsL + ((w - 2) * 2 + it) * 512);
    } else {
#pragma unroll
        for (int it = 0; it < 4; ++it)
            gl2lds16(vp0 + voff[it], VtL + (w * 4 + it) * 512);
    }
    __syncthreads();   // vmcnt drain: tile 0 staged

    for (int tk = 0; tk < nt; ++tk) {
        const int k0  = tk * 32;
        const int cur = tk & 1;

        // Issue DMA for tile tk+1 into the other buffer (no wait, no regs)
        if (tk + 1 < nt) {
            const int nxt = cur ^ 1;
            if (w >= 2) {
                const unsigned short* ks = kp0 + (size_t)(k0 + 32) * KW;
#pragma unroll
                for (int it = 0; it < 2; ++it)
                    gl2lds16(ks + koff[it], KsL + nxt * (32 * 192) + ((w - 2) * 2 + it) * 512);
            } else {
                const unsigned short* vs = vp0 + (k0 + 32);
#pragma unroll
                for (int it = 0; it < 4; ++it)
                    gl2lds16(vs + voff[it], VtL + nxt * (128 * 32) + (w * 4 + it) * 512);
            }
        }

        if (k0 <= wmax) {
            const unsigned short* Kc = KsL + cur * (32 * 192);
            const unsigned short* Vc = VtL + cur * (128 * 32);

            // ---- scores: S^T[32k][16q] = K @ Q^T (log2 domain), swapped ----
            f32x4 s[2];
            __builtin_amdgcn_s_setprio(1);
#pragma unroll
            for (int j = 0; j < 2; ++j) {
                f32x4 acc = {0.f, 0.f, 0.f, 0.f};
                const unsigned short* kr = Kc + (j * 16 + l15) * 192;
#pragma unroll
                for (int t = 0; t < 6; ++t) {
                    int sblk = (quad + 4 * t) ^ x7;
                    bf16x8 kf = __builtin_bit_cast(bf16x8, *(const uint4*)(kr + sblk * 8));
                    acc = __builtin_amdgcn_mfma_f32_16x16x32_bf16(kf, qf[t], acc, 0, 0, 0);
                }
                s[j] = acc;
            }
            __builtin_amdgcn_s_setprio(0);
            // lane holds S[q = l15][k = k0 + j*16 + quad*4 + i]

            // ---- softmax, fixed m=0, exp2; wave-uniform mask skip ----
            if (k0 + 31 <= q0w) {
#pragma unroll
                for (int j = 0; j < 2; ++j)
#pragma unroll
                    for (int i = 0; i < 4; ++i) {
                        float p = __builtin_amdgcn_exp2f(s[j][i]);
                        s[j][i] = p;
                        lp += p;
                    }
            } else {
                const int qrow = q0w + l15;
#pragma unroll
                for (int j = 0; j < 2; ++j)
#pragma unroll
                    for (int i = 0; i < 4; ++i) {
                        int kidx = k0 + j * 16 + quad * 4 + i;
                        float p = (kidx <= qrow) ? __builtin_amdgcn_exp2f(s[j][i]) : 0.f;
                        s[j][i] = p;
                        lp += p;
                    }
            }

            // ---- P -> A-frag: HW pack, pure in-register (k-permuted V) ----
            uint4 pk;
            pk.x = cvt_pk_bf16(s[0][0], s[0][1]);
            pk.y = cvt_pk_bf16(s[0][2], s[0][3]);
            pk.z = cvt_pk_bf16(s[1][0], s[1][1]);
            pk.w = cvt_pk_bf16(s[1][2], s[1][3]);
            bf16x8 pa = __builtin_bit_cast(bf16x8, pk);

            // ---- PV: 8 MFMAs, swizzled V frags ----
            __builtin_amdgcn_s_setprio(1);
#pragma unroll
            for (int c = 0; c < 8; ++c) {
                bf16x8 vf = __builtin_bit_cast(bf16x8,
                    *(const uint4*)(Vc + (c * 16 + l15) * 32 + ((quad ^ vx) * 8)));
                o[c] = __builtin_amdgcn_mfma_f32_16x16x32_bf16(pa, vf, o[c], 0, 0, 0);
            }
            __builtin_amdgcn_s_setprio(0);
        }

        __syncthreads();   // waves done with buf cur; DMA for tk+1 drained
    }

    // ---- epilogue: total l per q-row, redistribute to C-layout rows ----
    float lt = lp;
    lt += __shfl_xor(lt, 16);
    lt += __shfl_xor(lt, 32);      // all lanes: l for q-row = their l15

#pragma unroll
    for (int i = 0; i < 4; ++i) {
        float inv = 1.0f / __shfl(lt, (lane & 48) | (quad * 4 + i));
        size_t rowoff = (size_t)(b * SEQ + q0w + quad * 4 + i) * AW + h * D_VV + l15;
#pragma unroll
        for (int c = 0; c < 8; ++c)
            attnb[rowoff + c * 16] = f2bf(o[c][i] * inv);
    }
}

// ---------------------------------------------------------------------------
extern "C" void kernel_launch(void* const* d_in, const int* in_sizes, int n_in,
                              void* d_out, int out_size, void* d_ws, size_t ws_size,
                              hipStream_t stream)
{
    const float* X     = (const float*)d_in[0];
    const float* Wqkv  = (const float*)d_in[1];
    const float* Wk_up = (const float*)d_in[2];
    const float* Wv_up = (const float*)d_in[3];
    const float* Wo    = (const float*)d_in[4];
    float* out = (float*)d_out;

    unsigned short* Xb    = (unsigned short*)d_ws;                   // [4096][2048]
    unsigned short* Wqt   = Xb    + (size_t)NTOK * HIDN;             // [3584][2048]
    unsigned short* Wkt   = Wqt   + (size_t)QKV_W * HIDN;            // [768][512]
    unsigned short* Wvt   = Wkt   + (size_t)KW * LORA;               // [512][512]
    unsigned short* Wot   = Wvt   + (size_t)VW * LORA;               // [2048][2048]
    unsigned short* qkvb  = Wot   + (size_t)HIDN * AW;               // [4096][3584]
    unsigned short* kb    = qkvb  + (size_t)NTOK * QKV_W;            // [4096][768]
    unsigned short* vtb   = kb    + (size_t)NTOK * KW;               // [512][4096] (V^T, k-permuted)
    unsigned short* attnb = vtb   + (size_t)VW * NTOK;               // [4096][2048]

    cast_plain<<<NTOK * HIDN / 4 / 256, 256, 0, stream>>>(X, Xb);
    // q columns pre-scaled by (1/sqrt(192)) * log2(e): softmax runs in exp2 domain
    transpose_w<<<dim3(QKV_W / 64, HIDN / 64), 256, 0, stream>>>(
        Wqkv, Wqt, HIDN, QKV_W, NH * D_QKD, QSCALE * LOG2E);
    transpose_w<<<dim3(KW / 64, LORA / 64), 256, 0, stream>>>(Wk_up, Wkt, LORA, KW, 0, 1.0f);
    transpose_w<<<dim3(VW / 64, LORA / 64), 256, 0, stream>>>(Wv_up, Wvt, LORA, VW, 0, 1.0f);
    transpose_w<<<dim3(AW / 64, HIDN / 64), 256, 0, stream>>>(Wo, Wot, HIDN, AW, 0, 1.0f);

    // qkvb = Xb @ Wqt^T (bf16; q cols pre-scaled) — lean-sync 256x256
    gemm8p<1, 256><<<dim3(QKV_W / 256, NTOK / 256), 512, 131072, stream>>>(
        Xb, Wqt, qkvb, HIDN, HIDN, HIDN, QKV_W);

    // kb = c_kv @ Wkt^T (bf16) ; vt = (c_kv @ Wvt^T)^T (bf16, k-permuted cols)
    gemm_bt<1><<<dim3(KW / 128, NTOK / 128), 256, 0, stream>>>(
        qkvb + NH * D_QKD, Wkt, kb, LORA, QKV_W, LORA, KW);
    gemm_bt<2><<<dim3(VW / 128, NTOK / 128), 256, 0, stream>>>(
        qkvb + NH * D_QKD, Wvt, vtb, LORA, QKV_W, LORA, NTOK);

    rope_bf16<<<(NTOK * 20 * 32 + 255) / 256, 256, 0, stream>>>(qkvb, kb);

    attn_mfma<<<dim3(512), 512, 0, stream>>>(qkvb, kb, vtb, attnb);

    // out = attnb @ Wot^T (fp32) — lean-sync 256x128 (grid 256 = full CU fill)
    gemm8p<0, 128><<<dim3(HIDN / 128, NTOK / 256), 512, 98304, stream>>>(
        attnb, Wot, out, AW, AW, AW, HIDN);
}